// Round 21
// baseline (427.243 us; speedup 1.0000x reference)
//
#include <hip/hip_runtime.h>
#include <math.h>

#define NN 100000
#define EE 800000
#define ETOT (EE + NN)
#define CAP 128
#define NBLK2 440            // sort blocks
#define EPB 2048             // edges per sort block (440*2048 >= ETOT)
#define NBUCK 256            // histogram buckets; bucket = d>>9 (<=195)
#define NSCAN (NBUCK * NBLK2)
#define NGRP ((NN + 511) >> 9)   // 196 dst-groups of 512
// HID=64, HEADS=4, OBS=128, ACT=32

// ---------------- GEMM: C[M,Nc] = A[M,K] @ B[K,Nc] (+bias, optional relu) ----------------
// R20: BK=32 + 2-phase register pipeline. 1024 cyc of FMA per staged load (covers the
// ~900cyc HBM miss), half the barriers of BK=16. Stage regs 4x float4 (+16 VGPR).
// K % 32 == 0 (sites: 64/128/256); Nc <= 64, Nc % 4 == 0.
__global__ __launch_bounds__(256) void gemm_kernel(
    const float* __restrict__ A, const float* __restrict__ B,
    const float* __restrict__ bias, float* __restrict__ C,
    int M, int K, int Nc, int doRelu)
{
    __shared__ __align__(16) float sA[32 * 68];  // [k][row 0..63]
    __shared__ __align__(16) float sB[32 * 68];  // [k][col 0..63]

    const int bm = blockIdx.x * 64;
    const int tid = threadIdx.x;
    const int ty = tid >> 4;
    const int tx = tid & 15;

    // stage indexing (2 float4 per thread per matrix)
    const int ar0 = tid >> 3;           // A row for p=0 (0..31)  -> idx = tid
    const int ar1 = (tid + 256) >> 3;   // A row for p=1 (32..63)
    const int ac  = (tid & 7) * 4;      // A k-offset (float4)
    const int br0 = tid >> 4;           // B row p=0 (0..15)
    const int br1 = (tid + 256) >> 4;   // B row p=1 (16..31)
    const int bc  = (tid & 15) * 4;     // B col
    const int grA0 = bm + ar0, grA1 = bm + ar1;

    float acc[4][4] = {};
    float4 ra0 = {0,0,0,0}, ra1 = {0,0,0,0}, rb0 = {0,0,0,0}, rb1 = {0,0,0,0};
    const int NT = K >> 5;

    // prologue: load tile 0 into regs
    if (grA0 < M) ra0 = *(const float4*)&A[(size_t)grA0 * K + ac];
    if (grA1 < M) ra1 = *(const float4*)&A[(size_t)grA1 * K + ac];
    if (bc < Nc) {
        rb0 = *(const float4*)&B[(size_t)br0 * Nc + bc];
        rb1 = *(const float4*)&B[(size_t)br1 * Nc + bc];
    }

    for (int t = 0; t < NT; ++t) {
        // write staged regs to LDS (transpose A)
        sA[(ac + 0) * 68 + ar0] = ra0.x;
        sA[(ac + 1) * 68 + ar0] = ra0.y;
        sA[(ac + 2) * 68 + ar0] = ra0.z;
        sA[(ac + 3) * 68 + ar0] = ra0.w;
        sA[(ac + 0) * 68 + ar1] = ra1.x;
        sA[(ac + 1) * 68 + ar1] = ra1.y;
        sA[(ac + 2) * 68 + ar1] = ra1.z;
        sA[(ac + 3) * 68 + ar1] = ra1.w;
        *(float4*)&sB[br0 * 68 + bc] = rb0;
        *(float4*)&sB[br1 * 68 + bc] = rb1;
        __syncthreads();

        // issue next-tile loads (hide under 512 FMAs/thread below)
        if (t + 1 < NT) {
            const int k0 = (t + 1) << 5;
            ra0 = make_float4(0.f, 0.f, 0.f, 0.f);
            ra1 = make_float4(0.f, 0.f, 0.f, 0.f);
            rb0 = make_float4(0.f, 0.f, 0.f, 0.f);
            rb1 = make_float4(0.f, 0.f, 0.f, 0.f);
            if (grA0 < M) ra0 = *(const float4*)&A[(size_t)grA0 * K + k0 + ac];
            if (grA1 < M) ra1 = *(const float4*)&A[(size_t)grA1 * K + k0 + ac];
            if (bc < Nc) {
                rb0 = *(const float4*)&B[(size_t)(k0 + br0) * Nc + bc];
                rb1 = *(const float4*)&B[(size_t)(k0 + br1) * Nc + bc];
            }
        }

#pragma unroll
        for (int k = 0; k < 32; ++k) {
            float4 a0 = *(const float4*)&sA[k * 68 + ty * 4];
            float4 b0 = *(const float4*)&sB[k * 68 + tx * 4];
            float a[4] = {a0.x, a0.y, a0.z, a0.w};
            float b[4] = {b0.x, b0.y, b0.z, b0.w};
#pragma unroll
            for (int i = 0; i < 4; ++i)
#pragma unroll
                for (int j = 0; j < 4; ++j)
                    acc[i][j] = fmaf(a[i], b[j], acc[i][j]);
        }
        __syncthreads();
    }

    const int gc = tx * 4;
    float bv[4] = {0.f, 0.f, 0.f, 0.f};
    if (bias && gc < Nc) {
        bv[0] = bias[gc + 0]; bv[1] = bias[gc + 1];
        bv[2] = bias[gc + 2]; bv[3] = bias[gc + 3];
    }
    if (gc < Nc) {
#pragma unroll
        for (int i = 0; i < 4; ++i) {
            int gr = bm + ty * 4 + i;
            if (gr >= M) continue;
            float4 v;
            v.x = acc[i][0] + bv[0];
            v.y = acc[i][1] + bv[1];
            v.z = acc[i][2] + bv[2];
            v.w = acc[i][3] + bv[3];
            if (doRelu) {
                v.x = fmaxf(v.x, 0.f); v.y = fmaxf(v.y, 0.f);
                v.z = fmaxf(v.z, 0.f); v.w = fmaxf(v.w, 0.f);
            }
            *(float4*)&C[(size_t)gr * Nc + gc] = v;
        }
    }
}

__device__ __forceinline__ float lrelu(float x) { return fmaxf(x, 0.2f * x); }
__device__ __forceinline__ float fexp(float x) { return __expf(x); }  // v_exp_f32 path
__device__ __forceinline__ int edge_src(const int* ei, int e) { return e < EE ? ei[e] : e - EE; }
__device__ __forceinline__ int edge_dst(const int* ei, int e) { return e < EE ? ei[EE + e] : e - EE; }

// ================= generic 3-kernel exclusive scan (n <= 131072) =================
__global__ __launch_bounds__(256) void gscan_partial(const int* __restrict__ in, int* __restrict__ partial, int n)
{
    __shared__ int s[256];
    int b = blockIdx.x;
    int gi = b * 512 + threadIdx.x;
    int v = 0;
    if (gi < n) v += in[gi];
    if (gi + 256 < n) v += in[gi + 256];
    s[threadIdx.x] = v;
    __syncthreads();
    for (int off = 128; off > 0; off >>= 1) {
        if (threadIdx.x < off) s[threadIdx.x] += s[threadIdx.x + off];
        __syncthreads();
    }
    if (threadIdx.x == 0) partial[b] = s[0];
}

__global__ __launch_bounds__(256) void gscan_top(int* __restrict__ partial, int nb)
{
    __shared__ int s[256];
    int tid = threadIdx.x;
    s[tid] = (tid < nb) ? partial[tid] : 0;
    __syncthreads();
    for (int off = 1; off < 256; off <<= 1) {
        int t = (tid >= off) ? s[tid - off] : 0;
        __syncthreads();
        s[tid] += t;
        __syncthreads();
    }
    if (tid < nb) partial[tid] = (tid == 0) ? 0 : s[tid - 1];
}

__global__ __launch_bounds__(256) void gscan_final(
    const int* __restrict__ in, const int* __restrict__ partial, int* __restrict__ out, int n)
{
    __shared__ int s[512];
    int b = blockIdx.x;
    int tid = threadIdx.x;
    int g0 = b * 512 + tid, g1 = b * 512 + tid + 256;
    s[tid]       = (g0 < n) ? in[g0] : 0;
    s[tid + 256] = (g1 < n) ? in[g1] : 0;
    __syncthreads();
#pragma unroll
    for (int d = 0; d < 9; ++d) {
        int stride = 1 << d, nn2 = 256 >> d;
        if (tid < nn2) s[(2 * tid + 2) * stride - 1] += s[(2 * tid + 1) * stride - 1];
        __syncthreads();
    }
    if (tid == 0) s[511] = 0;
    __syncthreads();
#pragma unroll
    for (int d = 8; d >= 0; --d) {
        int stride = 1 << d, nn2 = 256 >> d;
        if (tid < nn2) {
            int i1 = (2 * tid + 1) * stride - 1, i2 = (2 * tid + 2) * stride - 1;
            int t = s[i1];
            s[i1] = s[i2];
            s[i2] += t;
        }
        __syncthreads();
    }
    int off = partial[b];
    if (g0 < n) out[g0] = s[tid] + off;
    if (g1 < n) out[g1] = s[tid + 256] + off;
}

__global__ void set_tail(int* __restrict__ row_ptr)
{
    row_ptr[NN] = ETOT;
}

// ================= counting sort of edges by dst-group =================
__global__ __launch_bounds__(256) void sort_hist(
    const int* __restrict__ ei, int* __restrict__ hist_bm, int* __restrict__ cnt)
{
    __shared__ int h[NBUCK];
    int tid = threadIdx.x, blk = blockIdx.x;
    h[tid] = 0;
    __syncthreads();
#pragma unroll
    for (int it = 0; it < EPB / 256; ++it) {
        int e = blk * EPB + it * 256 + tid;
        if (e < ETOT) {
            int d = edge_dst(ei, e);
            atomicAdd(&h[d >> 9], 1);
            atomicAdd(&cnt[d], 1);
        }
    }
    __syncthreads();
    hist_bm[tid * NBLK2 + blk] = h[tid];
}

__global__ __launch_bounds__(256) void sort_scatter(
    const int* __restrict__ ei, const int* __restrict__ off_bm, int2* __restrict__ srec)
{
    __shared__ int cur[NBUCK];
    int tid = threadIdx.x, blk = blockIdx.x;
    cur[tid] = off_bm[tid * NBLK2 + blk];
    __syncthreads();
#pragma unroll
    for (int it = 0; it < EPB / 256; ++it) {
        int e = blk * EPB + it * 256 + tid;
        if (e < ETOT) {
            int d = edge_dst(ei, e);
            int s = edge_src(ei, e);
            int pos = atomicAdd(&cur[d >> 9], 1);
            srec[pos] = make_int2(s, d);
        }
    }
}

__global__ __launch_bounds__(256) void csr_fill2(
    const int* __restrict__ row_ptr, const int2* __restrict__ srec, int* __restrict__ col_src)
{
    __shared__ int cur[512];
    int g = blockIdx.x, tid = threadIdx.x;
    int n0 = g << 9;
    for (int i = tid; i < 512; i += 256) {
        int nd = n0 + i;
        cur[i] = (nd < NN) ? row_ptr[nd] : 0;
    }
    __syncthreads();
    int lo = row_ptr[n0];
    int hi = (n0 + 512 <= NN) ? row_ptr[n0 + 512] : ETOT;
    for (int idx = lo + tid; idx < hi; idx += 256) {
        int2 r = srec[idx];
        int pos = atomicAdd(&cur[r.y - n0], 1);
        col_src[pos] = r.x;
    }
}

// ================= per-layer weight precomputes (att_vec + permW fused) =================
__global__ __launch_bounds__(256) void prep_kernel(
    const float* __restrict__ W, const float* __restrict__ attS,
    const float* __restrict__ attD, float* __restrict__ vs, float* __restrict__ vd,
    float* __restrict__ B2)
{
    int tid = threadIdx.x;
    if (blockIdx.x == 64) {
        int k = tid >> 2, h = tid & 3;
        const float* wr = W + (size_t)k * 256 + h * 64;
        const float* as = attS + h * 64;
        const float* ad = attD + h * 64;
        float ss = 0.f, sd = 0.f;
#pragma unroll
        for (int j = 0; j < 64; ++j) {
            float wv = wr[j];
            ss += wv * as[j];
            sd += wv * ad[j];
        }
        vs[tid] = ss;
        vd[tid] = sd;
    } else {
        int i = blockIdx.x * 256 + tid;   // i = r*64+j, r = h*64+k
        int r = i >> 6, j = i & 63;
        int h = r >> 6, k = r & 63;
        B2[i] = W[(size_t)k * 256 + h * 64 + j];
    }
}

// ================= attention scores directly from x =================
__global__ __launch_bounds__(256) void scores_x_kernel(
    const float* __restrict__ x, const float* __restrict__ vs,
    const float* __restrict__ vd, float4* __restrict__ a4s, float4* __restrict__ a4d)
{
    __shared__ float4 svs[64], svd[64];
    int tid = threadIdx.x;
    if (tid < 64) {
        svs[tid] = ((const float4*)vs)[tid];
        svd[tid] = ((const float4*)vd)[tid];
    }
    __syncthreads();
    int n = blockIdx.x * 256 + tid;
    if (n >= NN) return;
    const float4* xp = (const float4*)(x + (size_t)n * 64);
    float4 as = {0.f, 0.f, 0.f, 0.f}, ad = {0.f, 0.f, 0.f, 0.f};
#pragma unroll
    for (int i = 0; i < 16; ++i) {
        float4 xv = xp[i];
        float4 s0 = svs[i * 4 + 0], s1 = svs[i * 4 + 1], s2 = svs[i * 4 + 2], s3 = svs[i * 4 + 3];
        float4 d0 = svd[i * 4 + 0], d1 = svd[i * 4 + 1], d2 = svd[i * 4 + 2], d3 = svd[i * 4 + 3];
        as.x += xv.x * s0.x + xv.y * s1.x + xv.z * s2.x + xv.w * s3.x;
        as.y += xv.x * s0.y + xv.y * s1.y + xv.z * s2.y + xv.w * s3.y;
        as.z += xv.x * s0.z + xv.y * s1.z + xv.z * s2.z + xv.w * s3.z;
        as.w += xv.x * s0.w + xv.y * s1.w + xv.z * s2.w + xv.w * s3.w;
        ad.x += xv.x * d0.x + xv.y * d1.x + xv.z * d2.x + xv.w * d3.x;
        ad.y += xv.x * d0.y + xv.y * d1.y + xv.z * d2.y + xv.w * d3.y;
        ad.z += xv.x * d0.z + xv.y * d1.z + xv.z * d2.z + xv.w * d3.z;
        ad.w += xv.x * d0.w + xv.y * d1.w + xv.z * d2.w + xv.w * d3.w;
    }
    a4s[n] = as;
    a4d[n] = ad;
}

// ================= fused softmax + gather aggregation (wave per dst) =================
__global__ __launch_bounds__(256) void gat_fused(
    const int* __restrict__ row_ptr, const int* __restrict__ col_src,
    const float4* __restrict__ a4s, const float4* __restrict__ a4d,
    const float* __restrict__ x, float* __restrict__ agg)
{
    __shared__ float4 sp[4][CAP];
    __shared__ int    ssrc[4][CAP];
    const int wslot = threadIdx.x >> 6;
    const int lane = threadIdx.x & 63;
    const int d = (blockIdx.x * 256 + threadIdx.x) >> 6;   // grid sized so d < NN always

    const int rs = row_ptr[d];
    const int deg = row_ptr[d + 1] - rs;
    const float4 ad = a4d[d];

    // ---- Phase A: edge-parallel p + head sums ----
    float px = 0.f, py = 0.f, pz = 0.f, pw = 0.f;
    for (int base = 0; base < deg; base += 64) {
        int idx = base + lane;
        float4 p = {0.f, 0.f, 0.f, 0.f};
        int s = 0;
        if (idx < deg) {
            s = col_src[rs + idx];
            float4 v = a4s[s];
            p.x = fexp(lrelu(v.x + ad.x));
            p.y = fexp(lrelu(v.y + ad.y));
            p.z = fexp(lrelu(v.z + ad.z));
            p.w = fexp(lrelu(v.w + ad.w));
        }
        if (idx < CAP) { sp[wslot][idx] = p; ssrc[wslot][idx] = s; }
        px += p.x; py += p.y; pz += p.z; pw += p.w;
    }
#pragma unroll
    for (int off = 32; off > 0; off >>= 1) {
        px += __shfl_xor(px, off, 64);
        py += __shfl_xor(py, off, 64);
        pz += __shfl_xor(pz, off, 64);
        pw += __shfl_xor(pw, off, 64);
    }
    const float ivx = 0.25f * __builtin_amdgcn_rcpf(px);
    const float ivy = 0.25f * __builtin_amdgcn_rcpf(py);
    const float ivz = 0.25f * __builtin_amdgcn_rcpf(pz);
    const float ivw = 0.25f * __builtin_amdgcn_rcpf(pw);

    // ---- Phase B: feature-parallel x gather (scalar, 4-deep) ----
    float a0 = 0.f, a1 = 0.f, a2 = 0.f, a3 = 0.f;
    const int lim = deg < CAP ? deg : CAP;
    int e = 0;
    for (; e + 4 <= lim; e += 4) {
        float4 p0 = sp[wslot][e + 0], p1 = sp[wslot][e + 1];
        float4 p2 = sp[wslot][e + 2], p3 = sp[wslot][e + 3];
        int s0 = ssrc[wslot][e + 0], s1 = ssrc[wslot][e + 1];
        int s2 = ssrc[wslot][e + 2], s3 = ssrc[wslot][e + 3];
        float x0 = x[(size_t)s0 * 64 + lane];
        float x1 = x[(size_t)s1 * 64 + lane];
        float x2 = x[(size_t)s2 * 64 + lane];
        float x3 = x[(size_t)s3 * 64 + lane];
        a0 += p0.x * x0 + p1.x * x1 + p2.x * x2 + p3.x * x3;
        a1 += p0.y * x0 + p1.y * x1 + p2.y * x2 + p3.y * x3;
        a2 += p0.z * x0 + p1.z * x1 + p2.z * x2 + p3.z * x3;
        a3 += p0.w * x0 + p1.w * x1 + p2.w * x2 + p3.w * x3;
    }
    for (; e < lim; ++e) {
        float4 p = sp[wslot][e];
        int s = ssrc[wslot][e];
        float xv = x[(size_t)s * 64 + lane];
        a0 = fmaf(p.x, xv, a0);
        a1 = fmaf(p.y, xv, a1);
        a2 = fmaf(p.z, xv, a2);
        a3 = fmaf(p.w, xv, a3);
    }
    for (; e < deg; ++e) {   // slow path, statistically never taken
        int s = col_src[rs + e];
        float4 v = a4s[s];
        float4 p;
        p.x = fexp(lrelu(v.x + ad.x)); p.y = fexp(lrelu(v.y + ad.y));
        p.z = fexp(lrelu(v.z + ad.z)); p.w = fexp(lrelu(v.w + ad.w));
        float xv = x[(size_t)s * 64 + lane];
        a0 = fmaf(p.x, xv, a0);
        a1 = fmaf(p.y, xv, a1);
        a2 = fmaf(p.z, xv, a2);
        a3 = fmaf(p.w, xv, a3);
    }

    float* op = agg + (size_t)d * 256;
    __builtin_nontemporal_store(a0 * ivx, &op[lane]);
    __builtin_nontemporal_store(a1 * ivy, &op[64 + lane]);
    __builtin_nontemporal_store(a2 * ivz, &op[128 + lane]);
    __builtin_nontemporal_store(a3 * ivw, &op[192 + lane]);
}

// ---------------- host-side GAT layer ----------------
static void gat_layer(float* x /* in/out [N,64] */, const float* W, const float* attS,
                      const float* attD, const float* b, const int* row_ptr, const int* col_src,
                      float* agg, float4* a4s, float4* a4d,
                      float* vs, float* vd, float* B2, hipStream_t stream)
{
    prep_kernel<<<65, 256, 0, stream>>>(W, attS, attD, vs, vd, B2);
    scores_x_kernel<<<(NN + 255) / 256, 256, 0, stream>>>(x, vs, vd, a4s, a4d);
    gat_fused<<<(NN * 64) / 256, 256, 0, stream>>>(row_ptr, col_src, a4s, a4d, x, agg);
    // x_out = relu(agg @ B2 + b)   (0.25 folded into iv)
    gemm_kernel<<<(NN + 63) / 64, 256, 0, stream>>>(agg, B2, b, x, NN, 256, 64, 1);
}

extern "C" void kernel_launch(void* const* d_in, const int* in_sizes, int n_in,
                              void* d_out, int out_size, void* d_ws, size_t ws_size,
                              hipStream_t stream)
{
    const float* obs     = (const float*)d_in[0];
    const int*   ei      = (const int*)d_in[1];
    const float* enc_w1  = (const float*)d_in[2];
    const float* enc_b1  = (const float*)d_in[3];
    const float* enc_w2  = (const float*)d_in[4];
    const float* enc_b2  = (const float*)d_in[5];
    const float* gat1_w  = (const float*)d_in[6];
    const float* gat1_as = (const float*)d_in[7];
    const float* gat1_ad = (const float*)d_in[8];
    const float* gat1_b  = (const float*)d_in[9];
    const float* gat2_w  = (const float*)d_in[10];
    const float* gat2_as = (const float*)d_in[11];
    const float* gat2_ad = (const float*)d_in[12];
    const float* gat2_b  = (const float*)d_in[13];
    const float* dec_w1  = (const float*)d_in[14];
    const float* dec_b1  = (const float*)d_in[15];
    const float* dec_w2  = (const float*)d_in[16];
    const float* dec_b2  = (const float*)d_in[17];

    float* ws = (float*)d_ws;
    float* bufA    = ws;                                   // [N,64]
    float* bufB    = bufA + (size_t)NN * 64;               // [N,64]  (x)
    float* agg     = bufB + (size_t)NN * 64;               // [N,256]
    float4* a4s    = (float4*)(agg + (size_t)NN * 256);    // [N]
    float4* a4d    = a4s + NN;                             // [N]
    int* row_ptr   = (int*)(a4d + NN);                     // [N+1] (+pad)
    int* cnt       = row_ptr + NN + 4;                     // [N]
    int* col_src   = cnt + NN;                             // [ETOT]
    int* partial   = col_src + ETOT;                       // [256]
    int* partial2  = partial + 256;                        // [256]
    float* vs      = (float*)(partial2 + 256);             // [256]
    float* vd      = vs + 256;                             // [256]
    float* B2      = vd + 256;                             // [256*64]
    int* hist      = (int*)(B2 + 256 * 64);                // [NSCAN]
    int* off_bm    = hist + NSCAN;                         // [NSCAN]
    int2* srec     = (int2*)(off_bm + NSCAN);              // [ETOT]

    const int GB = (NN + 63) / 64;
    const int NCHUNK_N = (NN + 511) / 512;        // 196
    const int NCHUNK_S = (NSCAN + 511) / 512;     // 220

    // ---- CSR build via counting sort (once, reused by both GAT layers) ----
    hipMemsetAsync(cnt, 0, (size_t)NN * sizeof(int), stream);
    sort_hist<<<NBLK2, 256, 0, stream>>>(ei, hist, cnt);
    gscan_partial<<<NCHUNK_N, 256, 0, stream>>>(cnt, partial, NN);
    gscan_top<<<1, 256, 0, stream>>>(partial, NCHUNK_N);
    gscan_final<<<NCHUNK_N, 256, 0, stream>>>(cnt, partial, row_ptr, NN);
    set_tail<<<1, 1, 0, stream>>>(row_ptr);
    gscan_partial<<<NCHUNK_S, 256, 0, stream>>>(hist, partial2, NSCAN);
    gscan_top<<<1, 256, 0, stream>>>(partial2, NCHUNK_S);
    gscan_final<<<NCHUNK_S, 256, 0, stream>>>(hist, partial2, off_bm, NSCAN);
    sort_scatter<<<NBLK2, 256, 0, stream>>>(ei, off_bm, srec);
    csr_fill2<<<NGRP, 256, 0, stream>>>(row_ptr, srec, col_src);

    // ---- encoder ----
    gemm_kernel<<<GB, 256, 0, stream>>>(obs, enc_w1, enc_b1, bufA, NN, 128, 64, 1);
    gemm_kernel<<<GB, 256, 0, stream>>>(bufA, enc_w2, enc_b2, bufB, NN, 64, 64, 0);

    // ---- GAT layers (x lives in bufB) ----
    gat_layer(bufB, gat1_w, gat1_as, gat1_ad, gat1_b, row_ptr, col_src, agg, a4s, a4d, vs, vd, B2, stream);
    gat_layer(bufB, gat2_w, gat2_as, gat2_ad, gat2_b, row_ptr, col_src, agg, a4s, a4d, vs, vd, B2, stream);

    // ---- decoder ----
    gemm_kernel<<<GB, 256, 0, stream>>>(bufB, dec_w1, dec_b1, bufA, NN, 64, 64, 1);
    gemm_kernel<<<GB, 256, 0, stream>>>(bufA, dec_w2, dec_b2, (float*)d_out, NN, 64, 32, 0);
}

// Round 22
// 414.715 us; speedup vs baseline: 1.0302x; 1.0302x over previous
//
#include <hip/hip_runtime.h>
#include <math.h>

#define NN 100000
#define EE 800000
#define ETOT (EE + NN)
#define CAP 128
#define NBLK2 440            // sort blocks
#define EPB 2048             // edges per sort block (440*2048 >= ETOT)
#define NBUCK 256            // histogram buckets; bucket = d>>9 (<=195)
#define NSCAN (NBUCK * NBLK2)
#define NGRP ((NN + 511) >> 9)   // 196 dst-groups of 512
// HID=64, HEADS=4, OBS=128, ACT=32

// ---------------- GEMM: C[M,Nc] = A[M,K] @ B[K,Nc] (+bias, optional relu) ----------------
// R21: reverted to R19's BK=16 2-phase register pipeline (best measured: 414us total).
// R20's BK=32 variant regressed (+13us): 2x stage regs + 17.4KB LDS cost ~2 blocks/CU.
__global__ __launch_bounds__(256) void gemm_kernel(
    const float* __restrict__ A, const float* __restrict__ B,
    const float* __restrict__ bias, float* __restrict__ C,
    int M, int K, int Nc, int doRelu)
{
    __shared__ __align__(16) float sA[16 * 68];  // [k][row 0..63]
    __shared__ __align__(16) float sB[16 * 68];  // [k][col 0..63]

    const int bm = blockIdx.x * 64;
    const int tid = threadIdx.x;
    const int ty = tid >> 4;
    const int tx = tid & 15;

    const int ar  = tid >> 2;        // A stage row 0..63
    const int ac  = (tid & 3) * 4;   // A stage k-offset (float4)
    const int brw = tid >> 4;        // B stage row 0..15
    const int bc  = (tid & 15) * 4;  // B stage col (float4)
    const int grA = bm + ar;

    float acc[4][4] = {};
    float4 ra = {0.f, 0.f, 0.f, 0.f}, rb = {0.f, 0.f, 0.f, 0.f};
    const int NT = K >> 4;

    // prologue: load tile 0 into regs
    if (grA < M) ra = *(const float4*)&A[(size_t)grA * K + ac];
    if (bc < Nc) rb = *(const float4*)&B[(size_t)brw * Nc + bc];

    for (int t = 0; t < NT; ++t) {
        // write staged regs to LDS (transpose A)
        sA[(ac + 0) * 68 + ar] = ra.x;
        sA[(ac + 1) * 68 + ar] = ra.y;
        sA[(ac + 2) * 68 + ar] = ra.z;
        sA[(ac + 3) * 68 + ar] = ra.w;
        *(float4*)&sB[brw * 68 + bc] = rb;
        __syncthreads();

        // issue next-tile loads (latency hides under the 256-FMA compute below)
        if (t + 1 < NT) {
            const int k0 = (t + 1) << 4;
            ra = make_float4(0.f, 0.f, 0.f, 0.f);
            rb = make_float4(0.f, 0.f, 0.f, 0.f);
            if (grA < M) ra = *(const float4*)&A[(size_t)grA * K + k0 + ac];
            if (bc < Nc) rb = *(const float4*)&B[(size_t)(k0 + brw) * Nc + bc];
        }

#pragma unroll
        for (int k = 0; k < 16; ++k) {
            float4 a0 = *(const float4*)&sA[k * 68 + ty * 4];
            float4 b0 = *(const float4*)&sB[k * 68 + tx * 4];
            float a[4] = {a0.x, a0.y, a0.z, a0.w};
            float b[4] = {b0.x, b0.y, b0.z, b0.w};
#pragma unroll
            for (int i = 0; i < 4; ++i)
#pragma unroll
                for (int j = 0; j < 4; ++j)
                    acc[i][j] = fmaf(a[i], b[j], acc[i][j]);
        }
        __syncthreads();
    }

    const int gc = tx * 4;
    float bv[4] = {0.f, 0.f, 0.f, 0.f};
    if (bias && gc < Nc) {
        bv[0] = bias[gc + 0]; bv[1] = bias[gc + 1];
        bv[2] = bias[gc + 2]; bv[3] = bias[gc + 3];
    }
    if (gc < Nc) {
#pragma unroll
        for (int i = 0; i < 4; ++i) {
            int gr = bm + ty * 4 + i;
            if (gr >= M) continue;
            float4 v;
            v.x = acc[i][0] + bv[0];
            v.y = acc[i][1] + bv[1];
            v.z = acc[i][2] + bv[2];
            v.w = acc[i][3] + bv[3];
            if (doRelu) {
                v.x = fmaxf(v.x, 0.f); v.y = fmaxf(v.y, 0.f);
                v.z = fmaxf(v.z, 0.f); v.w = fmaxf(v.w, 0.f);
            }
            *(float4*)&C[(size_t)gr * Nc + gc] = v;
        }
    }
}

__device__ __forceinline__ float lrelu(float x) { return fmaxf(x, 0.2f * x); }
__device__ __forceinline__ float fexp(float x) { return __expf(x); }  // v_exp_f32 path
__device__ __forceinline__ int edge_src(const int* ei, int e) { return e < EE ? ei[e] : e - EE; }
__device__ __forceinline__ int edge_dst(const int* ei, int e) { return e < EE ? ei[EE + e] : e - EE; }

// ================= generic 3-kernel exclusive scan (n <= 131072) =================
__global__ __launch_bounds__(256) void gscan_partial(const int* __restrict__ in, int* __restrict__ partial, int n)
{
    __shared__ int s[256];
    int b = blockIdx.x;
    int gi = b * 512 + threadIdx.x;
    int v = 0;
    if (gi < n) v += in[gi];
    if (gi + 256 < n) v += in[gi + 256];
    s[threadIdx.x] = v;
    __syncthreads();
    for (int off = 128; off > 0; off >>= 1) {
        if (threadIdx.x < off) s[threadIdx.x] += s[threadIdx.x + off];
        __syncthreads();
    }
    if (threadIdx.x == 0) partial[b] = s[0];
}

__global__ __launch_bounds__(256) void gscan_top(int* __restrict__ partial, int nb)
{
    __shared__ int s[256];
    int tid = threadIdx.x;
    s[tid] = (tid < nb) ? partial[tid] : 0;
    __syncthreads();
    for (int off = 1; off < 256; off <<= 1) {
        int t = (tid >= off) ? s[tid - off] : 0;
        __syncthreads();
        s[tid] += t;
        __syncthreads();
    }
    if (tid < nb) partial[tid] = (tid == 0) ? 0 : s[tid - 1];
}

__global__ __launch_bounds__(256) void gscan_final(
    const int* __restrict__ in, const int* __restrict__ partial, int* __restrict__ out, int n)
{
    __shared__ int s[512];
    int b = blockIdx.x;
    int tid = threadIdx.x;
    int g0 = b * 512 + tid, g1 = b * 512 + tid + 256;
    s[tid]       = (g0 < n) ? in[g0] : 0;
    s[tid + 256] = (g1 < n) ? in[g1] : 0;
    __syncthreads();
#pragma unroll
    for (int d = 0; d < 9; ++d) {
        int stride = 1 << d, nn2 = 256 >> d;
        if (tid < nn2) s[(2 * tid + 2) * stride - 1] += s[(2 * tid + 1) * stride - 1];
        __syncthreads();
    }
    if (tid == 0) s[511] = 0;
    __syncthreads();
#pragma unroll
    for (int d = 8; d >= 0; --d) {
        int stride = 1 << d, nn2 = 256 >> d;
        if (tid < nn2) {
            int i1 = (2 * tid + 1) * stride - 1, i2 = (2 * tid + 2) * stride - 1;
            int t = s[i1];
            s[i1] = s[i2];
            s[i2] += t;
        }
        __syncthreads();
    }
    int off = partial[b];
    if (g0 < n) out[g0] = s[tid] + off;
    if (g1 < n) out[g1] = s[tid + 256] + off;
}

__global__ void set_tail(int* __restrict__ row_ptr)
{
    row_ptr[NN] = ETOT;
}

// ================= counting sort of edges by dst-group =================
__global__ __launch_bounds__(256) void sort_hist(
    const int* __restrict__ ei, int* __restrict__ hist_bm, int* __restrict__ cnt)
{
    __shared__ int h[NBUCK];
    int tid = threadIdx.x, blk = blockIdx.x;
    h[tid] = 0;
    __syncthreads();
#pragma unroll
    for (int it = 0; it < EPB / 256; ++it) {
        int e = blk * EPB + it * 256 + tid;
        if (e < ETOT) {
            int d = edge_dst(ei, e);
            atomicAdd(&h[d >> 9], 1);
            atomicAdd(&cnt[d], 1);
        }
    }
    __syncthreads();
    hist_bm[tid * NBLK2 + blk] = h[tid];
}

__global__ __launch_bounds__(256) void sort_scatter(
    const int* __restrict__ ei, const int* __restrict__ off_bm, int2* __restrict__ srec)
{
    __shared__ int cur[NBUCK];
    int tid = threadIdx.x, blk = blockIdx.x;
    cur[tid] = off_bm[tid * NBLK2 + blk];
    __syncthreads();
#pragma unroll
    for (int it = 0; it < EPB / 256; ++it) {
        int e = blk * EPB + it * 256 + tid;
        if (e < ETOT) {
            int d = edge_dst(ei, e);
            int s = edge_src(ei, e);
            int pos = atomicAdd(&cur[d >> 9], 1);
            srec[pos] = make_int2(s, d);
        }
    }
}

__global__ __launch_bounds__(256) void csr_fill2(
    const int* __restrict__ row_ptr, const int2* __restrict__ srec, int* __restrict__ col_src)
{
    __shared__ int cur[512];
    int g = blockIdx.x, tid = threadIdx.x;
    int n0 = g << 9;
    for (int i = tid; i < 512; i += 256) {
        int nd = n0 + i;
        cur[i] = (nd < NN) ? row_ptr[nd] : 0;
    }
    __syncthreads();
    int lo = row_ptr[n0];
    int hi = (n0 + 512 <= NN) ? row_ptr[n0 + 512] : ETOT;
    for (int idx = lo + tid; idx < hi; idx += 256) {
        int2 r = srec[idx];
        int pos = atomicAdd(&cur[r.y - n0], 1);
        col_src[pos] = r.x;
    }
}

// ================= per-layer weight precomputes (att_vec + permW fused) =================
__global__ __launch_bounds__(256) void prep_kernel(
    const float* __restrict__ W, const float* __restrict__ attS,
    const float* __restrict__ attD, float* __restrict__ vs, float* __restrict__ vd,
    float* __restrict__ B2)
{
    int tid = threadIdx.x;
    if (blockIdx.x == 64) {
        int k = tid >> 2, h = tid & 3;
        const float* wr = W + (size_t)k * 256 + h * 64;
        const float* as = attS + h * 64;
        const float* ad = attD + h * 64;
        float ss = 0.f, sd = 0.f;
#pragma unroll
        for (int j = 0; j < 64; ++j) {
            float wv = wr[j];
            ss += wv * as[j];
            sd += wv * ad[j];
        }
        vs[tid] = ss;
        vd[tid] = sd;
    } else {
        int i = blockIdx.x * 256 + tid;   // i = r*64+j, r = h*64+k
        int r = i >> 6, j = i & 63;
        int h = r >> 6, k = r & 63;
        B2[i] = W[(size_t)k * 256 + h * 64 + j];
    }
}

// ================= attention scores directly from x =================
__global__ __launch_bounds__(256) void scores_x_kernel(
    const float* __restrict__ x, const float* __restrict__ vs,
    const float* __restrict__ vd, float4* __restrict__ a4s, float4* __restrict__ a4d)
{
    __shared__ float4 svs[64], svd[64];
    int tid = threadIdx.x;
    if (tid < 64) {
        svs[tid] = ((const float4*)vs)[tid];
        svd[tid] = ((const float4*)vd)[tid];
    }
    __syncthreads();
    int n = blockIdx.x * 256 + tid;
    if (n >= NN) return;
    const float4* xp = (const float4*)(x + (size_t)n * 64);
    float4 as = {0.f, 0.f, 0.f, 0.f}, ad = {0.f, 0.f, 0.f, 0.f};
#pragma unroll
    for (int i = 0; i < 16; ++i) {
        float4 xv = xp[i];
        float4 s0 = svs[i * 4 + 0], s1 = svs[i * 4 + 1], s2 = svs[i * 4 + 2], s3 = svs[i * 4 + 3];
        float4 d0 = svd[i * 4 + 0], d1 = svd[i * 4 + 1], d2 = svd[i * 4 + 2], d3 = svd[i * 4 + 3];
        as.x += xv.x * s0.x + xv.y * s1.x + xv.z * s2.x + xv.w * s3.x;
        as.y += xv.x * s0.y + xv.y * s1.y + xv.z * s2.y + xv.w * s3.y;
        as.z += xv.x * s0.z + xv.y * s1.z + xv.z * s2.z + xv.w * s3.z;
        as.w += xv.x * s0.w + xv.y * s1.w + xv.z * s2.w + xv.w * s3.w;
        ad.x += xv.x * d0.x + xv.y * d1.x + xv.z * d2.x + xv.w * d3.x;
        ad.y += xv.x * d0.y + xv.y * d1.y + xv.z * d2.y + xv.w * d3.y;
        ad.z += xv.x * d0.z + xv.y * d1.z + xv.z * d2.z + xv.w * d3.z;
        ad.w += xv.x * d0.w + xv.y * d1.w + xv.z * d2.w + xv.w * d3.w;
    }
    a4s[n] = as;
    a4d[n] = ad;
}

// ================= fused softmax + gather aggregation (wave per dst) =================
__global__ __launch_bounds__(256) void gat_fused(
    const int* __restrict__ row_ptr, const int* __restrict__ col_src,
    const float4* __restrict__ a4s, const float4* __restrict__ a4d,
    const float* __restrict__ x, float* __restrict__ agg)
{
    __shared__ float4 sp[4][CAP];
    __shared__ int    ssrc[4][CAP];
    const int wslot = threadIdx.x >> 6;
    const int lane = threadIdx.x & 63;
    const int d = (blockIdx.x * 256 + threadIdx.x) >> 6;   // grid sized so d < NN always

    const int rs = row_ptr[d];
    const int deg = row_ptr[d + 1] - rs;
    const float4 ad = a4d[d];

    // ---- Phase A: edge-parallel p + head sums ----
    float px = 0.f, py = 0.f, pz = 0.f, pw = 0.f;
    for (int base = 0; base < deg; base += 64) {
        int idx = base + lane;
        float4 p = {0.f, 0.f, 0.f, 0.f};
        int s = 0;
        if (idx < deg) {
            s = col_src[rs + idx];
            float4 v = a4s[s];
            p.x = fexp(lrelu(v.x + ad.x));
            p.y = fexp(lrelu(v.y + ad.y));
            p.z = fexp(lrelu(v.z + ad.z));
            p.w = fexp(lrelu(v.w + ad.w));
        }
        if (idx < CAP) { sp[wslot][idx] = p; ssrc[wslot][idx] = s; }
        px += p.x; py += p.y; pz += p.z; pw += p.w;
    }
#pragma unroll
    for (int off = 32; off > 0; off >>= 1) {
        px += __shfl_xor(px, off, 64);
        py += __shfl_xor(py, off, 64);
        pz += __shfl_xor(pz, off, 64);
        pw += __shfl_xor(pw, off, 64);
    }
    const float ivx = 0.25f * __builtin_amdgcn_rcpf(px);
    const float ivy = 0.25f * __builtin_amdgcn_rcpf(py);
    const float ivz = 0.25f * __builtin_amdgcn_rcpf(pz);
    const float ivw = 0.25f * __builtin_amdgcn_rcpf(pw);

    // ---- Phase B: feature-parallel x gather (scalar, 4-deep) ----
    float a0 = 0.f, a1 = 0.f, a2 = 0.f, a3 = 0.f;
    const int lim = deg < CAP ? deg : CAP;
    int e = 0;
    for (; e + 4 <= lim; e += 4) {
        float4 p0 = sp[wslot][e + 0], p1 = sp[wslot][e + 1];
        float4 p2 = sp[wslot][e + 2], p3 = sp[wslot][e + 3];
        int s0 = ssrc[wslot][e + 0], s1 = ssrc[wslot][e + 1];
        int s2 = ssrc[wslot][e + 2], s3 = ssrc[wslot][e + 3];
        float x0 = x[(size_t)s0 * 64 + lane];
        float x1 = x[(size_t)s1 * 64 + lane];
        float x2 = x[(size_t)s2 * 64 + lane];
        float x3 = x[(size_t)s3 * 64 + lane];
        a0 += p0.x * x0 + p1.x * x1 + p2.x * x2 + p3.x * x3;
        a1 += p0.y * x0 + p1.y * x1 + p2.y * x2 + p3.y * x3;
        a2 += p0.z * x0 + p1.z * x1 + p2.z * x2 + p3.z * x3;
        a3 += p0.w * x0 + p1.w * x1 + p2.w * x2 + p3.w * x3;
    }
    for (; e < lim; ++e) {
        float4 p = sp[wslot][e];
        int s = ssrc[wslot][e];
        float xv = x[(size_t)s * 64 + lane];
        a0 = fmaf(p.x, xv, a0);
        a1 = fmaf(p.y, xv, a1);
        a2 = fmaf(p.z, xv, a2);
        a3 = fmaf(p.w, xv, a3);
    }
    for (; e < deg; ++e) {   // slow path, statistically never taken
        int s = col_src[rs + e];
        float4 v = a4s[s];
        float4 p;
        p.x = fexp(lrelu(v.x + ad.x)); p.y = fexp(lrelu(v.y + ad.y));
        p.z = fexp(lrelu(v.z + ad.z)); p.w = fexp(lrelu(v.w + ad.w));
        float xv = x[(size_t)s * 64 + lane];
        a0 = fmaf(p.x, xv, a0);
        a1 = fmaf(p.y, xv, a1);
        a2 = fmaf(p.z, xv, a2);
        a3 = fmaf(p.w, xv, a3);
    }

    float* op = agg + (size_t)d * 256;
    __builtin_nontemporal_store(a0 * ivx, &op[lane]);
    __builtin_nontemporal_store(a1 * ivy, &op[64 + lane]);
    __builtin_nontemporal_store(a2 * ivz, &op[128 + lane]);
    __builtin_nontemporal_store(a3 * ivw, &op[192 + lane]);
}

// ---------------- host-side GAT layer ----------------
static void gat_layer(float* x /* in/out [N,64] */, const float* W, const float* attS,
                      const float* attD, const float* b, const int* row_ptr, const int* col_src,
                      float* agg, float4* a4s, float4* a4d,
                      float* vs, float* vd, float* B2, hipStream_t stream)
{
    prep_kernel<<<65, 256, 0, stream>>>(W, attS, attD, vs, vd, B2);
    scores_x_kernel<<<(NN + 255) / 256, 256, 0, stream>>>(x, vs, vd, a4s, a4d);
    gat_fused<<<(NN * 64) / 256, 256, 0, stream>>>(row_ptr, col_src, a4s, a4d, x, agg);
    // x_out = relu(agg @ B2 + b)   (0.25 folded into iv)
    gemm_kernel<<<(NN + 63) / 64, 256, 0, stream>>>(agg, B2, b, x, NN, 256, 64, 1);
}

extern "C" void kernel_launch(void* const* d_in, const int* in_sizes, int n_in,
                              void* d_out, int out_size, void* d_ws, size_t ws_size,
                              hipStream_t stream)
{
    const float* obs     = (const float*)d_in[0];
    const int*   ei      = (const int*)d_in[1];
    const float* enc_w1  = (const float*)d_in[2];
    const float* enc_b1  = (const float*)d_in[3];
    const float* enc_w2  = (const float*)d_in[4];
    const float* enc_b2  = (const float*)d_in[5];
    const float* gat1_w  = (const float*)d_in[6];
    const float* gat1_as = (const float*)d_in[7];
    const float* gat1_ad = (const float*)d_in[8];
    const float* gat1_b  = (const float*)d_in[9];
    const float* gat2_w  = (const float*)d_in[10];
    const float* gat2_as = (const float*)d_in[11];
    const float* gat2_ad = (const float*)d_in[12];
    const float* gat2_b  = (const float*)d_in[13];
    const float* dec_w1  = (const float*)d_in[14];
    const float* dec_b1  = (const float*)d_in[15];
    const float* dec_w2  = (const float*)d_in[16];
    const float* dec_b2  = (const float*)d_in[17];

    float* ws = (float*)d_ws;
    float* bufA    = ws;                                   // [N,64]
    float* bufB    = bufA + (size_t)NN * 64;               // [N,64]  (x)
    float* agg     = bufB + (size_t)NN * 64;               // [N,256]
    float4* a4s    = (float4*)(agg + (size_t)NN * 256);    // [N]
    float4* a4d    = a4s + NN;                             // [N]
    int* row_ptr   = (int*)(a4d + NN);                     // [N+1] (+pad)
    int* cnt       = row_ptr + NN + 4;                     // [N]
    int* col_src   = cnt + NN;                             // [ETOT]
    int* partial   = col_src + ETOT;                       // [256]
    int* partial2  = partial + 256;                        // [256]
    float* vs      = (float*)(partial2 + 256);             // [256]
    float* vd      = vs + 256;                             // [256]
    float* B2      = vd + 256;                             // [256*64]
    int* hist      = (int*)(B2 + 256 * 64);                // [NSCAN]
    int* off_bm    = hist + NSCAN;                         // [NSCAN]
    int2* srec     = (int2*)(off_bm + NSCAN);              // [ETOT]

    const int GB = (NN + 63) / 64;
    const int NCHUNK_N = (NN + 511) / 512;        // 196
    const int NCHUNK_S = (NSCAN + 511) / 512;     // 220

    // ---- CSR build via counting sort (once, reused by both GAT layers) ----
    hipMemsetAsync(cnt, 0, (size_t)NN * sizeof(int), stream);
    sort_hist<<<NBLK2, 256, 0, stream>>>(ei, hist, cnt);
    gscan_partial<<<NCHUNK_N, 256, 0, stream>>>(cnt, partial, NN);
    gscan_top<<<1, 256, 0, stream>>>(partial, NCHUNK_N);
    gscan_final<<<NCHUNK_N, 256, 0, stream>>>(cnt, partial, row_ptr, NN);
    set_tail<<<1, 1, 0, stream>>>(row_ptr);
    gscan_partial<<<NCHUNK_S, 256, 0, stream>>>(hist, partial2, NSCAN);
    gscan_top<<<1, 256, 0, stream>>>(partial2, NCHUNK_S);
    gscan_final<<<NCHUNK_S, 256, 0, stream>>>(hist, partial2, off_bm, NSCAN);
    sort_scatter<<<NBLK2, 256, 0, stream>>>(ei, off_bm, srec);
    csr_fill2<<<NGRP, 256, 0, stream>>>(row_ptr, srec, col_src);

    // ---- encoder ----
    gemm_kernel<<<GB, 256, 0, stream>>>(obs, enc_w1, enc_b1, bufA, NN, 128, 64, 1);
    gemm_kernel<<<GB, 256, 0, stream>>>(bufA, enc_w2, enc_b2, bufB, NN, 64, 64, 0);

    // ---- GAT layers (x lives in bufB) ----
    gat_layer(bufB, gat1_w, gat1_as, gat1_ad, gat1_b, row_ptr, col_src, agg, a4s, a4d, vs, vd, B2, stream);
    gat_layer(bufB, gat2_w, gat2_as, gat2_ad, gat2_b, row_ptr, col_src, agg, a4s, a4d, vs, vd, B2, stream);

    // ---- decoder ----
    gemm_kernel<<<GB, 256, 0, stream>>>(bufB, dec_w1, dec_b1, bufA, NN, 64, 64, 1);
    gemm_kernel<<<GB, 256, 0, stream>>>(bufA, dec_w2, dec_b2, (float*)d_out, NN, 64, 32, 0);
}

// Round 23
// 414.429 us; speedup vs baseline: 1.0309x; 1.0007x over previous
//
#include <hip/hip_runtime.h>
#include <math.h>

#define NN 100000
#define EE 800000
#define ETOT (EE + NN)
#define CAP 128
#define NBLK2 440            // sort blocks
#define EPB 2048             // edges per sort block (440*2048 >= ETOT)
#define NBUCK 256            // histogram buckets; bucket = d>>9 (<=195)
#define NSCAN (NBUCK * NBLK2)
#define NGRP ((NN + 511) >> 9)   // 196 dst-groups of 512
// HID=64, HEADS=4, OBS=128, ACT=32

// ---------------- GEMM: C[M,Nc] = A[M,K] @ B[K,Nc] (+bias, optional relu) ----------------
// R19 BK=16 2-phase register pipeline (best measured). R22: optional fused score
// epilogue — when vsc!=null, computes a4s/a4d = (C-row)·vs/vd in-register (BN=64=full
// row per block; 16 same-row lanes reduce via shfl_xor), eliminating the scores_x
// kernel's 25.6MB re-read of the just-written x.
__global__ __launch_bounds__(256) void gemm_kernel(
    const float* __restrict__ A, const float* __restrict__ B,
    const float* __restrict__ bias, float* __restrict__ C,
    int M, int K, int Nc, int doRelu,
    const float* __restrict__ vsc, const float* __restrict__ vdc,
    float4* __restrict__ oas, float4* __restrict__ oad)
{
    __shared__ __align__(16) float sA[16 * 68];  // [k][row 0..63]
    __shared__ __align__(16) float sB[16 * 68];  // [k][col 0..63]
    __shared__ float svs[256], svd[256];

    const int bm = blockIdx.x * 64;
    const int tid = threadIdx.x;
    const int ty = tid >> 4;
    const int tx = tid & 15;

    const int ar  = tid >> 2;        // A stage row 0..63
    const int ac  = (tid & 3) * 4;   // A stage k-offset (float4)
    const int brw = tid >> 4;        // B stage row 0..15
    const int bc  = (tid & 15) * 4;  // B stage col (float4)
    const int grA = bm + ar;

    if (vsc) { svs[tid] = vsc[tid]; svd[tid] = vdc[tid]; }

    float acc[4][4] = {};
    float4 ra = {0.f, 0.f, 0.f, 0.f}, rb = {0.f, 0.f, 0.f, 0.f};
    const int NT = K >> 4;

    // prologue: load tile 0 into regs
    if (grA < M) ra = *(const float4*)&A[(size_t)grA * K + ac];
    if (bc < Nc) rb = *(const float4*)&B[(size_t)brw * Nc + bc];

    for (int t = 0; t < NT; ++t) {
        // write staged regs to LDS (transpose A)
        sA[(ac + 0) * 68 + ar] = ra.x;
        sA[(ac + 1) * 68 + ar] = ra.y;
        sA[(ac + 2) * 68 + ar] = ra.z;
        sA[(ac + 3) * 68 + ar] = ra.w;
        *(float4*)&sB[brw * 68 + bc] = rb;
        __syncthreads();

        // issue next-tile loads (latency hides under the 256-FMA compute below)
        if (t + 1 < NT) {
            const int k0 = (t + 1) << 4;
            ra = make_float4(0.f, 0.f, 0.f, 0.f);
            rb = make_float4(0.f, 0.f, 0.f, 0.f);
            if (grA < M) ra = *(const float4*)&A[(size_t)grA * K + k0 + ac];
            if (bc < Nc) rb = *(const float4*)&B[(size_t)(k0 + brw) * Nc + bc];
        }

#pragma unroll
        for (int k = 0; k < 16; ++k) {
            float4 a0 = *(const float4*)&sA[k * 68 + ty * 4];
            float4 b0 = *(const float4*)&sB[k * 68 + tx * 4];
            float a[4] = {a0.x, a0.y, a0.z, a0.w};
            float b[4] = {b0.x, b0.y, b0.z, b0.w};
#pragma unroll
            for (int i = 0; i < 4; ++i)
#pragma unroll
                for (int j = 0; j < 4; ++j)
                    acc[i][j] = fmaf(a[i], b[j], acc[i][j]);
        }
        __syncthreads();
    }

    const int gc = tx * 4;
    float bv[4] = {0.f, 0.f, 0.f, 0.f};
    if (bias && gc < Nc) {
        bv[0] = bias[gc + 0]; bv[1] = bias[gc + 1];
        bv[2] = bias[gc + 2]; bv[3] = bias[gc + 3];
    }
    float vv[4][4];
#pragma unroll
    for (int i = 0; i < 4; ++i)
#pragma unroll
        for (int j = 0; j < 4; ++j) {
            float v = acc[i][j] + bv[j];
            vv[i][j] = doRelu ? fmaxf(v, 0.f) : v;
        }
    if (gc < Nc) {
#pragma unroll
        for (int i = 0; i < 4; ++i) {
            int gr = bm + ty * 4 + i;
            if (gr >= M) continue;
            float4 v = {vv[i][0], vv[i][1], vv[i][2], vv[i][3]};
            *(float4*)&C[(size_t)gr * Nc + gc] = v;
        }
    }

    // ---- fused score epilogue (Nc==64 call sites only) ----
    if (vsc) {
        float cs[4][4], cd[4][4];
#pragma unroll
        for (int j = 0; j < 4; ++j)
#pragma unroll
            for (int h = 0; h < 4; ++h) {
                cs[j][h] = svs[(gc + j) * 4 + h];
                cd[j][h] = svd[(gc + j) * 4 + h];
            }
#pragma unroll
        for (int i = 0; i < 4; ++i) {
            float ps[4] = {0.f, 0.f, 0.f, 0.f};
            float pd[4] = {0.f, 0.f, 0.f, 0.f};
#pragma unroll
            for (int j = 0; j < 4; ++j)
#pragma unroll
                for (int h = 0; h < 4; ++h) {
                    ps[h] = fmaf(vv[i][j], cs[j][h], ps[h]);
                    pd[h] = fmaf(vv[i][j], cd[j][h], pd[h]);
                }
            // reduce across the 16 same-row lanes (tx = lane bits 0..3)
#pragma unroll
            for (int off = 1; off < 16; off <<= 1) {
#pragma unroll
                for (int h = 0; h < 4; ++h) {
                    ps[h] += __shfl_xor(ps[h], off, 64);
                    pd[h] += __shfl_xor(pd[h], off, 64);
                }
            }
            if (tx == 0) {
                int gr = bm + ty * 4 + i;
                if (gr < M) {
                    float4 s4 = {ps[0], ps[1], ps[2], ps[3]};
                    float4 d4 = {pd[0], pd[1], pd[2], pd[3]};
                    oas[gr] = s4;
                    oad[gr] = d4;
                }
            }
        }
    }
}

__device__ __forceinline__ float lrelu(float x) { return fmaxf(x, 0.2f * x); }
__device__ __forceinline__ float fexp(float x) { return __expf(x); }  // v_exp_f32 path
__device__ __forceinline__ int edge_src(const int* ei, int e) { return e < EE ? ei[e] : e - EE; }
__device__ __forceinline__ int edge_dst(const int* ei, int e) { return e < EE ? ei[EE + e] : e - EE; }

// ================= generic 3-kernel exclusive scan (n <= 131072) =================
__global__ __launch_bounds__(256) void gscan_partial(const int* __restrict__ in, int* __restrict__ partial, int n)
{
    __shared__ int s[256];
    int b = blockIdx.x;
    int gi = b * 512 + threadIdx.x;
    int v = 0;
    if (gi < n) v += in[gi];
    if (gi + 256 < n) v += in[gi + 256];
    s[threadIdx.x] = v;
    __syncthreads();
    for (int off = 128; off > 0; off >>= 1) {
        if (threadIdx.x < off) s[threadIdx.x] += s[threadIdx.x + off];
        __syncthreads();
    }
    if (threadIdx.x == 0) partial[b] = s[0];
}

__global__ __launch_bounds__(256) void gscan_top(int* __restrict__ partial, int nb)
{
    __shared__ int s[256];
    int tid = threadIdx.x;
    s[tid] = (tid < nb) ? partial[tid] : 0;
    __syncthreads();
    for (int off = 1; off < 256; off <<= 1) {
        int t = (tid >= off) ? s[tid - off] : 0;
        __syncthreads();
        s[tid] += t;
        __syncthreads();
    }
    if (tid < nb) partial[tid] = (tid == 0) ? 0 : s[tid - 1];
}

__global__ __launch_bounds__(256) void gscan_final(
    const int* __restrict__ in, const int* __restrict__ partial, int* __restrict__ out, int n)
{
    __shared__ int s[512];
    int b = blockIdx.x;
    int tid = threadIdx.x;
    int g0 = b * 512 + tid, g1 = b * 512 + tid + 256;
    s[tid]       = (g0 < n) ? in[g0] : 0;
    s[tid + 256] = (g1 < n) ? in[g1] : 0;
    __syncthreads();
#pragma unroll
    for (int d = 0; d < 9; ++d) {
        int stride = 1 << d, nn2 = 256 >> d;
        if (tid < nn2) s[(2 * tid + 2) * stride - 1] += s[(2 * tid + 1) * stride - 1];
        __syncthreads();
    }
    if (tid == 0) s[511] = 0;
    __syncthreads();
#pragma unroll
    for (int d = 8; d >= 0; --d) {
        int stride = 1 << d, nn2 = 256 >> d;
        if (tid < nn2) {
            int i1 = (2 * tid + 1) * stride - 1, i2 = (2 * tid + 2) * stride - 1;
            int t = s[i1];
            s[i1] = s[i2];
            s[i2] += t;
        }
        __syncthreads();
    }
    int off = partial[b];
    if (g0 < n) out[g0] = s[tid] + off;
    if (g1 < n) out[g1] = s[tid + 256] + off;
}

__global__ void set_tail(int* __restrict__ row_ptr)
{
    row_ptr[NN] = ETOT;
}

// ================= counting sort of edges by dst-group =================
__global__ __launch_bounds__(256) void sort_hist(
    const int* __restrict__ ei, int* __restrict__ hist_bm, int* __restrict__ cnt)
{
    __shared__ int h[NBUCK];
    int tid = threadIdx.x, blk = blockIdx.x;
    h[tid] = 0;
    __syncthreads();
#pragma unroll
    for (int it = 0; it < EPB / 256; ++it) {
        int e = blk * EPB + it * 256 + tid;
        if (e < ETOT) {
            int d = edge_dst(ei, e);
            atomicAdd(&h[d >> 9], 1);
            atomicAdd(&cnt[d], 1);
        }
    }
    __syncthreads();
    hist_bm[tid * NBLK2 + blk] = h[tid];
}

__global__ __launch_bounds__(256) void sort_scatter(
    const int* __restrict__ ei, const int* __restrict__ off_bm, int2* __restrict__ srec)
{
    __shared__ int cur[NBUCK];
    int tid = threadIdx.x, blk = blockIdx.x;
    cur[tid] = off_bm[tid * NBLK2 + blk];
    __syncthreads();
#pragma unroll
    for (int it = 0; it < EPB / 256; ++it) {
        int e = blk * EPB + it * 256 + tid;
        if (e < ETOT) {
            int d = edge_dst(ei, e);
            int s = edge_src(ei, e);
            int pos = atomicAdd(&cur[d >> 9], 1);
            srec[pos] = make_int2(s, d);
        }
    }
}

__global__ __launch_bounds__(256) void csr_fill2(
    const int* __restrict__ row_ptr, const int2* __restrict__ srec, int* __restrict__ col_src)
{
    __shared__ int cur[512];
    int g = blockIdx.x, tid = threadIdx.x;
    int n0 = g << 9;
    for (int i = tid; i < 512; i += 256) {
        int nd = n0 + i;
        cur[i] = (nd < NN) ? row_ptr[nd] : 0;
    }
    __syncthreads();
    int lo = row_ptr[n0];
    int hi = (n0 + 512 <= NN) ? row_ptr[n0 + 512] : ETOT;
    for (int idx = lo + tid; idx < hi; idx += 256) {
        int2 r = srec[idx];
        int pos = atomicAdd(&cur[r.y - n0], 1);
        col_src[pos] = r.x;
    }
}

// ================= per-layer weight precomputes (att_vec + permW fused) =================
__global__ __launch_bounds__(256) void prep_kernel(
    const float* __restrict__ W, const float* __restrict__ attS,
    const float* __restrict__ attD, float* __restrict__ vs, float* __restrict__ vd,
    float* __restrict__ B2)
{
    int tid = threadIdx.x;
    if (blockIdx.x == 64) {
        int k = tid >> 2, h = tid & 3;
        const float* wr = W + (size_t)k * 256 + h * 64;
        const float* as = attS + h * 64;
        const float* ad = attD + h * 64;
        float ss = 0.f, sd = 0.f;
#pragma unroll
        for (int j = 0; j < 64; ++j) {
            float wv = wr[j];
            ss += wv * as[j];
            sd += wv * ad[j];
        }
        vs[tid] = ss;
        vd[tid] = sd;
    } else {
        int i = blockIdx.x * 256 + tid;   // i = r*64+j, r = h*64+k
        int r = i >> 6, j = i & 63;
        int h = r >> 6, k = r & 63;
        B2[i] = W[(size_t)k * 256 + h * 64 + j];
    }
}

// ================= fused softmax + gather aggregation (wave per dst) =================
__global__ __launch_bounds__(256) void gat_fused(
    const int* __restrict__ row_ptr, const int* __restrict__ col_src,
    const float4* __restrict__ a4s, const float4* __restrict__ a4d,
    const float* __restrict__ x, float* __restrict__ agg)
{
    __shared__ float4 sp[4][CAP];
    __shared__ int    ssrc[4][CAP];
    const int wslot = threadIdx.x >> 6;
    const int lane = threadIdx.x & 63;
    const int d = (blockIdx.x * 256 + threadIdx.x) >> 6;   // grid sized so d < NN always

    const int rs = row_ptr[d];
    const int deg = row_ptr[d + 1] - rs;
    const float4 ad = a4d[d];

    // ---- Phase A: edge-parallel p + head sums ----
    float px = 0.f, py = 0.f, pz = 0.f, pw = 0.f;
    for (int base = 0; base < deg; base += 64) {
        int idx = base + lane;
        float4 p = {0.f, 0.f, 0.f, 0.f};
        int s = 0;
        if (idx < deg) {
            s = col_src[rs + idx];
            float4 v = a4s[s];
            p.x = fexp(lrelu(v.x + ad.x));
            p.y = fexp(lrelu(v.y + ad.y));
            p.z = fexp(lrelu(v.z + ad.z));
            p.w = fexp(lrelu(v.w + ad.w));
        }
        if (idx < CAP) { sp[wslot][idx] = p; ssrc[wslot][idx] = s; }
        px += p.x; py += p.y; pz += p.z; pw += p.w;
    }
#pragma unroll
    for (int off = 32; off > 0; off >>= 1) {
        px += __shfl_xor(px, off, 64);
        py += __shfl_xor(py, off, 64);
        pz += __shfl_xor(pz, off, 64);
        pw += __shfl_xor(pw, off, 64);
    }
    const float ivx = 0.25f * __builtin_amdgcn_rcpf(px);
    const float ivy = 0.25f * __builtin_amdgcn_rcpf(py);
    const float ivz = 0.25f * __builtin_amdgcn_rcpf(pz);
    const float ivw = 0.25f * __builtin_amdgcn_rcpf(pw);

    // ---- Phase B: feature-parallel x gather (scalar, 4-deep) ----
    float a0 = 0.f, a1 = 0.f, a2 = 0.f, a3 = 0.f;
    const int lim = deg < CAP ? deg : CAP;
    int e = 0;
    for (; e + 4 <= lim; e += 4) {
        float4 p0 = sp[wslot][e + 0], p1 = sp[wslot][e + 1];
        float4 p2 = sp[wslot][e + 2], p3 = sp[wslot][e + 3];
        int s0 = ssrc[wslot][e + 0], s1 = ssrc[wslot][e + 1];
        int s2 = ssrc[wslot][e + 2], s3 = ssrc[wslot][e + 3];
        float x0 = x[(size_t)s0 * 64 + lane];
        float x1 = x[(size_t)s1 * 64 + lane];
        float x2 = x[(size_t)s2 * 64 + lane];
        float x3 = x[(size_t)s3 * 64 + lane];
        a0 += p0.x * x0 + p1.x * x1 + p2.x * x2 + p3.x * x3;
        a1 += p0.y * x0 + p1.y * x1 + p2.y * x2 + p3.y * x3;
        a2 += p0.z * x0 + p1.z * x1 + p2.z * x2 + p3.z * x3;
        a3 += p0.w * x0 + p1.w * x1 + p2.w * x2 + p3.w * x3;
    }
    for (; e < lim; ++e) {
        float4 p = sp[wslot][e];
        int s = ssrc[wslot][e];
        float xv = x[(size_t)s * 64 + lane];
        a0 = fmaf(p.x, xv, a0);
        a1 = fmaf(p.y, xv, a1);
        a2 = fmaf(p.z, xv, a2);
        a3 = fmaf(p.w, xv, a3);
    }
    for (; e < deg; ++e) {   // slow path, statistically never taken
        int s = col_src[rs + e];
        float4 v = a4s[s];
        float4 p;
        p.x = fexp(lrelu(v.x + ad.x)); p.y = fexp(lrelu(v.y + ad.y));
        p.z = fexp(lrelu(v.z + ad.z)); p.w = fexp(lrelu(v.w + ad.w));
        float xv = x[(size_t)s * 64 + lane];
        a0 = fmaf(p.x, xv, a0);
        a1 = fmaf(p.y, xv, a1);
        a2 = fmaf(p.z, xv, a2);
        a3 = fmaf(p.w, xv, a3);
    }

    float* op = agg + (size_t)d * 256;
    __builtin_nontemporal_store(a0 * ivx, &op[lane]);
    __builtin_nontemporal_store(a1 * ivy, &op[64 + lane]);
    __builtin_nontemporal_store(a2 * ivz, &op[128 + lane]);
    __builtin_nontemporal_store(a3 * ivw, &op[192 + lane]);
}

extern "C" void kernel_launch(void* const* d_in, const int* in_sizes, int n_in,
                              void* d_out, int out_size, void* d_ws, size_t ws_size,
                              hipStream_t stream)
{
    const float* obs     = (const float*)d_in[0];
    const int*   ei      = (const int*)d_in[1];
    const float* enc_w1  = (const float*)d_in[2];
    const float* enc_b1  = (const float*)d_in[3];
    const float* enc_w2  = (const float*)d_in[4];
    const float* enc_b2  = (const float*)d_in[5];
    const float* gat1_w  = (const float*)d_in[6];
    const float* gat1_as = (const float*)d_in[7];
    const float* gat1_ad = (const float*)d_in[8];
    const float* gat1_b  = (const float*)d_in[9];
    const float* gat2_w  = (const float*)d_in[10];
    const float* gat2_as = (const float*)d_in[11];
    const float* gat2_ad = (const float*)d_in[12];
    const float* gat2_b  = (const float*)d_in[13];
    const float* dec_w1  = (const float*)d_in[14];
    const float* dec_b1  = (const float*)d_in[15];
    const float* dec_w2  = (const float*)d_in[16];
    const float* dec_b2  = (const float*)d_in[17];

    float* ws = (float*)d_ws;
    float* bufA    = ws;                                   // [N,64]
    float* bufB    = bufA + (size_t)NN * 64;               // [N,64]  (x)
    float* agg     = bufB + (size_t)NN * 64;               // [N,256]
    float4* a4s    = (float4*)(agg + (size_t)NN * 256);    // [N]
    float4* a4d    = a4s + NN;                             // [N]
    int* row_ptr   = (int*)(a4d + NN);                     // [N+1] (+pad)
    int* cnt       = row_ptr + NN + 4;                     // [N]
    int* col_src   = cnt + NN;                             // [ETOT]
    int* partial   = col_src + ETOT;                       // [256]
    int* partial2  = partial + 256;                        // [256]
    float* vs1     = (float*)(partial2 + 256);             // [256]
    float* vd1     = vs1 + 256;                            // [256]
    float* vs2     = vd1 + 256;                            // [256]
    float* vd2     = vs2 + 256;                            // [256]
    float* B2a     = vd2 + 256;                            // [256*64]
    float* B2b     = B2a + 256 * 64;                       // [256*64]
    int* hist      = (int*)(B2b + 256 * 64);               // [NSCAN]
    int* off_bm    = hist + NSCAN;                         // [NSCAN]
    int2* srec     = (int2*)(off_bm + NSCAN);              // [ETOT]

    const int GB = (NN + 63) / 64;
    const int NCHUNK_N = (NN + 511) / 512;        // 196
    const int NCHUNK_S = (NSCAN + 511) / 512;     // 220

    // ---- CSR build via counting sort (once, reused by both GAT layers) ----
    hipMemsetAsync(cnt, 0, (size_t)NN * sizeof(int), stream);
    sort_hist<<<NBLK2, 256, 0, stream>>>(ei, hist, cnt);
    gscan_partial<<<NCHUNK_N, 256, 0, stream>>>(cnt, partial, NN);
    gscan_top<<<1, 256, 0, stream>>>(partial, NCHUNK_N);
    gscan_final<<<NCHUNK_N, 256, 0, stream>>>(cnt, partial, row_ptr, NN);
    set_tail<<<1, 1, 0, stream>>>(row_ptr);
    gscan_partial<<<NCHUNK_S, 256, 0, stream>>>(hist, partial2, NSCAN);
    gscan_top<<<1, 256, 0, stream>>>(partial2, NCHUNK_S);
    gscan_final<<<NCHUNK_S, 256, 0, stream>>>(hist, partial2, off_bm, NSCAN);
    sort_scatter<<<NBLK2, 256, 0, stream>>>(ei, off_bm, srec);
    csr_fill2<<<NGRP, 256, 0, stream>>>(row_ptr, srec, col_src);

    // ---- per-layer weight precomputes (hoisted) ----
    prep_kernel<<<65, 256, 0, stream>>>(gat1_w, gat1_as, gat1_ad, vs1, vd1, B2a);
    prep_kernel<<<65, 256, 0, stream>>>(gat2_w, gat2_as, gat2_ad, vs2, vd2, B2b);

    // ---- encoder (GEMM2 fused with layer-1 scores) ----
    gemm_kernel<<<GB, 256, 0, stream>>>(obs, enc_w1, enc_b1, bufA, NN, 128, 64, 1,
                                        nullptr, nullptr, nullptr, nullptr);
    gemm_kernel<<<GB, 256, 0, stream>>>(bufA, enc_w2, enc_b2, bufB, NN, 64, 64, 0,
                                        vs1, vd1, a4s, a4d);

    // ---- GAT layer 1 (recombine fused with layer-2 scores) ----
    gat_fused<<<(NN * 64) / 256, 256, 0, stream>>>(row_ptr, col_src, a4s, a4d, bufB, agg);
    gemm_kernel<<<GB, 256, 0, stream>>>(agg, B2a, gat1_b, bufB, NN, 256, 64, 1,
                                        vs2, vd2, a4s, a4d);

    // ---- GAT layer 2 ----
    gat_fused<<<(NN * 64) / 256, 256, 0, stream>>>(row_ptr, col_src, a4s, a4d, bufB, agg);
    gemm_kernel<<<GB, 256, 0, stream>>>(agg, B2b, gat2_b, bufB, NN, 256, 64, 1,
                                        nullptr, nullptr, nullptr, nullptr);

    // ---- decoder ----
    gemm_kernel<<<GB, 256, 0, stream>>>(bufB, dec_w1, dec_b1, bufA, NN, 64, 64, 1,
                                        nullptr, nullptr, nullptr, nullptr);
    gemm_kernel<<<GB, 256, 0, stream>>>(bufA, dec_w2, dec_b2, (float*)d_out, NN, 64, 32, 0,
                                        nullptr, nullptr, nullptr, nullptr);
}

// Round 24
// 373.820 us; speedup vs baseline: 1.1429x; 1.1086x over previous
//
#include <hip/hip_runtime.h>
#include <math.h>

#define NN 100000
#define EE 800000
#define ETOT (EE + NN)
#define CAP 128
#define NBLK2 440            // sort blocks
#define EPB 2048             // edges per sort block (440*2048 >= ETOT)
#define NBUCK 256            // histogram buckets; bucket = d>>9 (<=195)
#define NSCAN (NBUCK * NBLK2)
#define NGRP ((NN + 511) >> 9)   // 196 dst-groups of 512
// HID=64, HEADS=4, OBS=128, ACT=32

typedef __attribute__((ext_vector_type(8))) short s8v;
typedef __attribute__((ext_vector_type(4))) float f4v;
typedef unsigned short u16;
typedef unsigned int   u32;

// ---------------- GEMM (vector fp32): R19 BK=16 2-phase pipeline + optional score epilogue ----------------
__global__ __launch_bounds__(256) void gemm_kernel(
    const float* __restrict__ A, const float* __restrict__ B,
    const float* __restrict__ bias, float* __restrict__ C,
    int M, int K, int Nc, int doRelu,
    const float* __restrict__ vsc, const float* __restrict__ vdc,
    float4* __restrict__ oas, float4* __restrict__ oad)
{
    __shared__ __align__(16) float sA[16 * 68];
    __shared__ __align__(16) float sB[16 * 68];
    __shared__ float svs[256], svd[256];

    const int bm = blockIdx.x * 64;
    const int tid = threadIdx.x;
    const int ty = tid >> 4;
    const int tx = tid & 15;

    const int ar  = tid >> 2;
    const int ac  = (tid & 3) * 4;
    const int brw = tid >> 4;
    const int bc  = (tid & 15) * 4;
    const int grA = bm + ar;

    if (vsc) { svs[tid] = vsc[tid]; svd[tid] = vdc[tid]; }

    float acc[4][4] = {};
    float4 ra = {0.f, 0.f, 0.f, 0.f}, rb = {0.f, 0.f, 0.f, 0.f};
    const int NT = K >> 4;

    if (grA < M) ra = *(const float4*)&A[(size_t)grA * K + ac];
    if (bc < Nc) rb = *(const float4*)&B[(size_t)brw * Nc + bc];

    for (int t = 0; t < NT; ++t) {
        sA[(ac + 0) * 68 + ar] = ra.x;
        sA[(ac + 1) * 68 + ar] = ra.y;
        sA[(ac + 2) * 68 + ar] = ra.z;
        sA[(ac + 3) * 68 + ar] = ra.w;
        *(float4*)&sB[brw * 68 + bc] = rb;
        __syncthreads();

        if (t + 1 < NT) {
            const int k0 = (t + 1) << 4;
            ra = make_float4(0.f, 0.f, 0.f, 0.f);
            rb = make_float4(0.f, 0.f, 0.f, 0.f);
            if (grA < M) ra = *(const float4*)&A[(size_t)grA * K + k0 + ac];
            if (bc < Nc) rb = *(const float4*)&B[(size_t)(k0 + brw) * Nc + bc];
        }

#pragma unroll
        for (int k = 0; k < 16; ++k) {
            float4 a0 = *(const float4*)&sA[k * 68 + ty * 4];
            float4 b0 = *(const float4*)&sB[k * 68 + tx * 4];
            float a[4] = {a0.x, a0.y, a0.z, a0.w};
            float b[4] = {b0.x, b0.y, b0.z, b0.w};
#pragma unroll
            for (int i = 0; i < 4; ++i)
#pragma unroll
                for (int j = 0; j < 4; ++j)
                    acc[i][j] = fmaf(a[i], b[j], acc[i][j]);
        }
        __syncthreads();
    }

    const int gc = tx * 4;
    float bv[4] = {0.f, 0.f, 0.f, 0.f};
    if (bias && gc < Nc) {
        bv[0] = bias[gc + 0]; bv[1] = bias[gc + 1];
        bv[2] = bias[gc + 2]; bv[3] = bias[gc + 3];
    }
    float vv[4][4];
#pragma unroll
    for (int i = 0; i < 4; ++i)
#pragma unroll
        for (int j = 0; j < 4; ++j) {
            float v = acc[i][j] + bv[j];
            vv[i][j] = doRelu ? fmaxf(v, 0.f) : v;
        }
    if (gc < Nc) {
#pragma unroll
        for (int i = 0; i < 4; ++i) {
            int gr = bm + ty * 4 + i;
            if (gr >= M) continue;
            float4 v = {vv[i][0], vv[i][1], vv[i][2], vv[i][3]};
            *(float4*)&C[(size_t)gr * Nc + gc] = v;
        }
    }

    if (vsc) {
        float cs[4][4], cd[4][4];
#pragma unroll
        for (int j = 0; j < 4; ++j)
#pragma unroll
            for (int h = 0; h < 4; ++h) {
                cs[j][h] = svs[(gc + j) * 4 + h];
                cd[j][h] = svd[(gc + j) * 4 + h];
            }
#pragma unroll
        for (int i = 0; i < 4; ++i) {
            float ps[4] = {0.f, 0.f, 0.f, 0.f};
            float pd[4] = {0.f, 0.f, 0.f, 0.f};
#pragma unroll
            for (int j = 0; j < 4; ++j)
#pragma unroll
                for (int h = 0; h < 4; ++h) {
                    ps[h] = fmaf(vv[i][j], cs[j][h], ps[h]);
                    pd[h] = fmaf(vv[i][j], cd[j][h], pd[h]);
                }
#pragma unroll
            for (int off = 1; off < 16; off <<= 1) {
#pragma unroll
                for (int h = 0; h < 4; ++h) {
                    ps[h] += __shfl_xor(ps[h], off, 64);
                    pd[h] += __shfl_xor(pd[h], off, 64);
                }
            }
            if (tx == 0) {
                int gr = bm + ty * 4 + i;
                if (gr < M) {
                    float4 s4 = {ps[0], ps[1], ps[2], ps[3]};
                    float4 d4 = {pd[0], pd[1], pd[2], pd[3]};
                    oas[gr] = s4;
                    oad[gr] = d4;
                }
            }
        }
    }
}

// ---------------- MFMA bf16-split recombine GEMM: C[M,64] = relu(A[M,256] @ Bp + bias) ----------------
// a*b ~= ah*bh + ah*bl + al*bh (error ~2^-16 |a||b|, fp32 MFMA accumulation).
// Bp pre-permuted frag-order: Bp[(k>>3)*512 + c*8 + (k&7)]. A converted on-the-fly in LDS.
// mfma_f32_16x16x32_bf16: A row=lane&15, k=(lane>>4)*8+e; B col=lane&15, k=(lane>>4)*8+e;
// D col=lane&15, row=(lane>>4)*4+reg (HW-verified per guide).
__global__ __launch_bounds__(256) void mfma_gemm(
    const float* __restrict__ A, const u16* __restrict__ Bph,
    const u16* __restrict__ Bpl, const float* __restrict__ bias,
    float* __restrict__ C, int M,
    const float* __restrict__ vsc, const float* __restrict__ vdc,
    float4* __restrict__ oas, float4* __restrict__ oad)
{
    __shared__ __align__(16) u16 aHi[64 * 40];   // [row][k], stride 40 (80B: 16B-aligned, ~2-way banks)
    __shared__ __align__(16) u16 aLo[64 * 40];
    __shared__ float svs[256], svd[256];

    const int tid = threadIdx.x;
    const int bm = blockIdx.x * 64;
    const int w = tid >> 6;          // wave 0..3 -> rows 16w..16w+15
    const int l = tid & 63;

    if (vsc) { svs[tid] = vsc[tid]; svd[tid] = vdc[tid]; }

    // staging: thread -> row=tid>>2, k-offset=(tid&3)*8 (8 floats)
    const int srow = tid >> 2;
    const int sks  = (tid & 3) * 8;
    const int gr   = bm + srow;
    const bool sval = gr < M;

    f4v acc[4];
#pragma unroll
    for (int cb = 0; cb < 4; ++cb) { acc[cb][0] = 0.f; acc[cb][1] = 0.f; acc[cb][2] = 0.f; acc[cb][3] = 0.f; }

    float4 r0 = {0.f,0.f,0.f,0.f}, r1 = {0.f,0.f,0.f,0.f};
    if (sval) {
        r0 = *(const float4*)&A[(size_t)gr * 256 + sks];
        r1 = *(const float4*)&A[(size_t)gr * 256 + sks + 4];
    }

    const int arow = 16 * w + (l & 15);
    const int akb8 = (l >> 4) * 8;
    const int bcol8 = (l & 15) * 8;

    for (int t = 0; t < 8; ++t) {
        // convert staged regs -> hi/lo bf16, write LDS
        float vals[8] = {r0.x, r0.y, r0.z, r0.w, r1.x, r1.y, r1.z, r1.w};
        s8v hv, lv;
#pragma unroll
        for (int e = 0; e < 8; ++e) {
            u32 u = __float_as_uint(vals[e]);
            u16 h = (u16)(u >> 16);
            float hf = __uint_as_float(u & 0xFFFF0000u);
            float lr = vals[e] - hf;
            u16 lo = (u16)(__float_as_uint(lr) >> 16);
            hv[e] = (short)h;
            lv[e] = (short)lo;
        }
        *(s8v*)&aHi[srow * 40 + sks] = hv;
        *(s8v*)&aLo[srow * 40 + sks] = lv;
        __syncthreads();

        // issue next K-step loads (hide under MFMA)
        if (t + 1 < 8) {
            const int k0 = (t + 1) * 32;
            r0 = make_float4(0.f, 0.f, 0.f, 0.f);
            r1 = make_float4(0.f, 0.f, 0.f, 0.f);
            if (sval) {
                r0 = *(const float4*)&A[(size_t)gr * 256 + k0 + sks];
                r1 = *(const float4*)&A[(size_t)gr * 256 + k0 + sks + 4];
            }
        }

        // frags + MFMA
        s8v ah = *(const s8v*)&aHi[arow * 40 + akb8];
        s8v al = *(const s8v*)&aLo[arow * 40 + akb8];
        const int bkb = 4 * t + (l >> 4);
#pragma unroll
        for (int cb = 0; cb < 4; ++cb) {
            int bidx = bkb * 512 + cb * 128 + bcol8;
            s8v bh = *(const s8v*)&Bph[bidx];
            s8v bl = *(const s8v*)&Bpl[bidx];
            acc[cb] = __builtin_amdgcn_mfma_f32_16x16x32_bf16(ah, bh, acc[cb], 0, 0, 0);
            acc[cb] = __builtin_amdgcn_mfma_f32_16x16x32_bf16(ah, bl, acc[cb], 0, 0, 0);
            acc[cb] = __builtin_amdgcn_mfma_f32_16x16x32_bf16(al, bh, acc[cb], 0, 0, 0);
        }
        __syncthreads();
    }

    // epilogue: bias + relu + store; D: col = cb*16 + (l&15), row = 16w + (l>>4)*4 + i
    const int ct = l & 15;
    const int cg = l >> 4;
    float val[4][4];
#pragma unroll
    for (int cb = 0; cb < 4; ++cb) {
        float bvv = bias[cb * 16 + ct];
#pragma unroll
        for (int i = 0; i < 4; ++i) {
            float v = fmaxf(acc[cb][i] + bvv, 0.f);
            val[cb][i] = v;
            int row = bm + 16 * w + cg * 4 + i;
            if (row < M) C[(size_t)row * 64 + cb * 16 + ct] = v;
        }
    }

    if (vsc) {
        float cs[4][4], cd[4][4];
#pragma unroll
        for (int cb = 0; cb < 4; ++cb)
#pragma unroll
            for (int h = 0; h < 4; ++h) {
                cs[cb][h] = svs[(cb * 16 + ct) * 4 + h];
                cd[cb][h] = svd[(cb * 16 + ct) * 4 + h];
            }
#pragma unroll
        for (int i = 0; i < 4; ++i) {
            float ps[4] = {0.f, 0.f, 0.f, 0.f};
            float pd[4] = {0.f, 0.f, 0.f, 0.f};
#pragma unroll
            for (int cb = 0; cb < 4; ++cb)
#pragma unroll
                for (int h = 0; h < 4; ++h) {
                    ps[h] = fmaf(val[cb][i], cs[cb][h], ps[h]);
                    pd[h] = fmaf(val[cb][i], cd[cb][h], pd[h]);
                }
#pragma unroll
            for (int off = 1; off < 16; off <<= 1) {
#pragma unroll
                for (int h = 0; h < 4; ++h) {
                    ps[h] += __shfl_xor(ps[h], off, 64);
                    pd[h] += __shfl_xor(pd[h], off, 64);
                }
            }
            if (ct == 0) {
                int row = bm + 16 * w + cg * 4 + i;
                if (row < M) {
                    float4 s4 = {ps[0], ps[1], ps[2], ps[3]};
                    float4 d4 = {pd[0], pd[1], pd[2], pd[3]};
                    oas[row] = s4;
                    oad[row] = d4;
                }
            }
        }
    }
}

__device__ __forceinline__ float lrelu(float x) { return fmaxf(x, 0.2f * x); }
__device__ __forceinline__ float fexp(float x) { return __expf(x); }
__device__ __forceinline__ int edge_src(const int* ei, int e) { return e < EE ? ei[e] : e - EE; }
__device__ __forceinline__ int edge_dst(const int* ei, int e) { return e < EE ? ei[EE + e] : e - EE; }

// ================= generic 3-kernel exclusive scan =================
__global__ __launch_bounds__(256) void gscan_partial(const int* __restrict__ in, int* __restrict__ partial, int n)
{
    __shared__ int s[256];
    int b = blockIdx.x;
    int gi = b * 512 + threadIdx.x;
    int v = 0;
    if (gi < n) v += in[gi];
    if (gi + 256 < n) v += in[gi + 256];
    s[threadIdx.x] = v;
    __syncthreads();
    for (int off = 128; off > 0; off >>= 1) {
        if (threadIdx.x < off) s[threadIdx.x] += s[threadIdx.x + off];
        __syncthreads();
    }
    if (threadIdx.x == 0) partial[b] = s[0];
}

__global__ __launch_bounds__(256) void gscan_top(int* __restrict__ partial, int nb)
{
    __shared__ int s[256];
    int tid = threadIdx.x;
    s[tid] = (tid < nb) ? partial[tid] : 0;
    __syncthreads();
    for (int off = 1; off < 256; off <<= 1) {
        int t = (tid >= off) ? s[tid - off] : 0;
        __syncthreads();
        s[tid] += t;
        __syncthreads();
    }
    if (tid < nb) partial[tid] = (tid == 0) ? 0 : s[tid - 1];
}

__global__ __launch_bounds__(256) void gscan_final(
    const int* __restrict__ in, const int* __restrict__ partial, int* __restrict__ out, int n)
{
    __shared__ int s[512];
    int b = blockIdx.x;
    int tid = threadIdx.x;
    int g0 = b * 512 + tid, g1 = b * 512 + tid + 256;
    s[tid]       = (g0 < n) ? in[g0] : 0;
    s[tid + 256] = (g1 < n) ? in[g1] : 0;
    __syncthreads();
#pragma unroll
    for (int d = 0; d < 9; ++d) {
        int stride = 1 << d, nn2 = 256 >> d;
        if (tid < nn2) s[(2 * tid + 2) * stride - 1] += s[(2 * tid + 1) * stride - 1];
        __syncthreads();
    }
    if (tid == 0) s[511] = 0;
    __syncthreads();
#pragma unroll
    for (int d = 8; d >= 0; --d) {
        int stride = 1 << d, nn2 = 256 >> d;
        if (tid < nn2) {
            int i1 = (2 * tid + 1) * stride - 1, i2 = (2 * tid + 2) * stride - 1;
            int t = s[i1];
            s[i1] = s[i2];
            s[i2] += t;
        }
        __syncthreads();
    }
    int off = partial[b];
    if (g0 < n) out[g0] = s[tid] + off;
    if (g1 < n) out[g1] = s[tid + 256] + off;
}

__global__ void set_tail(int* __restrict__ row_ptr)
{
    row_ptr[NN] = ETOT;
}

// ================= counting sort of edges by dst-group =================
__global__ __launch_bounds__(256) void sort_hist(
    const int* __restrict__ ei, int* __restrict__ hist_bm, int* __restrict__ cnt)
{
    __shared__ int h[NBUCK];
    int tid = threadIdx.x, blk = blockIdx.x;
    h[tid] = 0;
    __syncthreads();
#pragma unroll
    for (int it = 0; it < EPB / 256; ++it) {
        int e = blk * EPB + it * 256 + tid;
        if (e < ETOT) {
            int d = edge_dst(ei, e);
            atomicAdd(&h[d >> 9], 1);
            atomicAdd(&cnt[d], 1);
        }
    }
    __syncthreads();
    hist_bm[tid * NBLK2 + blk] = h[tid];
}

__global__ __launch_bounds__(256) void sort_scatter(
    const int* __restrict__ ei, const int* __restrict__ off_bm, int2* __restrict__ srec)
{
    __shared__ int cur[NBUCK];
    int tid = threadIdx.x, blk = blockIdx.x;
    cur[tid] = off_bm[tid * NBLK2 + blk];
    __syncthreads();
#pragma unroll
    for (int it = 0; it < EPB / 256; ++it) {
        int e = blk * EPB + it * 256 + tid;
        if (e < ETOT) {
            int d = edge_dst(ei, e);
            int s = edge_src(ei, e);
            int pos = atomicAdd(&cur[d >> 9], 1);
            srec[pos] = make_int2(s, d);
        }
    }
}

__global__ __launch_bounds__(256) void csr_fill2(
    const int* __restrict__ row_ptr, const int2* __restrict__ srec, int* __restrict__ col_src)
{
    __shared__ int cur[512];
    int g = blockIdx.x, tid = threadIdx.x;
    int n0 = g << 9;
    for (int i = tid; i < 512; i += 256) {
        int nd = n0 + i;
        cur[i] = (nd < NN) ? row_ptr[nd] : 0;
    }
    __syncthreads();
    int lo = row_ptr[n0];
    int hi = (n0 + 512 <= NN) ? row_ptr[n0 + 512] : ETOT;
    for (int idx = lo + tid; idx < hi; idx += 256) {
        int2 r = srec[idx];
        int pos = atomicAdd(&cur[r.y - n0], 1);
        col_src[pos] = r.x;
    }
}

// ================= per-layer weight precomputes: att vecs + frag-ordered hi/lo B =================
// blocks 0..63: Bp hi/lo from W (B2[r][c] = W[k'*256+h*64+c], r=h*64+k'); block 64: vs/vd.
__global__ __launch_bounds__(256) void prep_kernel(
    const float* __restrict__ W, const float* __restrict__ attS,
    const float* __restrict__ attD, float* __restrict__ vs, float* __restrict__ vd,
    u16* __restrict__ Bph, u16* __restrict__ Bpl)
{
    int tid = threadIdx.x;
    if (blockIdx.x == 64) {
        int k = tid >> 2, h = tid & 3;
        const float* wr = W + (size_t)k * 256 + h * 64;
        const float* as = attS + h * 64;
        const float* ad = attD + h * 64;
        float ss = 0.f, sd = 0.f;
#pragma unroll
        for (int j = 0; j < 64; ++j) {
            float wv = wr[j];
            ss += wv * as[j];
            sd += wv * ad[j];
        }
        vs[tid] = ss;
        vd[tid] = sd;
    } else {
        int i = blockIdx.x * 256 + tid;   // i = r*64+c
        int r = i >> 6, c = i & 63;
        int h = r >> 6, k = r & 63;
        float v = W[(size_t)k * 256 + h * 64 + c];
        u32 u = __float_as_uint(v);
        u16 hb = (u16)(u >> 16);
        float hf = __uint_as_float(u & 0xFFFF0000u);
        u16 lb = (u16)(__float_as_uint(v - hf) >> 16);
        int pos = (r >> 3) * 512 + c * 8 + (r & 7);
        Bph[pos] = hb;
        Bpl[pos] = lb;
    }
}

// ================= fused softmax + gather aggregation (wave per dst) =================
__global__ __launch_bounds__(256) void gat_fused(
    const int* __restrict__ row_ptr, const int* __restrict__ col_src,
    const float4* __restrict__ a4s, const float4* __restrict__ a4d,
    const float* __restrict__ x, float* __restrict__ agg)
{
    __shared__ float4 sp[4][CAP];
    __shared__ int    ssrc[4][CAP];
    const int wslot = threadIdx.x >> 6;
    const int lane = threadIdx.x & 63;
    const int d = (blockIdx.x * 256 + threadIdx.x) >> 6;

    const int rs = row_ptr[d];
    const int deg = row_ptr[d + 1] - rs;
    const float4 ad = a4d[d];

    float px = 0.f, py = 0.f, pz = 0.f, pw = 0.f;
    for (int base = 0; base < deg; base += 64) {
        int idx = base + lane;
        float4 p = {0.f, 0.f, 0.f, 0.f};
        int s = 0;
        if (idx < deg) {
            s = col_src[rs + idx];
            float4 v = a4s[s];
            p.x = fexp(lrelu(v.x + ad.x));
            p.y = fexp(lrelu(v.y + ad.y));
            p.z = fexp(lrelu(v.z + ad.z));
            p.w = fexp(lrelu(v.w + ad.w));
        }
        if (idx < CAP) { sp[wslot][idx] = p; ssrc[wslot][idx] = s; }
        px += p.x; py += p.y; pz += p.z; pw += p.w;
    }
#pragma unroll
    for (int off = 32; off > 0; off >>= 1) {
        px += __shfl_xor(px, off, 64);
        py += __shfl_xor(py, off, 64);
        pz += __shfl_xor(pz, off, 64);
        pw += __shfl_xor(pw, off, 64);
    }
    const float ivx = 0.25f * __builtin_amdgcn_rcpf(px);
    const float ivy = 0.25f * __builtin_amdgcn_rcpf(py);
    const float ivz = 0.25f * __builtin_amdgcn_rcpf(pz);
    const float ivw = 0.25f * __builtin_amdgcn_rcpf(pw);

    float a0 = 0.f, a1 = 0.f, a2 = 0.f, a3 = 0.f;
    const int lim = deg < CAP ? deg : CAP;
    int e = 0;
    for (; e + 4 <= lim; e += 4) {
        float4 p0 = sp[wslot][e + 0], p1 = sp[wslot][e + 1];
        float4 p2 = sp[wslot][e + 2], p3 = sp[wslot][e + 3];
        int s0 = ssrc[wslot][e + 0], s1 = ssrc[wslot][e + 1];
        int s2 = ssrc[wslot][e + 2], s3 = ssrc[wslot][e + 3];
        float x0 = x[(size_t)s0 * 64 + lane];
        float x1 = x[(size_t)s1 * 64 + lane];
        float x2 = x[(size_t)s2 * 64 + lane];
        float x3 = x[(size_t)s3 * 64 + lane];
        a0 += p0.x * x0 + p1.x * x1 + p2.x * x2 + p3.x * x3;
        a1 += p0.y * x0 + p1.y * x1 + p2.y * x2 + p3.y * x3;
        a2 += p0.z * x0 + p1.z * x1 + p2.z * x2 + p3.z * x3;
        a3 += p0.w * x0 + p1.w * x1 + p2.w * x2 + p3.w * x3;
    }
    for (; e < lim; ++e) {
        float4 p = sp[wslot][e];
        int s = ssrc[wslot][e];
        float xv = x[(size_t)s * 64 + lane];
        a0 = fmaf(p.x, xv, a0);
        a1 = fmaf(p.y, xv, a1);
        a2 = fmaf(p.z, xv, a2);
        a3 = fmaf(p.w, xv, a3);
    }
    for (; e < deg; ++e) {
        int s = col_src[rs + e];
        float4 v = a4s[s];
        float4 p;
        p.x = fexp(lrelu(v.x + ad.x)); p.y = fexp(lrelu(v.y + ad.y));
        p.z = fexp(lrelu(v.z + ad.z)); p.w = fexp(lrelu(v.w + ad.w));
        float xv = x[(size_t)s * 64 + lane];
        a0 = fmaf(p.x, xv, a0);
        a1 = fmaf(p.y, xv, a1);
        a2 = fmaf(p.z, xv, a2);
        a3 = fmaf(p.w, xv, a3);
    }

    float* op = agg + (size_t)d * 256;
    __builtin_nontemporal_store(a0 * ivx, &op[lane]);
    __builtin_nontemporal_store(a1 * ivy, &op[64 + lane]);
    __builtin_nontemporal_store(a2 * ivz, &op[128 + lane]);
    __builtin_nontemporal_store(a3 * ivw, &op[192 + lane]);
}

extern "C" void kernel_launch(void* const* d_in, const int* in_sizes, int n_in,
                              void* d_out, int out_size, void* d_ws, size_t ws_size,
                              hipStream_t stream)
{
    const float* obs     = (const float*)d_in[0];
    const int*   ei      = (const int*)d_in[1];
    const float* enc_w1  = (const float*)d_in[2];
    const float* enc_b1  = (const float*)d_in[3];
    const float* enc_w2  = (const float*)d_in[4];
    const float* enc_b2  = (const float*)d_in[5];
    const float* gat1_w  = (const float*)d_in[6];
    const float* gat1_as = (const float*)d_in[7];
    const float* gat1_ad = (const float*)d_in[8];
    const float* gat1_b  = (const float*)d_in[9];
    const float* gat2_w  = (const float*)d_in[10];
    const float* gat2_as = (const float*)d_in[11];
    const float* gat2_ad = (const float*)d_in[12];
    const float* gat2_b  = (const float*)d_in[13];
    const float* dec_w1  = (const float*)d_in[14];
    const float* dec_b1  = (const float*)d_in[15];
    const float* dec_w2  = (const float*)d_in[16];
    const float* dec_b2  = (const float*)d_in[17];

    float* ws = (float*)d_ws;
    float* bufA    = ws;                                   // [N,64]
    float* bufB    = bufA + (size_t)NN * 64;               // [N,64]  (x)
    float* agg     = bufB + (size_t)NN * 64;               // [N,256]
    float4* a4s    = (float4*)(agg + (size_t)NN * 256);    // [N]
    float4* a4d    = a4s + NN;                             // [N]
    int* row_ptr   = (int*)(a4d + NN);                     // [N+1] (+pad)
    int* cnt       = row_ptr + NN + 4;                     // [N]
    int* col_src   = cnt + NN;                             // [ETOT]
    int* partial   = col_src + ETOT;                       // [256]
    int* partial2  = partial + 256;                        // [256]
    float* vs1     = (float*)(partial2 + 256);             // [256]
    float* vd1     = vs1 + 256;                            // [256]
    float* vs2     = vd1 + 256;                            // [256]
    float* vd2     = vs2 + 256;                            // [256]
    float* B2a     = vd2 + 256;                            // 64KB region -> Bp hi/lo layer1
    float* B2b     = B2a + 256 * 64;                       // 64KB region -> Bp hi/lo layer2
    int* hist      = (int*)(B2b + 256 * 64);               // [NSCAN]
    int* off_bm    = hist + NSCAN;                         // [NSCAN]
    int2* srec     = (int2*)(off_bm + NSCAN);              // [ETOT]

    u16* Bph_a = (u16*)B2a;
    u16* Bpl_a = Bph_a + 256 * 64;
    u16* Bph_b = (u16*)B2b;
    u16* Bpl_b = Bph_b + 256 * 64;

    const int GB = (NN + 63) / 64;
    const int NCHUNK_N = (NN + 511) / 512;        // 196
    const int NCHUNK_S = (NSCAN + 511) / 512;     // 220

    // ---- CSR build via counting sort (once, reused by both GAT layers) ----
    hipMemsetAsync(cnt, 0, (size_t)NN * sizeof(int), stream);
    sort_hist<<<NBLK2, 256, 0, stream>>>(ei, hist, cnt);
    gscan_partial<<<NCHUNK_N, 256, 0, stream>>>(cnt, partial, NN);
    gscan_top<<<1, 256, 0, stream>>>(partial, NCHUNK_N);
    gscan_final<<<NCHUNK_N, 256, 0, stream>>>(cnt, partial, row_ptr, NN);
    set_tail<<<1, 1, 0, stream>>>(row_ptr);
    gscan_partial<<<NCHUNK_S, 256, 0, stream>>>(hist, partial2, NSCAN);
    gscan_top<<<1, 256, 0, stream>>>(partial2, NCHUNK_S);
    gscan_final<<<NCHUNK_S, 256, 0, stream>>>(hist, partial2, off_bm, NSCAN);
    sort_scatter<<<NBLK2, 256, 0, stream>>>(ei, off_bm, srec);
    csr_fill2<<<NGRP, 256, 0, stream>>>(row_ptr, srec, col_src);

    // ---- per-layer weight precomputes (hoisted) ----
    prep_kernel<<<65, 256, 0, stream>>>(gat1_w, gat1_as, gat1_ad, vs1, vd1, Bph_a, Bpl_a);
    prep_kernel<<<65, 256, 0, stream>>>(gat2_w, gat2_as, gat2_ad, vs2, vd2, Bph_b, Bpl_b);

    // ---- encoder (GEMM2 fused with layer-1 scores) ----
    gemm_kernel<<<GB, 256, 0, stream>>>(obs, enc_w1, enc_b1, bufA, NN, 128, 64, 1,
                                        nullptr, nullptr, nullptr, nullptr);
    gemm_kernel<<<GB, 256, 0, stream>>>(bufA, enc_w2, enc_b2, bufB, NN, 64, 64, 0,
                                        vs1, vd1, a4s, a4d);

    // ---- GAT layer 1 (MFMA recombine fused with layer-2 scores) ----
    gat_fused<<<(NN * 64) / 256, 256, 0, stream>>>(row_ptr, col_src, a4s, a4d, bufB, agg);
    mfma_gemm<<<GB, 256, 0, stream>>>(agg, Bph_a, Bpl_a, gat1_b, bufB, NN,
                                      vs2, vd2, a4s, a4d);

    // ---- GAT layer 2 (MFMA recombine) ----
    gat_fused<<<(NN * 64) / 256, 256, 0, stream>>>(row_ptr, col_src, a4s, a4d, bufB, agg);
    mfma_gemm<<<GB, 256, 0, stream>>>(agg, Bph_b, Bpl_b, gat2_b, bufB, NN,
                                      nullptr, nullptr, nullptr, nullptr);

    // ---- decoder ----
    gemm_kernel<<<GB, 256, 0, stream>>>(bufB, dec_w1, dec_b1, bufA, NN, 64, 64, 1,
                                        nullptr, nullptr, nullptr, nullptr);
    gemm_kernel<<<GB, 256, 0, stream>>>(bufA, dec_w2, dec_b2, (float*)d_out, NN, 64, 32, 0,
                                        nullptr, nullptr, nullptr, nullptr);
}

// Round 25
// 362.195 us; speedup vs baseline: 1.1796x; 1.0321x over previous
//
#include <hip/hip_runtime.h>
#include <math.h>

#define NN 100000
#define EE 800000
#define ETOT (EE + NN)
#define CAP 128
#define NBLK2 440            // sort blocks
#define EPB 2048             // edges per sort block (440*2048 >= ETOT)
#define NBUCK 256            // histogram buckets; bucket = d>>9 (<=195)
#define NSCAN (NBUCK * NBLK2)
#define NGRP ((NN + 511) >> 9)   // 196 dst-groups of 512
// HID=64, HEADS=4, OBS=128, ACT=32

typedef __attribute__((ext_vector_type(8))) short s8v;
typedef __attribute__((ext_vector_type(4))) float f4v;
typedef unsigned short u16;
typedef unsigned int   u32;

__device__ __forceinline__ void split_bf16(float v, short& h, short& lo)
{
    u32 u = __float_as_uint(v);
    h = (short)(u >> 16);
    float hf = __uint_as_float(u & 0xFFFF0000u);
    lo = (short)(__float_as_uint(v - hf) >> 16);
}

// ---------------- MFMA bf16-split GEMM: C[M,Nc] = act(A[M,K] @ Bp + bias) ----------------
// a*b ~= ah*bh + ah*bl + al*bh (fp32 MFMA accumulation; error ~2^-16 |a||b|).
// Bp frag-order: Bp[((k>>3)*Nc + c)*8 + (k&7)]. A hi/lo-split on the fly via LDS with
// the R19 2-phase register pipeline. NCB = Nc/16 compile-time (static acc indexing).
// mfma_f32_16x16x32_bf16 layouts (HW-verified R24): A row=lane&15,k=(lane>>4)*8+e;
// B col=lane&15,k likewise; D col=lane&15,row=(lane>>4)*4+reg.
template <int NCB>
__global__ __launch_bounds__(256) void mfma_gemm(
    const float* __restrict__ A, const u16* __restrict__ Bph,
    const u16* __restrict__ Bpl, const float* __restrict__ bias,
    float* __restrict__ C, int M, int K, int doRelu,
    const float* __restrict__ vsc, const float* __restrict__ vdc,
    float4* __restrict__ oas, float4* __restrict__ oad)
{
    constexpr int Nc = NCB * 16;
    __shared__ __align__(16) u16 aHi[64 * 40];
    __shared__ __align__(16) u16 aLo[64 * 40];
    __shared__ float svs[256], svd[256];

    const int tid = threadIdx.x;
    const int bm = blockIdx.x * 64;
    const int w = tid >> 6;
    const int l = tid & 63;

    if (vsc) { svs[tid] = vsc[tid]; svd[tid] = vdc[tid]; }

    const int srow = tid >> 2;
    const int sks  = (tid & 3) * 8;
    const int gr   = bm + srow;
    const bool sval = gr < M;
    const int NT = K >> 5;

    f4v acc[NCB];
#pragma unroll
    for (int cb = 0; cb < NCB; ++cb) { acc[cb][0] = 0.f; acc[cb][1] = 0.f; acc[cb][2] = 0.f; acc[cb][3] = 0.f; }

    float4 r0 = {0.f,0.f,0.f,0.f}, r1 = {0.f,0.f,0.f,0.f};
    if (sval) {
        r0 = *(const float4*)&A[(size_t)gr * K + sks];
        r1 = *(const float4*)&A[(size_t)gr * K + sks + 4];
    }

    const int arow = 16 * w + (l & 15);
    const int akb8 = (l >> 4) * 8;
    const int colg = l & 15;

    for (int t = 0; t < NT; ++t) {
        float vals[8] = {r0.x, r0.y, r0.z, r0.w, r1.x, r1.y, r1.z, r1.w};
        s8v hv, lv;
#pragma unroll
        for (int e = 0; e < 8; ++e) { short h, lo; split_bf16(vals[e], h, lo); hv[e] = h; lv[e] = lo; }
        *(s8v*)&aHi[srow * 40 + sks] = hv;
        *(s8v*)&aLo[srow * 40 + sks] = lv;
        __syncthreads();

        if (t + 1 < NT) {
            const int k0 = (t + 1) << 5;
            r0 = make_float4(0.f, 0.f, 0.f, 0.f);
            r1 = make_float4(0.f, 0.f, 0.f, 0.f);
            if (sval) {
                r0 = *(const float4*)&A[(size_t)gr * K + k0 + sks];
                r1 = *(const float4*)&A[(size_t)gr * K + k0 + sks + 4];
            }
        }

        s8v ah = *(const s8v*)&aHi[arow * 40 + akb8];
        s8v al = *(const s8v*)&aLo[arow * 40 + akb8];
        const int bkb = 4 * t + (l >> 4);
#pragma unroll
        for (int cb = 0; cb < NCB; ++cb) {
            int bidx = (bkb * Nc + cb * 16 + colg) * 8;
            s8v bh = *(const s8v*)&Bph[bidx];
            s8v bl = *(const s8v*)&Bpl[bidx];
            acc[cb] = __builtin_amdgcn_mfma_f32_16x16x32_bf16(ah, bh, acc[cb], 0, 0, 0);
            acc[cb] = __builtin_amdgcn_mfma_f32_16x16x32_bf16(ah, bl, acc[cb], 0, 0, 0);
            acc[cb] = __builtin_amdgcn_mfma_f32_16x16x32_bf16(al, bh, acc[cb], 0, 0, 0);
        }
        __syncthreads();
    }

    const int ct = l & 15;
    const int cg = l >> 4;
    float val[NCB][4];
#pragma unroll
    for (int cb = 0; cb < NCB; ++cb) {
        float bvv = bias[cb * 16 + ct];
#pragma unroll
        for (int i = 0; i < 4; ++i) {
            float v = acc[cb][i] + bvv;
            if (doRelu) v = fmaxf(v, 0.f);
            val[cb][i] = v;
            int row = bm + 16 * w + cg * 4 + i;
            if (row < M) C[(size_t)row * Nc + cb * 16 + ct] = v;
        }
    }

    if (vsc) {
        float cs[NCB][4], cd[NCB][4];
#pragma unroll
        for (int cb = 0; cb < NCB; ++cb)
#pragma unroll
            for (int h = 0; h < 4; ++h) {
                cs[cb][h] = svs[(cb * 16 + ct) * 4 + h];
                cd[cb][h] = svd[(cb * 16 + ct) * 4 + h];
            }
#pragma unroll
        for (int i = 0; i < 4; ++i) {
            float ps[4] = {0.f, 0.f, 0.f, 0.f};
            float pd[4] = {0.f, 0.f, 0.f, 0.f};
#pragma unroll
            for (int cb = 0; cb < NCB; ++cb)
#pragma unroll
                for (int h = 0; h < 4; ++h) {
                    ps[h] = fmaf(val[cb][i], cs[cb][h], ps[h]);
                    pd[h] = fmaf(val[cb][i], cd[cb][h], pd[h]);
                }
#pragma unroll
            for (int off = 1; off < 16; off <<= 1) {
#pragma unroll
                for (int h = 0; h < 4; ++h) {
                    ps[h] += __shfl_xor(ps[h], off, 64);
                    pd[h] += __shfl_xor(pd[h], off, 64);
                }
            }
            if (ct == 0) {
                int row = bm + 16 * w + cg * 4 + i;
                if (row < M) {
                    float4 s4 = {ps[0], ps[1], ps[2], ps[3]};
                    float4 d4 = {pd[0], pd[1], pd[2], pd[3]};
                    oas[row] = s4;
                    oad[row] = d4;
                }
            }
        }
    }
}

__device__ __forceinline__ float lrelu(float x) { return fmaxf(x, 0.2f * x); }
__device__ __forceinline__ float fexp(float x) { return __expf(x); }
__device__ __forceinline__ int edge_src(const int* ei, int e) { return e < EE ? ei[e] : e - EE; }
__device__ __forceinline__ int edge_dst(const int* ei, int e) { return e < EE ? ei[EE + e] : e - EE; }

// ================= generic 3-kernel exclusive scan =================
__global__ __launch_bounds__(256) void gscan_partial(const int* __restrict__ in, int* __restrict__ partial, int n)
{
    __shared__ int s[256];
    int b = blockIdx.x;
    int gi = b * 512 + threadIdx.x;
    int v = 0;
    if (gi < n) v += in[gi];
    if (gi + 256 < n) v += in[gi + 256];
    s[threadIdx.x] = v;
    __syncthreads();
    for (int off = 128; off > 0; off >>= 1) {
        if (threadIdx.x < off) s[threadIdx.x] += s[threadIdx.x + off];
        __syncthreads();
    }
    if (threadIdx.x == 0) partial[b] = s[0];
}

__global__ __launch_bounds__(256) void gscan_top(int* __restrict__ partial, int nb)
{
    __shared__ int s[256];
    int tid = threadIdx.x;
    s[tid] = (tid < nb) ? partial[tid] : 0;
    __syncthreads();
    for (int off = 1; off < 256; off <<= 1) {
        int t = (tid >= off) ? s[tid - off] : 0;
        __syncthreads();
        s[tid] += t;
        __syncthreads();
    }
    if (tid < nb) partial[tid] = (tid == 0) ? 0 : s[tid - 1];
}

__global__ __launch_bounds__(256) void gscan_final(
    const int* __restrict__ in, const int* __restrict__ partial, int* __restrict__ out, int n)
{
    __shared__ int s[512];
    int b = blockIdx.x;
    int tid = threadIdx.x;
    int g0 = b * 512 + tid, g1 = b * 512 + tid + 256;
    s[tid]       = (g0 < n) ? in[g0] : 0;
    s[tid + 256] = (g1 < n) ? in[g1] : 0;
    __syncthreads();
#pragma unroll
    for (int d = 0; d < 9; ++d) {
        int stride = 1 << d, nn2 = 256 >> d;
        if (tid < nn2) s[(2 * tid + 2) * stride - 1] += s[(2 * tid + 1) * stride - 1];
        __syncthreads();
    }
    if (tid == 0) s[511] = 0;
    __syncthreads();
#pragma unroll
    for (int d = 8; d >= 0; --d) {
        int stride = 1 << d, nn2 = 256 >> d;
        if (tid < nn2) {
            int i1 = (2 * tid + 1) * stride - 1, i2 = (2 * tid + 2) * stride - 1;
            int t = s[i1];
            s[i1] = s[i2];
            s[i2] += t;
        }
        __syncthreads();
    }
    int off = partial[b];
    if (g0 < n) out[g0] = s[tid] + off;
    if (g1 < n) out[g1] = s[tid + 256] + off;
}

__global__ void set_tail(int* __restrict__ row_ptr)
{
    row_ptr[NN] = ETOT;
}

// ================= counting sort of edges by dst-group =================
__global__ __launch_bounds__(256) void sort_hist(
    const int* __restrict__ ei, int* __restrict__ hist_bm, int* __restrict__ cnt)
{
    __shared__ int h[NBUCK];
    int tid = threadIdx.x, blk = blockIdx.x;
    h[tid] = 0;
    __syncthreads();
#pragma unroll
    for (int it = 0; it < EPB / 256; ++it) {
        int e = blk * EPB + it * 256 + tid;
        if (e < ETOT) {
            int d = edge_dst(ei, e);
            atomicAdd(&h[d >> 9], 1);
            atomicAdd(&cnt[d], 1);
        }
    }
    __syncthreads();
    hist_bm[tid * NBLK2 + blk] = h[tid];
}

__global__ __launch_bounds__(256) void sort_scatter(
    const int* __restrict__ ei, const int* __restrict__ off_bm, int2* __restrict__ srec)
{
    __shared__ int cur[NBUCK];
    int tid = threadIdx.x, blk = blockIdx.x;
    cur[tid] = off_bm[tid * NBLK2 + blk];
    __syncthreads();
#pragma unroll
    for (int it = 0; it < EPB / 256; ++it) {
        int e = blk * EPB + it * 256 + tid;
        if (e < ETOT) {
            int d = edge_dst(ei, e);
            int s = edge_src(ei, e);
            int pos = atomicAdd(&cur[d >> 9], 1);
            srec[pos] = make_int2(s, d);
        }
    }
}

__global__ __launch_bounds__(256) void csr_fill2(
    const int* __restrict__ row_ptr, const int2* __restrict__ srec, int* __restrict__ col_src)
{
    __shared__ int cur[512];
    int g = blockIdx.x, tid = threadIdx.x;
    int n0 = g << 9;
    for (int i = tid; i < 512; i += 256) {
        int nd = n0 + i;
        cur[i] = (nd < NN) ? row_ptr[nd] : 0;
    }
    __syncthreads();
    int lo = row_ptr[n0];
    int hi = (n0 + 512 <= NN) ? row_ptr[n0 + 512] : ETOT;
    for (int idx = lo + tid; idx < hi; idx += 256) {
        int2 r = srec[idx];
        int pos = atomicAdd(&cur[r.y - n0], 1);
        col_src[pos] = r.x;
    }
}

// ================= per-layer precomputes: att vecs + frag-ordered hi/lo recombine B =================
__global__ __launch_bounds__(256) void prep_kernel(
    const float* __restrict__ W, const float* __restrict__ attS,
    const float* __restrict__ attD, float* __restrict__ vs, float* __restrict__ vd,
    u16* __restrict__ Bph, u16* __restrict__ Bpl)
{
    int tid = threadIdx.x;
    if (blockIdx.x == 64) {
        int k = tid >> 2, h = tid & 3;
        const float* wr = W + (size_t)k * 256 + h * 64;
        const float* as = attS + h * 64;
        const float* ad = attD + h * 64;
        float ss = 0.f, sd = 0.f;
#pragma unroll
        for (int j = 0; j < 64; ++j) {
            float wv = wr[j];
            ss += wv * as[j];
            sd += wv * ad[j];
        }
        vs[tid] = ss;
        vd[tid] = sd;
    } else {
        int i = blockIdx.x * 256 + tid;   // i = r*64+c ; r = h*64+k'
        int r = i >> 6, c = i & 63;
        int h = r >> 6, k = r & 63;
        float v = W[(size_t)k * 256 + h * 64 + c];
        short hb, lb;
        split_bf16(v, hb, lb);
        int pos = ((r >> 3) * 64 + c) * 8 + (r & 7);
        Bph[pos] = (u16)hb;
        Bpl[pos] = (u16)lb;
    }
}

// ================= plain weight -> frag-ordered hi/lo (W[K][Nc] row-major) =================
__global__ __launch_bounds__(256) void prep_w(
    const float* __restrict__ W, u16* __restrict__ Bph, u16* __restrict__ Bpl, int K, int Nc)
{
    int i = blockIdx.x * 256 + threadIdx.x;
    if (i >= K * Nc) return;
    int k = i / Nc, c = i - k * Nc;
    short hb, lb;
    split_bf16(W[i], hb, lb);
    int pos = ((k >> 3) * Nc + c) * 8 + (k & 7);
    Bph[pos] = (u16)hb;
    Bpl[pos] = (u16)lb;
}

// ================= fused softmax + gather aggregation (wave per dst) =================
__global__ __launch_bounds__(256) void gat_fused(
    const int* __restrict__ row_ptr, const int* __restrict__ col_src,
    const float4* __restrict__ a4s, const float4* __restrict__ a4d,
    const float* __restrict__ x, float* __restrict__ agg)
{
    __shared__ float4 sp[4][CAP];
    __shared__ int    ssrc[4][CAP];
    const int wslot = threadIdx.x >> 6;
    const int lane = threadIdx.x & 63;
    const int d = (blockIdx.x * 256 + threadIdx.x) >> 6;

    const int rs = row_ptr[d];
    const int deg = row_ptr[d + 1] - rs;
    const float4 ad = a4d[d];

    float px = 0.f, py = 0.f, pz = 0.f, pw = 0.f;
    for (int base = 0; base < deg; base += 64) {
        int idx = base + lane;
        float4 p = {0.f, 0.f, 0.f, 0.f};
        int s = 0;
        if (idx < deg) {
            s = col_src[rs + idx];
            float4 v = a4s[s];
            p.x = fexp(lrelu(v.x + ad.x));
            p.y = fexp(lrelu(v.y + ad.y));
            p.z = fexp(lrelu(v.z + ad.z));
            p.w = fexp(lrelu(v.w + ad.w));
        }
        if (idx < CAP) { sp[wslot][idx] = p; ssrc[wslot][idx] = s; }
        px += p.x; py += p.y; pz += p.z; pw += p.w;
    }
#pragma unroll
    for (int off = 32; off > 0; off >>= 1) {
        px += __shfl_xor(px, off, 64);
        py += __shfl_xor(py, off, 64);
        pz += __shfl_xor(pz, off, 64);
        pw += __shfl_xor(pw, off, 64);
    }
    const float ivx = 0.25f * __builtin_amdgcn_rcpf(px);
    const float ivy = 0.25f * __builtin_amdgcn_rcpf(py);
    const float ivz = 0.25f * __builtin_amdgcn_rcpf(pz);
    const float ivw = 0.25f * __builtin_amdgcn_rcpf(pw);

    float a0 = 0.f, a1 = 0.f, a2 = 0.f, a3 = 0.f;
    const int lim = deg < CAP ? deg : CAP;
    int e = 0;
    for (; e + 4 <= lim; e += 4) {
        float4 p0 = sp[wslot][e + 0], p1 = sp[wslot][e + 1];
        float4 p2 = sp[wslot][e + 2], p3 = sp[wslot][e + 3];
        int s0 = ssrc[wslot][e + 0], s1 = ssrc[wslot][e + 1];
        int s2 = ssrc[wslot][e + 2], s3 = ssrc[wslot][e + 3];
        float x0 = x[(size_t)s0 * 64 + lane];
        float x1 = x[(size_t)s1 * 64 + lane];
        float x2 = x[(size_t)s2 * 64 + lane];
        float x3 = x[(size_t)s3 * 64 + lane];
        a0 += p0.x * x0 + p1.x * x1 + p2.x * x2 + p3.x * x3;
        a1 += p0.y * x0 + p1.y * x1 + p2.y * x2 + p3.y * x3;
        a2 += p0.z * x0 + p1.z * x1 + p2.z * x2 + p3.z * x3;
        a3 += p0.w * x0 + p1.w * x1 + p2.w * x2 + p3.w * x3;
    }
    for (; e < lim; ++e) {
        float4 p = sp[wslot][e];
        int s = ssrc[wslot][e];
        float xv = x[(size_t)s * 64 + lane];
        a0 = fmaf(p.x, xv, a0);
        a1 = fmaf(p.y, xv, a1);
        a2 = fmaf(p.z, xv, a2);
        a3 = fmaf(p.w, xv, a3);
    }
    for (; e < deg; ++e) {
        int s = col_src[rs + e];
        float4 v = a4s[s];
        float4 p;
        p.x = fexp(lrelu(v.x + ad.x)); p.y = fexp(lrelu(v.y + ad.y));
        p.z = fexp(lrelu(v.z + ad.z)); p.w = fexp(lrelu(v.w + ad.w));
        float xv = x[(size_t)s * 64 + lane];
        a0 = fmaf(p.x, xv, a0);
        a1 = fmaf(p.y, xv, a1);
        a2 = fmaf(p.z, xv, a2);
        a3 = fmaf(p.w, xv, a3);
    }

    float* op = agg + (size_t)d * 256;
    __builtin_nontemporal_store(a0 * ivx, &op[lane]);
    __builtin_nontemporal_store(a1 * ivy, &op[64 + lane]);
    __builtin_nontemporal_store(a2 * ivz, &op[128 + lane]);
    __builtin_nontemporal_store(a3 * ivw, &op[192 + lane]);
}

extern "C" void kernel_launch(void* const* d_in, const int* in_sizes, int n_in,
                              void* d_out, int out_size, void* d_ws, size_t ws_size,
                              hipStream_t stream)
{
    const float* obs     = (const float*)d_in[0];
    const int*   ei      = (const int*)d_in[1];
    const float* enc_w1  = (const float*)d_in[2];
    const float* enc_b1  = (const float*)d_in[3];
    const float* enc_w2  = (const float*)d_in[4];
    const float* enc_b2  = (const float*)d_in[5];
    const float* gat1_w  = (const float*)d_in[6];
    const float* gat1_as = (const float*)d_in[7];
    const float* gat1_ad = (const float*)d_in[8];
    const float* gat1_b  = (const float*)d_in[9];
    const float* gat2_w  = (const float*)d_in[10];
    const float* gat2_as = (const float*)d_in[11];
    const float* gat2_ad = (const float*)d_in[12];
    const float* gat2_b  = (const float*)d_in[13];
    const float* dec_w1  = (const float*)d_in[14];
    const float* dec_b1  = (const float*)d_in[15];
    const float* dec_w2  = (const float*)d_in[16];
    const float* dec_b2  = (const float*)d_in[17];

    float* ws = (float*)d_ws;
    float* bufA    = ws;                                   // [N,64]
    float* bufB    = bufA + (size_t)NN * 64;               // [N,64]  (x)
    float* agg     = bufB + (size_t)NN * 64;               // [N,256]
    float4* a4s    = (float4*)(agg + (size_t)NN * 256);    // [N]
    float4* a4d    = a4s + NN;                             // [N]
    int* row_ptr   = (int*)(a4d + NN);                     // [N+1] (+pad)
    int* cnt       = row_ptr + NN + 4;                     // [N]
    int* col_src   = cnt + NN;                             // [ETOT]
    int* partial   = col_src + ETOT;                       // [256]
    int* partial2  = partial + 256;                        // [256]
    float* vs1     = (float*)(partial2 + 256);             // [256]
    float* vd1     = vs1 + 256;                            // [256]
    float* vs2     = vd1 + 256;                            // [256]
    float* vd2     = vs2 + 256;                            // [256]
    float* B2a     = vd2 + 256;                            // 64KB -> recombine Bp hi/lo L1
    float* B2b     = B2a + 256 * 64;                       // 64KB -> recombine Bp hi/lo L2
    float* Wenc1   = B2b + 256 * 64;                       // 32KB -> enc_w1 hi/lo (128*64*2 u16)
    float* Wenc2   = Wenc1 + 128 * 64;                     // 16KB -> enc_w2 hi/lo
    float* Wdec1   = Wenc2 + 64 * 64;                      // 16KB -> dec_w1 hi/lo
    float* Wdec2   = Wdec1 + 64 * 64;                      // 8KB  -> dec_w2 hi/lo
    int* hist      = (int*)(Wdec2 + 64 * 32);              // [NSCAN]
    int* off_bm    = hist + NSCAN;                         // [NSCAN]
    int2* srec     = (int2*)(off_bm + NSCAN);              // [ETOT]

    u16* Bph_a = (u16*)B2a;  u16* Bpl_a = Bph_a + 256 * 64;
    u16* Bph_b = (u16*)B2b;  u16* Bpl_b = Bph_b + 256 * 64;
    u16* e1h = (u16*)Wenc1;  u16* e1l = e1h + 128 * 64;
    u16* e2h = (u16*)Wenc2;  u16* e2l = e2h + 64 * 64;
    u16* d1h = (u16*)Wdec1;  u16* d1l = d1h + 64 * 64;
    u16* d2h = (u16*)Wdec2;  u16* d2l = d2h + 64 * 32;

    const int GB = (NN + 63) / 64;
    const int NCHUNK_N = (NN + 511) / 512;        // 196
    const int NCHUNK_S = (NSCAN + 511) / 512;     // 220

    // ---- CSR build via counting sort (once, reused by both GAT layers) ----
    hipMemsetAsync(cnt, 0, (size_t)NN * sizeof(int), stream);
    sort_hist<<<NBLK2, 256, 0, stream>>>(ei, hist, cnt);
    gscan_partial<<<NCHUNK_N, 256, 0, stream>>>(cnt, partial, NN);
    gscan_top<<<1, 256, 0, stream>>>(partial, NCHUNK_N);
    gscan_final<<<NCHUNK_N, 256, 0, stream>>>(cnt, partial, row_ptr, NN);
    set_tail<<<1, 1, 0, stream>>>(row_ptr);
    gscan_partial<<<NCHUNK_S, 256, 0, stream>>>(hist, partial2, NSCAN);
    gscan_top<<<1, 256, 0, stream>>>(partial2, NCHUNK_S);
    gscan_final<<<NCHUNK_S, 256, 0, stream>>>(hist, partial2, off_bm, NSCAN);
    sort_scatter<<<NBLK2, 256, 0, stream>>>(ei, off_bm, srec);
    csr_fill2<<<NGRP, 256, 0, stream>>>(row_ptr, srec, col_src);

    // ---- weight precomputes (hoisted) ----
    prep_kernel<<<65, 256, 0, stream>>>(gat1_w, gat1_as, gat1_ad, vs1, vd1, Bph_a, Bpl_a);
    prep_kernel<<<65, 256, 0, stream>>>(gat2_w, gat2_as, gat2_ad, vs2, vd2, Bph_b, Bpl_b);
    prep_w<<<32, 256, 0, stream>>>(enc_w1, e1h, e1l, 128, 64);
    prep_w<<<16, 256, 0, stream>>>(enc_w2, e2h, e2l, 64, 64);
    prep_w<<<16, 256, 0, stream>>>(dec_w1, d1h, d1l, 64, 64);
    prep_w<<<8, 256, 0, stream>>>(dec_w2, d2h, d2l, 64, 32);

    // ---- encoder (GEMM2 fused with layer-1 scores) ----
    mfma_gemm<4><<<GB, 256, 0, stream>>>(obs, e1h, e1l, enc_b1, bufA, NN, 128, 1,
                                         nullptr, nullptr, nullptr, nullptr);
    mfma_gemm<4><<<GB, 256, 0, stream>>>(bufA, e2h, e2l, enc_b2, bufB, NN, 64, 0,
                                         vs1, vd1, a4s, a4d);

    // ---- GAT layer 1 (recombine fused with layer-2 scores) ----
    gat_fused<<<(NN * 64) / 256, 256, 0, stream>>>(row_ptr, col_src, a4s, a4d, bufB, agg);
    mfma_gemm<4><<<GB, 256, 0, stream>>>(agg, Bph_a, Bpl_a, gat1_b, bufB, NN, 256, 1,
                                         vs2, vd2, a4s, a4d);

    // ---- GAT layer 2 ----
    gat_fused<<<(NN * 64) / 256, 256, 0, stream>>>(row_ptr, col_src, a4s, a4d, bufB, agg);
    mfma_gemm<4><<<GB, 256, 0, stream>>>(agg, Bph_b, Bpl_b, gat2_b, bufB, NN, 256, 1,
                                         nullptr, nullptr, nullptr, nullptr);

    // ---- decoder ----
    mfma_gemm<4><<<GB, 256, 0, stream>>>(bufB, d1h, d1l, dec_b1, bufA, NN, 64, 1,
                                         nullptr, nullptr, nullptr, nullptr);
    mfma_gemm<2><<<GB, 256, 0, stream>>>(bufA, d2h, d2l, dec_b2, (float*)d_out, NN, 64, 0,
                                         nullptr, nullptr, nullptr, nullptr);
}

// Round 26
// 341.767 us; speedup vs baseline: 1.2501x; 1.0598x over previous
//
#include <hip/hip_runtime.h>
#include <math.h>

#define NN 100000
#define EE 800000
#define ETOT (EE + NN)
#define CAP 128
#define NBLK2 440            // sort blocks
#define EPB 2048             // edges per sort block (440*2048 >= ETOT)
#define NBUCK 256            // histogram buckets; bucket = d>>9 (<=195)
#define NSCAN (NBUCK * NBLK2)
#define NGRP ((NN + 511) >> 9)   // 196 dst-groups of 512
// HID=64, HEADS=4, OBS=128, ACT=32

typedef __attribute__((ext_vector_type(8))) short s8v;
typedef __attribute__((ext_vector_type(4))) float f4v;
typedef unsigned short u16;
typedef unsigned int   u32;

__device__ __forceinline__ void split_bf16(float v, short& h, short& lo)
{
    u32 u = __float_as_uint(v);
    h = (short)(u >> 16);
    float hf = __uint_as_float(u & 0xFFFF0000u);
    lo = (short)(__float_as_uint(v - hf) >> 16);
}

// ---------------- MFMA bf16-split GEMM (recombine): C[M,Nc]=act(A[M,K]@Bp+bias) ----------------
// Validated R24/R25. Bp frag-order Bp[((k>>3)*Nc+c)*8+(k&7)].
template <int NCB>
__global__ __launch_bounds__(256) void mfma_gemm(
    const float* __restrict__ A, const u16* __restrict__ Bph,
    const u16* __restrict__ Bpl, const float* __restrict__ bias,
    float* __restrict__ C, int M, int K, int doRelu,
    const float* __restrict__ vsc, const float* __restrict__ vdc,
    float4* __restrict__ oas, float4* __restrict__ oad)
{
    constexpr int Nc = NCB * 16;
    __shared__ __align__(16) u16 aHi[64 * 40];
    __shared__ __align__(16) u16 aLo[64 * 40];
    __shared__ float svs[256], svd[256];

    const int tid = threadIdx.x;
    const int bm = blockIdx.x * 64;
    const int w = tid >> 6;
    const int l = tid & 63;

    if (vsc) { svs[tid] = vsc[tid]; svd[tid] = vdc[tid]; }

    const int srow = tid >> 2;
    const int sks  = (tid & 3) * 8;
    const int gr   = bm + srow;
    const bool sval = gr < M;
    const int NT = K >> 5;

    f4v acc[NCB];
#pragma unroll
    for (int cb = 0; cb < NCB; ++cb) { acc[cb][0] = 0.f; acc[cb][1] = 0.f; acc[cb][2] = 0.f; acc[cb][3] = 0.f; }

    float4 r0 = {0.f,0.f,0.f,0.f}, r1 = {0.f,0.f,0.f,0.f};
    if (sval) {
        r0 = *(const float4*)&A[(size_t)gr * K + sks];
        r1 = *(const float4*)&A[(size_t)gr * K + sks + 4];
    }

    const int arow = 16 * w + (l & 15);
    const int akb8 = (l >> 4) * 8;
    const int colg = l & 15;

    for (int t = 0; t < NT; ++t) {
        float vals[8] = {r0.x, r0.y, r0.z, r0.w, r1.x, r1.y, r1.z, r1.w};
        s8v hv, lv;
#pragma unroll
        for (int e = 0; e < 8; ++e) { short h, lo; split_bf16(vals[e], h, lo); hv[e] = h; lv[e] = lo; }
        *(s8v*)&aHi[srow * 40 + sks] = hv;
        *(s8v*)&aLo[srow * 40 + sks] = lv;
        __syncthreads();

        if (t + 1 < NT) {
            const int k0 = (t + 1) << 5;
            r0 = make_float4(0.f, 0.f, 0.f, 0.f);
            r1 = make_float4(0.f, 0.f, 0.f, 0.f);
            if (sval) {
                r0 = *(const float4*)&A[(size_t)gr * K + k0 + sks];
                r1 = *(const float4*)&A[(size_t)gr * K + k0 + sks + 4];
            }
        }

        s8v ah = *(const s8v*)&aHi[arow * 40 + akb8];
        s8v al = *(const s8v*)&aLo[arow * 40 + akb8];
        const int bkb = 4 * t + (l >> 4);
#pragma unroll
        for (int cb = 0; cb < NCB; ++cb) {
            int bidx = (bkb * Nc + cb * 16 + colg) * 8;
            s8v bh = *(const s8v*)&Bph[bidx];
            s8v bl = *(const s8v*)&Bpl[bidx];
            acc[cb] = __builtin_amdgcn_mfma_f32_16x16x32_bf16(ah, bh, acc[cb], 0, 0, 0);
            acc[cb] = __builtin_amdgcn_mfma_f32_16x16x32_bf16(ah, bl, acc[cb], 0, 0, 0);
            acc[cb] = __builtin_amdgcn_mfma_f32_16x16x32_bf16(al, bh, acc[cb], 0, 0, 0);
        }
        __syncthreads();
    }

    const int ct = l & 15;
    const int cg = l >> 4;
    float val[NCB][4];
#pragma unroll
    for (int cb = 0; cb < NCB; ++cb) {
        float bvv = bias[cb * 16 + ct];
#pragma unroll
        for (int i = 0; i < 4; ++i) {
            float v = acc[cb][i] + bvv;
            if (doRelu) v = fmaxf(v, 0.f);
            val[cb][i] = v;
            int row = bm + 16 * w + cg * 4 + i;
            if (row < M) C[(size_t)row * Nc + cb * 16 + ct] = v;
        }
    }

    if (vsc) {
        float cs[NCB][4], cd[NCB][4];
#pragma unroll
        for (int cb = 0; cb < NCB; ++cb)
#pragma unroll
            for (int h = 0; h < 4; ++h) {
                cs[cb][h] = svs[(cb * 16 + ct) * 4 + h];
                cd[cb][h] = svd[(cb * 16 + ct) * 4 + h];
            }
#pragma unroll
        for (int i = 0; i < 4; ++i) {
            float ps[4] = {0.f, 0.f, 0.f, 0.f};
            float pd[4] = {0.f, 0.f, 0.f, 0.f};
#pragma unroll
            for (int cb = 0; cb < NCB; ++cb)
#pragma unroll
                for (int h = 0; h < 4; ++h) {
                    ps[h] = fmaf(val[cb][i], cs[cb][h], ps[h]);
                    pd[h] = fmaf(val[cb][i], cd[cb][h], pd[h]);
                }
#pragma unroll
            for (int off = 1; off < 16; off <<= 1) {
#pragma unroll
                for (int h = 0; h < 4; ++h) {
                    ps[h] += __shfl_xor(ps[h], off, 64);
                    pd[h] += __shfl_xor(pd[h], off, 64);
                }
            }
            if (ct == 0) {
                int row = bm + 16 * w + cg * 4 + i;
                if (row < M) {
                    float4 s4 = {ps[0], ps[1], ps[2], ps[3]};
                    float4 d4 = {pd[0], pd[1], pd[2], pd[3]};
                    oas[row] = s4;
                    oad[row] = d4;
                }
            }
        }
    }
}

// ---------------- fused 2-layer MLP: C = (relu(A@B1+b1))@B2 + b2, optional scores ----------------
// Stage-1 hidden (full 64-wide per block) hi/lo-split straight into the LDS frag buffer
// (no HBM round-trip). Stride 72 u16 rows: 16B-aligned frag reads, 2-way banks (free).
template <int NCB2>
__global__ __launch_bounds__(256) void mlp2_gemm(
    const float* __restrict__ A,
    const u16* __restrict__ B1h, const u16* __restrict__ B1l, const float* __restrict__ bias1,
    const u16* __restrict__ B2h, const u16* __restrict__ B2l, const float* __restrict__ bias2,
    float* __restrict__ C, int M, int K1,
    const float* __restrict__ vsc, const float* __restrict__ vdc,
    float4* __restrict__ oas, float4* __restrict__ oad)
{
    constexpr int Nc2 = NCB2 * 16;
    __shared__ __align__(16) u16 aHi[64 * 72];
    __shared__ __align__(16) u16 aLo[64 * 72];
    __shared__ float svs[256], svd[256];

    const int tid = threadIdx.x;
    const int bm = blockIdx.x * 64;
    const int w = tid >> 6;
    const int l = tid & 63;

    if (vsc) { svs[tid] = vsc[tid]; svd[tid] = vdc[tid]; }

    const int srow = tid >> 2;
    const int sks  = (tid & 3) * 8;
    const int gr   = bm + srow;
    const bool sval = gr < M;
    const int NT = K1 >> 5;

    f4v acc1[4];
#pragma unroll
    for (int cb = 0; cb < 4; ++cb) { acc1[cb][0] = 0.f; acc1[cb][1] = 0.f; acc1[cb][2] = 0.f; acc1[cb][3] = 0.f; }

    float4 r0 = {0.f,0.f,0.f,0.f}, r1 = {0.f,0.f,0.f,0.f};
    if (sval) {
        r0 = *(const float4*)&A[(size_t)gr * K1 + sks];
        r1 = *(const float4*)&A[(size_t)gr * K1 + sks + 4];
    }

    const int arow = 16 * w + (l & 15);
    const int akb8 = (l >> 4) * 8;
    const int colg = l & 15;

    // ---- stage 1: hidden = relu(A @ B1 + b1), K1 pipelined ----
    for (int t = 0; t < NT; ++t) {
        float vals[8] = {r0.x, r0.y, r0.z, r0.w, r1.x, r1.y, r1.z, r1.w};
        s8v hv, lv;
#pragma unroll
        for (int e = 0; e < 8; ++e) { short h, lo; split_bf16(vals[e], h, lo); hv[e] = h; lv[e] = lo; }
        *(s8v*)&aHi[srow * 72 + sks] = hv;
        *(s8v*)&aLo[srow * 72 + sks] = lv;
        __syncthreads();

        if (t + 1 < NT) {
            const int k0 = (t + 1) << 5;
            r0 = make_float4(0.f, 0.f, 0.f, 0.f);
            r1 = make_float4(0.f, 0.f, 0.f, 0.f);
            if (sval) {
                r0 = *(const float4*)&A[(size_t)gr * K1 + k0 + sks];
                r1 = *(const float4*)&A[(size_t)gr * K1 + k0 + sks + 4];
            }
        }

        s8v ah = *(const s8v*)&aHi[arow * 72 + akb8];
        s8v al = *(const s8v*)&aLo[arow * 72 + akb8];
        const int bkb = 4 * t + (l >> 4);
#pragma unroll
        for (int cb = 0; cb < 4; ++cb) {
            int bidx = (bkb * 64 + cb * 16 + colg) * 8;
            s8v bh = *(const s8v*)&B1h[bidx];
            s8v bl = *(const s8v*)&B1l[bidx];
            acc1[cb] = __builtin_amdgcn_mfma_f32_16x16x32_bf16(ah, bh, acc1[cb], 0, 0, 0);
            acc1[cb] = __builtin_amdgcn_mfma_f32_16x16x32_bf16(ah, bl, acc1[cb], 0, 0, 0);
            acc1[cb] = __builtin_amdgcn_mfma_f32_16x16x32_bf16(al, bh, acc1[cb], 0, 0, 0);
        }
        __syncthreads();
    }

    // ---- stage-1 epilogue: hidden -> LDS frag buffer (D layout -> A layout) ----
    const int ct = l & 15;
    const int cg = l >> 4;
#pragma unroll
    for (int cb = 0; cb < 4; ++cb) {
        float bvv = bias1[cb * 16 + ct];
#pragma unroll
        for (int i = 0; i < 4; ++i) {
            float v = fmaxf(acc1[cb][i] + bvv, 0.f);
            int row = 16 * w + cg * 4 + i;
            int col = cb * 16 + ct;
            short hb, lb;
            split_bf16(v, hb, lb);
            aHi[row * 72 + col] = (u16)hb;
            aLo[row * 72 + col] = (u16)lb;
        }
    }
    __syncthreads();

    // ---- stage 2: C = hidden @ B2 + b2 (K=64, 2 frag steps) ----
    f4v acc2[NCB2];
#pragma unroll
    for (int cb = 0; cb < NCB2; ++cb) { acc2[cb][0] = 0.f; acc2[cb][1] = 0.f; acc2[cb][2] = 0.f; acc2[cb][3] = 0.f; }
#pragma unroll
    for (int t2 = 0; t2 < 2; ++t2) {
        s8v ah = *(const s8v*)&aHi[arow * 72 + 32 * t2 + akb8];
        s8v al = *(const s8v*)&aLo[arow * 72 + 32 * t2 + akb8];
        const int bkb = 4 * t2 + (l >> 4);
#pragma unroll
        for (int cb = 0; cb < NCB2; ++cb) {
            int bidx = (bkb * Nc2 + cb * 16 + colg) * 8;
            s8v bh = *(const s8v*)&B2h[bidx];
            s8v bl = *(const s8v*)&B2l[bidx];
            acc2[cb] = __builtin_amdgcn_mfma_f32_16x16x32_bf16(ah, bh, acc2[cb], 0, 0, 0);
            acc2[cb] = __builtin_amdgcn_mfma_f32_16x16x32_bf16(ah, bl, acc2[cb], 0, 0, 0);
            acc2[cb] = __builtin_amdgcn_mfma_f32_16x16x32_bf16(al, bh, acc2[cb], 0, 0, 0);
        }
    }

    // ---- stage-2 epilogue: bias + store (+ optional scores) ----
    float val[NCB2][4];
#pragma unroll
    for (int cb = 0; cb < NCB2; ++cb) {
        float bvv = bias2[cb * 16 + ct];
#pragma unroll
        for (int i = 0; i < 4; ++i) {
            float v = acc2[cb][i] + bvv;
            val[cb][i] = v;
            int row = bm + 16 * w + cg * 4 + i;
            if (row < M) C[(size_t)row * Nc2 + cb * 16 + ct] = v;
        }
    }

    if (vsc) {
        float cs[NCB2][4], cd[NCB2][4];
#pragma unroll
        for (int cb = 0; cb < NCB2; ++cb)
#pragma unroll
            for (int h = 0; h < 4; ++h) {
                cs[cb][h] = svs[(cb * 16 + ct) * 4 + h];
                cd[cb][h] = svd[(cb * 16 + ct) * 4 + h];
            }
#pragma unroll
        for (int i = 0; i < 4; ++i) {
            float ps[4] = {0.f, 0.f, 0.f, 0.f};
            float pd[4] = {0.f, 0.f, 0.f, 0.f};
#pragma unroll
            for (int cb = 0; cb < NCB2; ++cb)
#pragma unroll
                for (int h = 0; h < 4; ++h) {
                    ps[h] = fmaf(val[cb][i], cs[cb][h], ps[h]);
                    pd[h] = fmaf(val[cb][i], cd[cb][h], pd[h]);
                }
#pragma unroll
            for (int off = 1; off < 16; off <<= 1) {
#pragma unroll
                for (int h = 0; h < 4; ++h) {
                    ps[h] += __shfl_xor(ps[h], off, 64);
                    pd[h] += __shfl_xor(pd[h], off, 64);
                }
            }
            if (ct == 0) {
                int row = bm + 16 * w + cg * 4 + i;
                if (row < M) {
                    float4 s4 = {ps[0], ps[1], ps[2], ps[3]};
                    float4 d4 = {pd[0], pd[1], pd[2], pd[3]};
                    oas[row] = s4;
                    oad[row] = d4;
                }
            }
        }
    }
}

__device__ __forceinline__ float lrelu(float x) { return fmaxf(x, 0.2f * x); }
__device__ __forceinline__ float fexp(float x) { return __expf(x); }
__device__ __forceinline__ int edge_src(const int* ei, int e) { return e < EE ? ei[e] : e - EE; }
__device__ __forceinline__ int edge_dst(const int* ei, int e) { return e < EE ? ei[EE + e] : e - EE; }

// ================= generic 3-kernel exclusive scan =================
__global__ __launch_bounds__(256) void gscan_partial(const int* __restrict__ in, int* __restrict__ partial, int n)
{
    __shared__ int s[256];
    int b = blockIdx.x;
    int gi = b * 512 + threadIdx.x;
    int v = 0;
    if (gi < n) v += in[gi];
    if (gi + 256 < n) v += in[gi + 256];
    s[threadIdx.x] = v;
    __syncthreads();
    for (int off = 128; off > 0; off >>= 1) {
        if (threadIdx.x < off) s[threadIdx.x] += s[threadIdx.x + off];
        __syncthreads();
    }
    if (threadIdx.x == 0) partial[b] = s[0];
}

__global__ __launch_bounds__(256) void gscan_top(int* __restrict__ partial, int nb)
{
    __shared__ int s[256];
    int tid = threadIdx.x;
    s[tid] = (tid < nb) ? partial[tid] : 0;
    __syncthreads();
    for (int off = 1; off < 256; off <<= 1) {
        int t = (tid >= off) ? s[tid - off] : 0;
        __syncthreads();
        s[tid] += t;
        __syncthreads();
    }
    if (tid < nb) partial[tid] = (tid == 0) ? 0 : s[tid - 1];
}

__global__ __launch_bounds__(256) void gscan_final(
    const int* __restrict__ in, const int* __restrict__ partial, int* __restrict__ out, int n)
{
    __shared__ int s[512];
    int b = blockIdx.x;
    int tid = threadIdx.x;
    int g0 = b * 512 + tid, g1 = b * 512 + tid + 256;
    s[tid]       = (g0 < n) ? in[g0] : 0;
    s[tid + 256] = (g1 < n) ? in[g1] : 0;
    __syncthreads();
#pragma unroll
    for (int d = 0; d < 9; ++d) {
        int stride = 1 << d, nn2 = 256 >> d;
        if (tid < nn2) s[(2 * tid + 2) * stride - 1] += s[(2 * tid + 1) * stride - 1];
        __syncthreads();
    }
    if (tid == 0) s[511] = 0;
    __syncthreads();
#pragma unroll
    for (int d = 8; d >= 0; --d) {
        int stride = 1 << d, nn2 = 256 >> d;
        if (tid < nn2) {
            int i1 = (2 * tid + 1) * stride - 1, i2 = (2 * tid + 2) * stride - 1;
            int t = s[i1];
            s[i1] = s[i2];
            s[i2] += t;
        }
        __syncthreads();
    }
    int off = partial[b];
    if (g0 < n) out[g0] = s[tid] + off;
    if (g1 < n) out[g1] = s[tid + 256] + off;
}

__global__ void set_tail(int* __restrict__ row_ptr)
{
    row_ptr[NN] = ETOT;
}

// ================= counting sort of edges by dst-group =================
__global__ __launch_bounds__(256) void sort_hist(
    const int* __restrict__ ei, int* __restrict__ hist_bm, int* __restrict__ cnt)
{
    __shared__ int h[NBUCK];
    int tid = threadIdx.x, blk = blockIdx.x;
    h[tid] = 0;
    __syncthreads();
#pragma unroll
    for (int it = 0; it < EPB / 256; ++it) {
        int e = blk * EPB + it * 256 + tid;
        if (e < ETOT) {
            int d = edge_dst(ei, e);
            atomicAdd(&h[d >> 9], 1);
            atomicAdd(&cnt[d], 1);
        }
    }
    __syncthreads();
    hist_bm[tid * NBLK2 + blk] = h[tid];
}

__global__ __launch_bounds__(256) void sort_scatter(
    const int* __restrict__ ei, const int* __restrict__ off_bm, int2* __restrict__ srec)
{
    __shared__ int cur[NBUCK];
    int tid = threadIdx.x, blk = blockIdx.x;
    cur[tid] = off_bm[tid * NBLK2 + blk];
    __syncthreads();
#pragma unroll
    for (int it = 0; it < EPB / 256; ++it) {
        int e = blk * EPB + it * 256 + tid;
        if (e < ETOT) {
            int d = edge_dst(ei, e);
            int s = edge_src(ei, e);
            int pos = atomicAdd(&cur[d >> 9], 1);
            srec[pos] = make_int2(s, d);
        }
    }
}

__global__ __launch_bounds__(256) void csr_fill2(
    const int* __restrict__ row_ptr, const int2* __restrict__ srec, int* __restrict__ col_src)
{
    __shared__ int cur[512];
    int g = blockIdx.x, tid = threadIdx.x;
    int n0 = g << 9;
    for (int i = tid; i < 512; i += 256) {
        int nd = n0 + i;
        cur[i] = (nd < NN) ? row_ptr[nd] : 0;
    }
    __syncthreads();
    int lo = row_ptr[n0];
    int hi = (n0 + 512 <= NN) ? row_ptr[n0 + 512] : ETOT;
    for (int idx = lo + tid; idx < hi; idx += 256) {
        int2 r = srec[idx];
        int pos = atomicAdd(&cur[r.y - n0], 1);
        col_src[pos] = r.x;
    }
}

// ================= per-layer precomputes: att vecs + frag-ordered hi/lo recombine B =================
__global__ __launch_bounds__(256) void prep_kernel(
    const float* __restrict__ W, const float* __restrict__ attS,
    const float* __restrict__ attD, float* __restrict__ vs, float* __restrict__ vd,
    u16* __restrict__ Bph, u16* __restrict__ Bpl)
{
    int tid = threadIdx.x;
    if (blockIdx.x == 64) {
        int k = tid >> 2, h = tid & 3;
        const float* wr = W + (size_t)k * 256 + h * 64;
        const float* as = attS + h * 64;
        const float* ad = attD + h * 64;
        float ss = 0.f, sd = 0.f;
#pragma unroll
        for (int j = 0; j < 64; ++j) {
            float wv = wr[j];
            ss += wv * as[j];
            sd += wv * ad[j];
        }
        vs[tid] = ss;
        vd[tid] = sd;
    } else {
        int i = blockIdx.x * 256 + tid;   // i = r*64+c ; r = h*64+k'
        int r = i >> 6, c = i & 63;
        int h = r >> 6, k = r & 63;
        float v = W[(size_t)k * 256 + h * 64 + c];
        short hb, lb;
        split_bf16(v, hb, lb);
        int pos = ((r >> 3) * 64 + c) * 8 + (r & 7);
        Bph[pos] = (u16)hb;
        Bpl[pos] = (u16)lb;
    }
}

// ================= plain weight -> frag-ordered hi/lo (W[K][Nc] row-major) =================
__global__ __launch_bounds__(256) void prep_w(
    const float* __restrict__ W, u16* __restrict__ Bph, u16* __restrict__ Bpl, int K, int Nc)
{
    int i = blockIdx.x * 256 + threadIdx.x;
    if (i >= K * Nc) return;
    int k = i / Nc, c = i - k * Nc;
    short hb, lb;
    split_bf16(W[i], hb, lb);
    int pos = ((k >> 3) * Nc + c) * 8 + (k & 7);
    Bph[pos] = (u16)hb;
    Bpl[pos] = (u16)lb;
}

// ================= fused softmax + gather aggregation (wave per dst) =================
__global__ __launch_bounds__(256) void gat_fused(
    const int* __restrict__ row_ptr, const int* __restrict__ col_src,
    const float4* __restrict__ a4s, const float4* __restrict__ a4d,
    const float* __restrict__ x, float* __restrict__ agg)
{
    __shared__ float4 sp[4][CAP];
    __shared__ int    ssrc[4][CAP];
    const int wslot = threadIdx.x >> 6;
    const int lane = threadIdx.x & 63;
    const int d = (blockIdx.x * 256 + threadIdx.x) >> 6;

    const int rs = row_ptr[d];
    const int deg = row_ptr[d + 1] - rs;
    const float4 ad = a4d[d];

    float px = 0.f, py = 0.f, pz = 0.f, pw = 0.f;
    for (int base = 0; base < deg; base += 64) {
        int idx = base + lane;
        float4 p = {0.f, 0.f, 0.f, 0.f};
        int s = 0;
        if (idx < deg) {
            s = col_src[rs + idx];
            float4 v = a4s[s];
            p.x = fexp(lrelu(v.x + ad.x));
            p.y = fexp(lrelu(v.y + ad.y));
            p.z = fexp(lrelu(v.z + ad.z));
            p.w = fexp(lrelu(v.w + ad.w));
        }
        if (idx < CAP) { sp[wslot][idx] = p; ssrc[wslot][idx] = s; }
        px += p.x; py += p.y; pz += p.z; pw += p.w;
    }
#pragma unroll
    for (int off = 32; off > 0; off >>= 1) {
        px += __shfl_xor(px, off, 64);
        py += __shfl_xor(py, off, 64);
        pz += __shfl_xor(pz, off, 64);
        pw += __shfl_xor(pw, off, 64);
    }
    const float ivx = 0.25f * __builtin_amdgcn_rcpf(px);
    const float ivy = 0.25f * __builtin_amdgcn_rcpf(py);
    const float ivz = 0.25f * __builtin_amdgcn_rcpf(pz);
    const float ivw = 0.25f * __builtin_amdgcn_rcpf(pw);

    float a0 = 0.f, a1 = 0.f, a2 = 0.f, a3 = 0.f;
    const int lim = deg < CAP ? deg : CAP;
    int e = 0;
    for (; e + 4 <= lim; e += 4) {
        float4 p0 = sp[wslot][e + 0], p1 = sp[wslot][e + 1];
        float4 p2 = sp[wslot][e + 2], p3 = sp[wslot][e + 3];
        int s0 = ssrc[wslot][e + 0], s1 = ssrc[wslot][e + 1];
        int s2 = ssrc[wslot][e + 2], s3 = ssrc[wslot][e + 3];
        float x0 = x[(size_t)s0 * 64 + lane];
        float x1 = x[(size_t)s1 * 64 + lane];
        float x2 = x[(size_t)s2 * 64 + lane];
        float x3 = x[(size_t)s3 * 64 + lane];
        a0 += p0.x * x0 + p1.x * x1 + p2.x * x2 + p3.x * x3;
        a1 += p0.y * x0 + p1.y * x1 + p2.y * x2 + p3.y * x3;
        a2 += p0.z * x0 + p1.z * x1 + p2.z * x2 + p3.z * x3;
        a3 += p0.w * x0 + p1.w * x1 + p2.w * x2 + p3.w * x3;
    }
    for (; e < lim; ++e) {
        float4 p = sp[wslot][e];
        int s = ssrc[wslot][e];
        float xv = x[(size_t)s * 64 + lane];
        a0 = fmaf(p.x, xv, a0);
        a1 = fmaf(p.y, xv, a1);
        a2 = fmaf(p.z, xv, a2);
        a3 = fmaf(p.w, xv, a3);
    }
    for (; e < deg; ++e) {
        int s = col_src[rs + e];
        float4 v = a4s[s];
        float4 p;
        p.x = fexp(lrelu(v.x + ad.x)); p.y = fexp(lrelu(v.y + ad.y));
        p.z = fexp(lrelu(v.z + ad.z)); p.w = fexp(lrelu(v.w + ad.w));
        float xv = x[(size_t)s * 64 + lane];
        a0 = fmaf(p.x, xv, a0);
        a1 = fmaf(p.y, xv, a1);
        a2 = fmaf(p.z, xv, a2);
        a3 = fmaf(p.w, xv, a3);
    }

    float* op = agg + (size_t)d * 256;
    __builtin_nontemporal_store(a0 * ivx, &op[lane]);
    __builtin_nontemporal_store(a1 * ivy, &op[64 + lane]);
    __builtin_nontemporal_store(a2 * ivz, &op[128 + lane]);
    __builtin_nontemporal_store(a3 * ivw, &op[192 + lane]);
}

extern "C" void kernel_launch(void* const* d_in, const int* in_sizes, int n_in,
                              void* d_out, int out_size, void* d_ws, size_t ws_size,
                              hipStream_t stream)
{
    const float* obs     = (const float*)d_in[0];
    const int*   ei      = (const int*)d_in[1];
    const float* enc_w1  = (const float*)d_in[2];
    const float* enc_b1  = (const float*)d_in[3];
    const float* enc_w2  = (const float*)d_in[4];
    const float* enc_b2  = (const float*)d_in[5];
    const float* gat1_w  = (const float*)d_in[6];
    const float* gat1_as = (const float*)d_in[7];
    const float* gat1_ad = (const float*)d_in[8];
    const float* gat1_b  = (const float*)d_in[9];
    const float* gat2_w  = (const float*)d_in[10];
    const float* gat2_as = (const float*)d_in[11];
    const float* gat2_ad = (const float*)d_in[12];
    const float* gat2_b  = (const float*)d_in[13];
    const float* dec_w1  = (const float*)d_in[14];
    const float* dec_b1  = (const float*)d_in[15];
    const float* dec_w2  = (const float*)d_in[16];
    const float* dec_b2  = (const float*)d_in[17];

    float* ws = (float*)d_ws;
    float* bufA    = ws;                                   // [N,64] (unused now, kept for layout)
    float* bufB    = bufA + (size_t)NN * 64;               // [N,64]  (x)
    float* agg     = bufB + (size_t)NN * 64;               // [N,256]
    float4* a4s    = (float4*)(agg + (size_t)NN * 256);    // [N]
    float4* a4d    = a4s + NN;                             // [N]
    int* row_ptr   = (int*)(a4d + NN);                     // [N+1] (+pad)
    int* cnt       = row_ptr + NN + 4;                     // [N]
    int* col_src   = cnt + NN;                             // [ETOT]
    int* partial   = col_src + ETOT;                       // [256]
    int* partial2  = partial + 256;                        // [256]
    float* vs1     = (float*)(partial2 + 256);             // [256]
    float* vd1     = vs1 + 256;                            // [256]
    float* vs2     = vd1 + 256;                            // [256]
    float* vd2     = vs2 + 256;                            // [256]
    float* B2a     = vd2 + 256;                            // 64KB -> recombine Bp hi/lo L1
    float* B2b     = B2a + 256 * 64;                       // 64KB -> recombine Bp hi/lo L2
    float* Wenc1   = B2b + 256 * 64;                       // 32KB -> enc_w1 hi/lo
    float* Wenc2   = Wenc1 + 128 * 64;                     // 16KB -> enc_w2 hi/lo
    float* Wdec1   = Wenc2 + 64 * 64;                      // 16KB -> dec_w1 hi/lo
    float* Wdec2   = Wdec1 + 64 * 64;                      // 8KB  -> dec_w2 hi/lo
    int* hist      = (int*)(Wdec2 + 64 * 32);              // [NSCAN]
    int* off_bm    = hist + NSCAN;                         // [NSCAN]
    int2* srec     = (int2*)(off_bm + NSCAN);              // [ETOT]

    u16* Bph_a = (u16*)B2a;  u16* Bpl_a = Bph_a + 256 * 64;
    u16* Bph_b = (u16*)B2b;  u16* Bpl_b = Bph_b + 256 * 64;
    u16* e1h = (u16*)Wenc1;  u16* e1l = e1h + 128 * 64;
    u16* e2h = (u16*)Wenc2;  u16* e2l = e2h + 64 * 64;
    u16* d1h = (u16*)Wdec1;  u16* d1l = d1h + 64 * 64;
    u16* d2h = (u16*)Wdec2;  u16* d2l = d2h + 64 * 32;

    const int GB = (NN + 63) / 64;
    const int NCHUNK_N = (NN + 511) / 512;        // 196
    const int NCHUNK_S = (NSCAN + 511) / 512;     // 220

    // ---- CSR build via counting sort (once, reused by both GAT layers) ----
    hipMemsetAsync(cnt, 0, (size_t)NN * sizeof(int), stream);
    sort_hist<<<NBLK2, 256, 0, stream>>>(ei, hist, cnt);
    gscan_partial<<<NCHUNK_N, 256, 0, stream>>>(cnt, partial, NN);
    gscan_top<<<1, 256, 0, stream>>>(partial, NCHUNK_N);
    gscan_final<<<NCHUNK_N, 256, 0, stream>>>(cnt, partial, row_ptr, NN);
    set_tail<<<1, 1, 0, stream>>>(row_ptr);
    gscan_partial<<<NCHUNK_S, 256, 0, stream>>>(hist, partial2, NSCAN);
    gscan_top<<<1, 256, 0, stream>>>(partial2, NCHUNK_S);
    gscan_final<<<NCHUNK_S, 256, 0, stream>>>(hist, partial2, off_bm, NSCAN);
    sort_scatter<<<NBLK2, 256, 0, stream>>>(ei, off_bm, srec);
    csr_fill2<<<NGRP, 256, 0, stream>>>(row_ptr, srec, col_src);

    // ---- weight precomputes (hoisted) ----
    prep_kernel<<<65, 256, 0, stream>>>(gat1_w, gat1_as, gat1_ad, vs1, vd1, Bph_a, Bpl_a);
    prep_kernel<<<65, 256, 0, stream>>>(gat2_w, gat2_as, gat2_ad, vs2, vd2, Bph_b, Bpl_b);
    prep_w<<<32, 256, 0, stream>>>(enc_w1, e1h, e1l, 128, 64);
    prep_w<<<16, 256, 0, stream>>>(enc_w2, e2h, e2l, 64, 64);
    prep_w<<<16, 256, 0, stream>>>(dec_w1, d1h, d1l, 64, 64);
    prep_w<<<8, 256, 0, stream>>>(dec_w2, d2h, d2l, 64, 32);

    // ---- encoder: fused 2-layer MLP + layer-1 scores ----
    mlp2_gemm<4><<<GB, 256, 0, stream>>>(obs, e1h, e1l, enc_b1, e2h, e2l, enc_b2,
                                         bufB, NN, 128, vs1, vd1, a4s, a4d);

    // ---- GAT layer 1 (recombine fused with layer-2 scores) ----
    gat_fused<<<(NN * 64) / 256, 256, 0, stream>>>(row_ptr, col_src, a4s, a4d, bufB, agg);
    mfma_gemm<4><<<GB, 256, 0, stream>>>(agg, Bph_a, Bpl_a, gat1_b, bufB, NN, 256, 1,
                                         vs2, vd2, a4s, a4d);

    // ---- GAT layer 2 ----
    gat_fused<<<(NN * 64) / 256, 256, 0, stream>>>(row_ptr, col_src, a4s, a4d, bufB, agg);
    mfma_gemm<4><<<GB, 256, 0, stream>>>(agg, Bph_b, Bpl_b, gat2_b, bufB, NN, 256, 1,
                                         nullptr, nullptr, nullptr, nullptr);

    // ---- decoder: fused 2-layer MLP ----
    mlp2_gemm<2><<<GB, 256, 0, stream>>>(bufB, d1h, d1l, dec_b1, d2h, d2l, dec_b2,
                                         (float*)d_out, NN, 64, nullptr, nullptr, nullptr, nullptr);
}

// Round 27
// 312.848 us; speedup vs baseline: 1.3657x; 1.0924x over previous
//
#include <hip/hip_runtime.h>
#include <math.h>

#define NN 100000
#define EE 800000
#define ETOT (EE + NN)
#define CAP 128
#define NBLK2 440            // sort blocks
#define EPB 2048             // edges per sort block (440*2048 >= ETOT)
#define NBUCK 256            // histogram buckets; bucket = d>>9 (<=195)
#define NSCAN (NBUCK * NBLK2)
#define NGRP ((NN + 511) >> 9)   // 196 dst-groups of 512
// HID=64, HEADS=4, OBS=128, ACT=32

typedef __attribute__((ext_vector_type(8))) short s8v;
typedef __attribute__((ext_vector_type(4))) float f4v;
typedef unsigned short u16;
typedef unsigned int   u32;

__device__ __forceinline__ void split_bf16(float v, short& h, short& lo)
{
    u32 u = __float_as_uint(v);
    h = (short)(u >> 16);
    float hf = __uint_as_float(u & 0xFFFF0000u);
    lo = (short)(__float_as_uint(v - hf) >> 16);
}
__device__ __forceinline__ float bf2f(u16 u) { return __uint_as_float(((u32)u) << 16); }
__device__ __forceinline__ u16 f2bf(float v)   // round-to-nearest-even
{
    u32 u = __float_as_uint(v);
    return (u16)((u + 0x7FFFu + ((u >> 16) & 1u)) >> 16);
}

// ---------------- MFMA recombine GEMM, bf16 A: C_bf16[M,Nc]=relu(A_bf16[M,K]@Bp+bias) ----------------
// A exact bf16 -> a*b = ah*(bh+bl): 2 MFMAs/step. Bp frag-order Bp[((k>>3)*Nc+c)*8+(k&7)].
template <int NCB>
__global__ __launch_bounds__(256) void mfma_gemm_b(
    const u16* __restrict__ A, const u16* __restrict__ Bph,
    const u16* __restrict__ Bpl, const float* __restrict__ bias,
    u16* __restrict__ C, int M, int K,
    const float* __restrict__ vsc, const float* __restrict__ vdc,
    float4* __restrict__ oas, float4* __restrict__ oad)
{
    constexpr int Nc = NCB * 16;
    __shared__ __align__(16) u16 aHi[64 * 40];
    __shared__ float svs[256], svd[256];

    const int tid = threadIdx.x;
    const int bm = blockIdx.x * 64;
    const int w = tid >> 6;
    const int l = tid & 63;

    if (vsc) { svs[tid] = vsc[tid]; svd[tid] = vdc[tid]; }

    const int srow = tid >> 2;
    const int sks  = (tid & 3) * 8;
    const int gr   = bm + srow;
    const bool sval = gr < M;
    const int NT = K >> 5;

    f4v acc[NCB];
#pragma unroll
    for (int cb = 0; cb < NCB; ++cb) { acc[cb][0] = 0.f; acc[cb][1] = 0.f; acc[cb][2] = 0.f; acc[cb][3] = 0.f; }

    s8v ra = {0,0,0,0,0,0,0,0};
    if (sval) ra = *(const s8v*)&A[(size_t)gr * K + sks];

    const int arow = 16 * w + (l & 15);
    const int akb8 = (l >> 4) * 8;
    const int colg = l & 15;

    for (int t = 0; t < NT; ++t) {
        *(s8v*)&aHi[srow * 40 + sks] = ra;
        __syncthreads();

        if (t + 1 < NT) {
            const int k0 = (t + 1) << 5;
            s8v z = {0,0,0,0,0,0,0,0};
            ra = z;
            if (sval) ra = *(const s8v*)&A[(size_t)gr * K + k0 + sks];
        }

        s8v ah = *(const s8v*)&aHi[arow * 40 + akb8];
        const int bkb = 4 * t + (l >> 4);
#pragma unroll
        for (int cb = 0; cb < NCB; ++cb) {
            int bidx = (bkb * Nc + cb * 16 + colg) * 8;
            s8v bh = *(const s8v*)&Bph[bidx];
            s8v bl = *(const s8v*)&Bpl[bidx];
            acc[cb] = __builtin_amdgcn_mfma_f32_16x16x32_bf16(ah, bh, acc[cb], 0, 0, 0);
            acc[cb] = __builtin_amdgcn_mfma_f32_16x16x32_bf16(ah, bl, acc[cb], 0, 0, 0);
        }
        __syncthreads();
    }

    const int ct = l & 15;
    const int cg = l >> 4;
    float val[NCB][4];
#pragma unroll
    for (int cb = 0; cb < NCB; ++cb) {
        float bvv = bias[cb * 16 + ct];
#pragma unroll
        for (int i = 0; i < 4; ++i) {
            float v = fmaxf(acc[cb][i] + bvv, 0.f);
            val[cb][i] = v;
            int row = bm + 16 * w + cg * 4 + i;
            if (row < M) C[(size_t)row * Nc + cb * 16 + ct] = f2bf(v);
        }
    }

    if (vsc) {
        float cs[NCB][4], cd[NCB][4];
#pragma unroll
        for (int cb = 0; cb < NCB; ++cb)
#pragma unroll
            for (int h = 0; h < 4; ++h) {
                cs[cb][h] = svs[(cb * 16 + ct) * 4 + h];
                cd[cb][h] = svd[(cb * 16 + ct) * 4 + h];
            }
#pragma unroll
        for (int i = 0; i < 4; ++i) {
            float ps[4] = {0.f, 0.f, 0.f, 0.f};
            float pd[4] = {0.f, 0.f, 0.f, 0.f};
#pragma unroll
            for (int cb = 0; cb < NCB; ++cb)
#pragma unroll
                for (int h = 0; h < 4; ++h) {
                    ps[h] = fmaf(val[cb][i], cs[cb][h], ps[h]);
                    pd[h] = fmaf(val[cb][i], cd[cb][h], pd[h]);
                }
#pragma unroll
            for (int off = 1; off < 16; off <<= 1) {
#pragma unroll
                for (int h = 0; h < 4; ++h) {
                    ps[h] += __shfl_xor(ps[h], off, 64);
                    pd[h] += __shfl_xor(pd[h], off, 64);
                }
            }
            if (ct == 0) {
                int row = bm + 16 * w + cg * 4 + i;
                if (row < M) {
                    float4 s4 = {ps[0], ps[1], ps[2], ps[3]};
                    float4 d4 = {pd[0], pd[1], pd[2], pd[3]};
                    oas[row] = s4;
                    oad[row] = d4;
                }
            }
        }
    }
}

// ---------------- fused 2-layer MLP (templated A/out dtype) ----------------
// AB16: A is exact bf16 (2 MFMAs/step). OB16: store C as bf16 (RNE), else fp32.
template <int NCB2, bool AB16, bool OB16>
__global__ __launch_bounds__(256) void mlp2_gemm(
    const void* __restrict__ Ap,
    const u16* __restrict__ B1h, const u16* __restrict__ B1l, const float* __restrict__ bias1,
    const u16* __restrict__ B2h, const u16* __restrict__ B2l, const float* __restrict__ bias2,
    void* __restrict__ Cp, int M, int K1,
    const float* __restrict__ vsc, const float* __restrict__ vdc,
    float4* __restrict__ oas, float4* __restrict__ oad)
{
    constexpr int Nc2 = NCB2 * 16;
    __shared__ __align__(16) u16 aHi[64 * 72];
    __shared__ __align__(16) u16 aLo[64 * 72];
    __shared__ float svs[256], svd[256];

    const float* Af = (const float*)Ap;
    const u16*   Ab = (const u16*)Ap;
    float* Cf = (float*)Cp;
    u16*   Cb = (u16*)Cp;

    const int tid = threadIdx.x;
    const int bm = blockIdx.x * 64;
    const int w = tid >> 6;
    const int l = tid & 63;

    if (vsc) { svs[tid] = vsc[tid]; svd[tid] = vdc[tid]; }

    const int srow = tid >> 2;
    const int sks  = (tid & 3) * 8;
    const int gr   = bm + srow;
    const bool sval = gr < M;
    const int NT = K1 >> 5;

    f4v acc1[4];
#pragma unroll
    for (int cb = 0; cb < 4; ++cb) { acc1[cb][0] = 0.f; acc1[cb][1] = 0.f; acc1[cb][2] = 0.f; acc1[cb][3] = 0.f; }

    float4 r0 = {0.f,0.f,0.f,0.f}, r1 = {0.f,0.f,0.f,0.f};
    s8v rb = {0,0,0,0,0,0,0,0};
    if (sval) {
        if constexpr (AB16) {
            rb = *(const s8v*)&Ab[(size_t)gr * K1 + sks];
        } else {
            r0 = *(const float4*)&Af[(size_t)gr * K1 + sks];
            r1 = *(const float4*)&Af[(size_t)gr * K1 + sks + 4];
        }
    }

    const int arow = 16 * w + (l & 15);
    const int akb8 = (l >> 4) * 8;
    const int colg = l & 15;

    // ---- stage 1 ----
    for (int t = 0; t < NT; ++t) {
        if constexpr (AB16) {
            *(s8v*)&aHi[srow * 72 + sks] = rb;
        } else {
            float vals[8] = {r0.x, r0.y, r0.z, r0.w, r1.x, r1.y, r1.z, r1.w};
            s8v hv, lv;
#pragma unroll
            for (int e = 0; e < 8; ++e) { short h, lo; split_bf16(vals[e], h, lo); hv[e] = h; lv[e] = lo; }
            *(s8v*)&aHi[srow * 72 + sks] = hv;
            *(s8v*)&aLo[srow * 72 + sks] = lv;
        }
        __syncthreads();

        if (t + 1 < NT) {
            const int k0 = (t + 1) << 5;
            if constexpr (AB16) {
                s8v z = {0,0,0,0,0,0,0,0};
                rb = z;
                if (sval) rb = *(const s8v*)&Ab[(size_t)gr * K1 + k0 + sks];
            } else {
                r0 = make_float4(0.f, 0.f, 0.f, 0.f);
                r1 = make_float4(0.f, 0.f, 0.f, 0.f);
                if (sval) {
                    r0 = *(const float4*)&Af[(size_t)gr * K1 + k0 + sks];
                    r1 = *(const float4*)&Af[(size_t)gr * K1 + k0 + sks + 4];
                }
            }
        }

        s8v ah = *(const s8v*)&aHi[arow * 72 + akb8];
        s8v al;
        if constexpr (!AB16) al = *(const s8v*)&aLo[arow * 72 + akb8];
        const int bkb = 4 * t + (l >> 4);
#pragma unroll
        for (int cb = 0; cb < 4; ++cb) {
            int bidx = (bkb * 64 + cb * 16 + colg) * 8;
            s8v bh = *(const s8v*)&B1h[bidx];
            s8v bl = *(const s8v*)&B1l[bidx];
            acc1[cb] = __builtin_amdgcn_mfma_f32_16x16x32_bf16(ah, bh, acc1[cb], 0, 0, 0);
            acc1[cb] = __builtin_amdgcn_mfma_f32_16x16x32_bf16(ah, bl, acc1[cb], 0, 0, 0);
            if constexpr (!AB16)
                acc1[cb] = __builtin_amdgcn_mfma_f32_16x16x32_bf16(al, bh, acc1[cb], 0, 0, 0);
        }
        __syncthreads();
    }

    // ---- stage-1 epilogue: hidden (fp32) -> hi/lo LDS frag buffer ----
    const int ct = l & 15;
    const int cg = l >> 4;
#pragma unroll
    for (int cb = 0; cb < 4; ++cb) {
        float bvv = bias1[cb * 16 + ct];
#pragma unroll
        for (int i = 0; i < 4; ++i) {
            float v = fmaxf(acc1[cb][i] + bvv, 0.f);
            int row = 16 * w + cg * 4 + i;
            int col = cb * 16 + ct;
            short hb, lb;
            split_bf16(v, hb, lb);
            aHi[row * 72 + col] = (u16)hb;
            aLo[row * 72 + col] = (u16)lb;
        }
    }
    __syncthreads();

    // ---- stage 2: K=64, hidden hi/lo (3 MFMAs/step) ----
    f4v acc2[NCB2];
#pragma unroll
    for (int cb = 0; cb < NCB2; ++cb) { acc2[cb][0] = 0.f; acc2[cb][1] = 0.f; acc2[cb][2] = 0.f; acc2[cb][3] = 0.f; }
#pragma unroll
    for (int t2 = 0; t2 < 2; ++t2) {
        s8v ah = *(const s8v*)&aHi[arow * 72 + 32 * t2 + akb8];
        s8v al = *(const s8v*)&aLo[arow * 72 + 32 * t2 + akb8];
        const int bkb = 4 * t2 + (l >> 4);
#pragma unroll
        for (int cb = 0; cb < NCB2; ++cb) {
            int bidx = (bkb * Nc2 + cb * 16 + colg) * 8;
            s8v bh = *(const s8v*)&B2h[bidx];
            s8v bl = *(const s8v*)&B2l[bidx];
            acc2[cb] = __builtin_amdgcn_mfma_f32_16x16x32_bf16(ah, bh, acc2[cb], 0, 0, 0);
            acc2[cb] = __builtin_amdgcn_mfma_f32_16x16x32_bf16(ah, bl, acc2[cb], 0, 0, 0);
            acc2[cb] = __builtin_amdgcn_mfma_f32_16x16x32_bf16(al, bh, acc2[cb], 0, 0, 0);
        }
    }

    // ---- stage-2 epilogue ----
    float val[NCB2][4];
#pragma unroll
    for (int cb = 0; cb < NCB2; ++cb) {
        float bvv = bias2[cb * 16 + ct];
#pragma unroll
        for (int i = 0; i < 4; ++i) {
            float v = acc2[cb][i] + bvv;
            val[cb][i] = v;
            int row = bm + 16 * w + cg * 4 + i;
            if (row < M) {
                if constexpr (OB16) Cb[(size_t)row * Nc2 + cb * 16 + ct] = f2bf(v);
                else                Cf[(size_t)row * Nc2 + cb * 16 + ct] = v;
            }
        }
    }

    if (vsc) {
        float cs[NCB2][4], cd[NCB2][4];
#pragma unroll
        for (int cb = 0; cb < NCB2; ++cb)
#pragma unroll
            for (int h = 0; h < 4; ++h) {
                cs[cb][h] = svs[(cb * 16 + ct) * 4 + h];
                cd[cb][h] = svd[(cb * 16 + ct) * 4 + h];
            }
#pragma unroll
        for (int i = 0; i < 4; ++i) {
            float ps[4] = {0.f, 0.f, 0.f, 0.f};
            float pd[4] = {0.f, 0.f, 0.f, 0.f};
#pragma unroll
            for (int cb = 0; cb < NCB2; ++cb)
#pragma unroll
                for (int h = 0; h < 4; ++h) {
                    ps[h] = fmaf(val[cb][i], cs[cb][h], ps[h]);
                    pd[h] = fmaf(val[cb][i], cd[cb][h], pd[h]);
                }
#pragma unroll
            for (int off = 1; off < 16; off <<= 1) {
#pragma unroll
                for (int h = 0; h < 4; ++h) {
                    ps[h] += __shfl_xor(ps[h], off, 64);
                    pd[h] += __shfl_xor(pd[h], off, 64);
                }
            }
            if (ct == 0) {
                int row = bm + 16 * w + cg * 4 + i;
                if (row < M) {
                    float4 s4 = {ps[0], ps[1], ps[2], ps[3]};
                    float4 d4 = {pd[0], pd[1], pd[2], pd[3]};
                    oas[row] = s4;
                    oad[row] = d4;
                }
            }
        }
    }
}

__device__ __forceinline__ float lrelu(float x) { return fmaxf(x, 0.2f * x); }
__device__ __forceinline__ float fexp(float x) { return __expf(x); }
__device__ __forceinline__ int edge_src(const int* ei, int e) { return e < EE ? ei[e] : e - EE; }
__device__ __forceinline__ int edge_dst(const int* ei, int e) { return e < EE ? ei[EE + e] : e - EE; }

// ================= generic 3-kernel exclusive scan =================
__global__ __launch_bounds__(256) void gscan_partial(const int* __restrict__ in, int* __restrict__ partial, int n)
{
    __shared__ int s[256];
    int b = blockIdx.x;
    int gi = b * 512 + threadIdx.x;
    int v = 0;
    if (gi < n) v += in[gi];
    if (gi + 256 < n) v += in[gi + 256];
    s[threadIdx.x] = v;
    __syncthreads();
    for (int off = 128; off > 0; off >>= 1) {
        if (threadIdx.x < off) s[threadIdx.x] += s[threadIdx.x + off];
        __syncthreads();
    }
    if (threadIdx.x == 0) partial[b] = s[0];
}

__global__ __launch_bounds__(256) void gscan_top(int* __restrict__ partial, int nb)
{
    __shared__ int s[256];
    int tid = threadIdx.x;
    s[tid] = (tid < nb) ? partial[tid] : 0;
    __syncthreads();
    for (int off = 1; off < 256; off <<= 1) {
        int t = (tid >= off) ? s[tid - off] : 0;
        __syncthreads();
        s[tid] += t;
        __syncthreads();
    }
    if (tid < nb) partial[tid] = (tid == 0) ? 0 : s[tid - 1];
}

__global__ __launch_bounds__(256) void gscan_final(
    const int* __restrict__ in, const int* __restrict__ partial, int* __restrict__ out, int n)
{
    __shared__ int s[512];
    int b = blockIdx.x;
    int tid = threadIdx.x;
    int g0 = b * 512 + tid, g1 = b * 512 + tid + 256;
    s[tid]       = (g0 < n) ? in[g0] : 0;
    s[tid + 256] = (g1 < n) ? in[g1] : 0;
    __syncthreads();
#pragma unroll
    for (int d = 0; d < 9; ++d) {
        int stride = 1 << d, nn2 = 256 >> d;
        if (tid < nn2) s[(2 * tid + 2) * stride - 1] += s[(2 * tid + 1) * stride - 1];
        __syncthreads();
    }
    if (tid == 0) s[511] = 0;
    __syncthreads();
#pragma unroll
    for (int d = 8; d >= 0; --d) {
        int stride = 1 << d, nn2 = 256 >> d;
        if (tid < nn2) {
            int i1 = (2 * tid + 1) * stride - 1, i2 = (2 * tid + 2) * stride - 1;
            int t = s[i1];
            s[i1] = s[i2];
            s[i2] += t;
        }
        __syncthreads();
    }
    int off = partial[b];
    if (g0 < n) out[g0] = s[tid] + off;
    if (g1 < n) out[g1] = s[tid + 256] + off;
}

__global__ void set_tail(int* __restrict__ row_ptr)
{
    row_ptr[NN] = ETOT;
}

// ================= counting sort of edges by dst-group =================
__global__ __launch_bounds__(256) void sort_hist(
    const int* __restrict__ ei, int* __restrict__ hist_bm, int* __restrict__ cnt)
{
    __shared__ int h[NBUCK];
    int tid = threadIdx.x, blk = blockIdx.x;
    h[tid] = 0;
    __syncthreads();
#pragma unroll
    for (int it = 0; it < EPB / 256; ++it) {
        int e = blk * EPB + it * 256 + tid;
        if (e < ETOT) {
            int d = edge_dst(ei, e);
            atomicAdd(&h[d >> 9], 1);
            atomicAdd(&cnt[d], 1);
        }
    }
    __syncthreads();
    hist_bm[tid * NBLK2 + blk] = h[tid];
}

__global__ __launch_bounds__(256) void sort_scatter(
    const int* __restrict__ ei, const int* __restrict__ off_bm, int2* __restrict__ srec)
{
    __shared__ int cur[NBUCK];
    int tid = threadIdx.x, blk = blockIdx.x;
    cur[tid] = off_bm[tid * NBLK2 + blk];
    __syncthreads();
#pragma unroll
    for (int it = 0; it < EPB / 256; ++it) {
        int e = blk * EPB + it * 256 + tid;
        if (e < ETOT) {
            int d = edge_dst(ei, e);
            int s = edge_src(ei, e);
            int pos = atomicAdd(&cur[d >> 9], 1);
            srec[pos] = make_int2(s, d);
        }
    }
}

__global__ __launch_bounds__(256) void csr_fill2(
    const int* __restrict__ row_ptr, const int2* __restrict__ srec, int* __restrict__ col_src)
{
    __shared__ int cur[512];
    int g = blockIdx.x, tid = threadIdx.x;
    int n0 = g << 9;
    for (int i = tid; i < 512; i += 256) {
        int nd = n0 + i;
        cur[i] = (nd < NN) ? row_ptr[nd] : 0;
    }
    __syncthreads();
    int lo = row_ptr[n0];
    int hi = (n0 + 512 <= NN) ? row_ptr[n0 + 512] : ETOT;
    for (int idx = lo + tid; idx < hi; idx += 256) {
        int2 r = srec[idx];
        int pos = atomicAdd(&cur[r.y - n0], 1);
        col_src[pos] = r.x;
    }
}

// ================= per-layer precomputes: att vecs + frag-ordered hi/lo recombine B =================
__global__ __launch_bounds__(256) void prep_kernel(
    const float* __restrict__ W, const float* __restrict__ attS,
    const float* __restrict__ attD, float* __restrict__ vs, float* __restrict__ vd,
    u16* __restrict__ Bph, u16* __restrict__ Bpl)
{
    int tid = threadIdx.x;
    if (blockIdx.x == 64) {
        int k = tid >> 2, h = tid & 3;
        const float* wr = W + (size_t)k * 256 + h * 64;
        const float* as = attS + h * 64;
        const float* ad = attD + h * 64;
        float ss = 0.f, sd = 0.f;
#pragma unroll
        for (int j = 0; j < 64; ++j) {
            float wv = wr[j];
            ss += wv * as[j];
            sd += wv * ad[j];
        }
        vs[tid] = ss;
        vd[tid] = sd;
    } else {
        int i = blockIdx.x * 256 + tid;   // i = r*64+c ; r = h*64+k'
        int r = i >> 6, c = i & 63;
        int h = r >> 6, k = r & 63;
        float v = W[(size_t)k * 256 + h * 64 + c];
        short hb, lb;
        split_bf16(v, hb, lb);
        int pos = ((r >> 3) * 64 + c) * 8 + (r & 7);
        Bph[pos] = (u16)hb;
        Bpl[pos] = (u16)lb;
    }
}

// ================= plain weight -> frag-ordered hi/lo (W[K][Nc] row-major) =================
__global__ __launch_bounds__(256) void prep_w(
    const float* __restrict__ W, u16* __restrict__ Bph, u16* __restrict__ Bpl, int K, int Nc)
{
    int i = blockIdx.x * 256 + threadIdx.x;
    if (i >= K * Nc) return;
    int k = i / Nc, c = i - k * Nc;
    short hb, lb;
    split_bf16(W[i], hb, lb);
    int pos = ((k >> 3) * Nc + c) * 8 + (k & 7);
    Bph[pos] = (u16)hb;
    Bpl[pos] = (u16)lb;
}

// ================= fused softmax + gather aggregation (wave per dst; bf16 x, bf16 agg) =================
__global__ __launch_bounds__(256) void gat_fused(
    const int* __restrict__ row_ptr, const int* __restrict__ col_src,
    const float4* __restrict__ a4s, const float4* __restrict__ a4d,
    const u16* __restrict__ x, u16* __restrict__ agg)
{
    __shared__ float4 sp[4][CAP];
    __shared__ int    ssrc[4][CAP];
    const int wslot = threadIdx.x >> 6;
    const int lane = threadIdx.x & 63;
    const int d = (blockIdx.x * 256 + threadIdx.x) >> 6;

    const int rs = row_ptr[d];
    const int deg = row_ptr[d + 1] - rs;
    const float4 ad = a4d[d];

    float px = 0.f, py = 0.f, pz = 0.f, pw = 0.f;
    for (int base = 0; base < deg; base += 64) {
        int idx = base + lane;
        float4 p = {0.f, 0.f, 0.f, 0.f};
        int s = 0;
        if (idx < deg) {
            s = col_src[rs + idx];
            float4 v = a4s[s];
            p.x = fexp(lrelu(v.x + ad.x));
            p.y = fexp(lrelu(v.y + ad.y));
            p.z = fexp(lrelu(v.z + ad.z));
            p.w = fexp(lrelu(v.w + ad.w));
        }
        if (idx < CAP) { sp[wslot][idx] = p; ssrc[wslot][idx] = s; }
        px += p.x; py += p.y; pz += p.z; pw += p.w;
    }
#pragma unroll
    for (int off = 32; off > 0; off >>= 1) {
        px += __shfl_xor(px, off, 64);
        py += __shfl_xor(py, off, 64);
        pz += __shfl_xor(pz, off, 64);
        pw += __shfl_xor(pw, off, 64);
    }
    const float ivx = 0.25f * __builtin_amdgcn_rcpf(px);
    const float ivy = 0.25f * __builtin_amdgcn_rcpf(py);
    const float ivz = 0.25f * __builtin_amdgcn_rcpf(pz);
    const float ivw = 0.25f * __builtin_amdgcn_rcpf(pw);

    float a0 = 0.f, a1 = 0.f, a2 = 0.f, a3 = 0.f;
    const int lim = deg < CAP ? deg : CAP;
    int e = 0;
    for (; e + 4 <= lim; e += 4) {
        float4 p0 = sp[wslot][e + 0], p1 = sp[wslot][e + 1];
        float4 p2 = sp[wslot][e + 2], p3 = sp[wslot][e + 3];
        int s0 = ssrc[wslot][e + 0], s1 = ssrc[wslot][e + 1];
        int s2 = ssrc[wslot][e + 2], s3 = ssrc[wslot][e + 3];
        float x0 = bf2f(x[(size_t)s0 * 64 + lane]);
        float x1 = bf2f(x[(size_t)s1 * 64 + lane]);
        float x2 = bf2f(x[(size_t)s2 * 64 + lane]);
        float x3 = bf2f(x[(size_t)s3 * 64 + lane]);
        a0 += p0.x * x0 + p1.x * x1 + p2.x * x2 + p3.x * x3;
        a1 += p0.y * x0 + p1.y * x1 + p2.y * x2 + p3.y * x3;
        a2 += p0.z * x0 + p1.z * x1 + p2.z * x2 + p3.z * x3;
        a3 += p0.w * x0 + p1.w * x1 + p2.w * x2 + p3.w * x3;
    }
    for (; e < lim; ++e) {
        float4 p = sp[wslot][e];
        int s = ssrc[wslot][e];
        float xv = bf2f(x[(size_t)s * 64 + lane]);
        a0 = fmaf(p.x, xv, a0);
        a1 = fmaf(p.y, xv, a1);
        a2 = fmaf(p.z, xv, a2);
        a3 = fmaf(p.w, xv, a3);
    }
    for (; e < deg; ++e) {
        int s = col_src[rs + e];
        float4 v = a4s[s];
        float4 p;
        p.x = fexp(lrelu(v.x + ad.x)); p.y = fexp(lrelu(v.y + ad.y));
        p.z = fexp(lrelu(v.z + ad.z)); p.w = fexp(lrelu(v.w + ad.w));
        float xv = bf2f(x[(size_t)s * 64 + lane]);
        a0 = fmaf(p.x, xv, a0);
        a1 = fmaf(p.y, xv, a1);
        a2 = fmaf(p.z, xv, a2);
        a3 = fmaf(p.w, xv, a3);
    }

    u16* op = agg + (size_t)d * 256;
    __builtin_nontemporal_store(f2bf(a0 * ivx), &op[lane]);
    __builtin_nontemporal_store(f2bf(a1 * ivy), &op[64 + lane]);
    __builtin_nontemporal_store(f2bf(a2 * ivz), &op[128 + lane]);
    __builtin_nontemporal_store(f2bf(a3 * ivw), &op[192 + lane]);
}

extern "C" void kernel_launch(void* const* d_in, const int* in_sizes, int n_in,
                              void* d_out, int out_size, void* d_ws, size_t ws_size,
                              hipStream_t stream)
{
    const float* obs     = (const float*)d_in[0];
    const int*   ei      = (const int*)d_in[1];
    const float* enc_w1  = (const float*)d_in[2];
    const float* enc_b1  = (const float*)d_in[3];
    const float* enc_w2  = (const float*)d_in[4];
    const float* enc_b2  = (const float*)d_in[5];
    const float* gat1_w  = (const float*)d_in[6];
    const float* gat1_as = (const float*)d_in[7];
    const float* gat1_ad = (const float*)d_in[8];
    const float* gat1_b  = (const float*)d_in[9];
    const float* gat2_w  = (const float*)d_in[10];
    const float* gat2_as = (const float*)d_in[11];
    const float* gat2_ad = (const float*)d_in[12];
    const float* gat2_b  = (const float*)d_in[13];
    const float* dec_w1  = (const float*)d_in[14];
    const float* dec_b1  = (const float*)d_in[15];
    const float* dec_w2  = (const float*)d_in[16];
    const float* dec_b2  = (const float*)d_in[17];

    float* ws = (float*)d_ws;
    float* bufA    = ws;                                   // [N,64] (spare)
    float* bufB    = bufA + (size_t)NN * 64;               // region for x (bf16 [N,64])
    float* agg     = bufB + (size_t)NN * 64;               // region for agg (bf16 [N,256])
    float4* a4s    = (float4*)(agg + (size_t)NN * 256);    // [N]
    float4* a4d    = a4s + NN;                             // [N]
    int* row_ptr   = (int*)(a4d + NN);                     // [N+1] (+pad)
    int* cnt       = row_ptr + NN + 4;                     // [N]
    int* col_src   = cnt + NN;                             // [ETOT]
    int* partial   = col_src + ETOT;                       // [256]
    int* partial2  = partial + 256;                        // [256]
    float* vs1     = (float*)(partial2 + 256);             // [256]
    float* vd1     = vs1 + 256;                            // [256]
    float* vs2     = vd1 + 256;                            // [256]
    float* vd2     = vs2 + 256;                            // [256]
    float* B2a     = vd2 + 256;                            // recombine Bp hi/lo L1
    float* B2b     = B2a + 256 * 64;                       // recombine Bp hi/lo L2
    float* Wenc1   = B2b + 256 * 64;                       // enc_w1 hi/lo
    float* Wenc2   = Wenc1 + 128 * 64;                     // enc_w2 hi/lo
    float* Wdec1   = Wenc2 + 64 * 64;                      // dec_w1 hi/lo
    float* Wdec2   = Wdec1 + 64 * 64;                      // dec_w2 hi/lo
    int* hist      = (int*)(Wdec2 + 64 * 32);              // [NSCAN]
    int* off_bm    = hist + NSCAN;                         // [NSCAN]
    int2* srec     = (int2*)(off_bm + NSCAN);              // [ETOT]

    u16* xb   = (u16*)bufB;       // x as bf16 [N,64]
    u16* aggb = (u16*)agg;        // agg as bf16 [N,256]

    u16* Bph_a = (u16*)B2a;  u16* Bpl_a = Bph_a + 256 * 64;
    u16* Bph_b = (u16*)B2b;  u16* Bpl_b = Bph_b + 256 * 64;
    u16* e1h = (u16*)Wenc1;  u16* e1l = e1h + 128 * 64;
    u16* e2h = (u16*)Wenc2;  u16* e2l = e2h + 64 * 64;
    u16* d1h = (u16*)Wdec1;  u16* d1l = d1h + 64 * 64;
    u16* d2h = (u16*)Wdec2;  u16* d2l = d2h + 64 * 32;

    const int GB = (NN + 63) / 64;
    const int NCHUNK_N = (NN + 511) / 512;        // 196
    const int NCHUNK_S = (NSCAN + 511) / 512;     // 220

    // ---- CSR build via counting sort (once, reused by both GAT layers) ----
    hipMemsetAsync(cnt, 0, (size_t)NN * sizeof(int), stream);
    sort_hist<<<NBLK2, 256, 0, stream>>>(ei, hist, cnt);
    gscan_partial<<<NCHUNK_N, 256, 0, stream>>>(cnt, partial, NN);
    gscan_top<<<1, 256, 0, stream>>>(partial, NCHUNK_N);
    gscan_final<<<NCHUNK_N, 256, 0, stream>>>(cnt, partial, row_ptr, NN);
    set_tail<<<1, 1, 0, stream>>>(row_ptr);
    gscan_partial<<<NCHUNK_S, 256, 0, stream>>>(hist, partial2, NSCAN);
    gscan_top<<<1, 256, 0, stream>>>(partial2, NCHUNK_S);
    gscan_final<<<NCHUNK_S, 256, 0, stream>>>(hist, partial2, off_bm, NSCAN);
    sort_scatter<<<NBLK2, 256, 0, stream>>>(ei, off_bm, srec);
    csr_fill2<<<NGRP, 256, 0, stream>>>(row_ptr, srec, col_src);

    // ---- weight precomputes (hoisted) ----
    prep_kernel<<<65, 256, 0, stream>>>(gat1_w, gat1_as, gat1_ad, vs1, vd1, Bph_a, Bpl_a);
    prep_kernel<<<65, 256, 0, stream>>>(gat2_w, gat2_as, gat2_ad, vs2, vd2, Bph_b, Bpl_b);
    prep_w<<<32, 256, 0, stream>>>(enc_w1, e1h, e1l, 128, 64);
    prep_w<<<16, 256, 0, stream>>>(enc_w2, e2h, e2l, 64, 64);
    prep_w<<<16, 256, 0, stream>>>(dec_w1, d1h, d1l, 64, 64);
    prep_w<<<8, 256, 0, stream>>>(dec_w2, d2h, d2l, 64, 32);

    // ---- encoder: fused 2-layer MLP (fp32 obs -> bf16 x) + layer-1 scores ----
    mlp2_gemm<4, false, true><<<GB, 256, 0, stream>>>(obs, e1h, e1l, enc_b1, e2h, e2l, enc_b2,
                                                      xb, NN, 128, vs1, vd1, a4s, a4d);

    // ---- GAT layer 1 (bf16 recombine fused with layer-2 scores) ----
    gat_fused<<<(NN * 64) / 256, 256, 0, stream>>>(row_ptr, col_src, a4s, a4d, xb, aggb);
    mfma_gemm_b<4><<<GB, 256, 0, stream>>>(aggb, Bph_a, Bpl_a, gat1_b, xb, NN, 256,
                                           vs2, vd2, a4s, a4d);

    // ---- GAT layer 2 ----
    gat_fused<<<(NN * 64) / 256, 256, 0, stream>>>(row_ptr, col_src, a4s, a4d, xb, aggb);
    mfma_gemm_b<4><<<GB, 256, 0, stream>>>(aggb, Bph_b, Bpl_b, gat2_b, xb, NN, 256,
                                           nullptr, nullptr, nullptr, nullptr);

    // ---- decoder: fused 2-layer MLP (bf16 x -> fp32 out) ----
    mlp2_gemm<2, true, false><<<GB, 256, 0, stream>>>(xb, d1h, d1l, dec_b1, d2h, d2l, dec_b2,
                                                      d_out, NN, 64, nullptr, nullptr, nullptr, nullptr);
}

// Round 28
// 302.446 us; speedup vs baseline: 1.4126x; 1.0344x over previous
//
#include <hip/hip_runtime.h>
#include <math.h>

#define NN 100000
#define EE 800000
#define ETOT (EE + NN)
#define CAP 128
#define NBLK2 440            // sort blocks
#define EPB 2048             // edges per sort block (440*2048 >= ETOT)
#define NBUCK 256            // histogram buckets; bucket = d>>9 (<=195)
#define NSCAN (NBUCK * NBLK2)
#define NGRP ((NN + 511) >> 9)   // 196 dst-groups of 512
// HID=64, HEADS=4, OBS=128, ACT=32

typedef __attribute__((ext_vector_type(8))) short s8v;
typedef __attribute__((ext_vector_type(4))) float f4v;
typedef unsigned short u16;
typedef unsigned int   u32;

__device__ __forceinline__ void split_bf16(float v, short& h, short& lo)
{
    u32 u = __float_as_uint(v);
    h = (short)(u >> 16);
    float hf = __uint_as_float(u & 0xFFFF0000u);
    lo = (short)(__float_as_uint(v - hf) >> 16);
}
__device__ __forceinline__ float bf2f(u16 u) { return __uint_as_float(((u32)u) << 16); }
__device__ __forceinline__ u16 f2bf(float v)   // round-to-nearest-even
{
    u32 u = __float_as_uint(v);
    return (u16)((u + 0x7FFFu + ((u >> 16) & 1u)) >> 16);
}

// ---------------- MFMA recombine GEMM, bf16 A: C_bf16[M,Nc]=relu(A_bf16[M,K]@Bp+bias) ----------------
template <int NCB>
__global__ __launch_bounds__(256) void mfma_gemm_b(
    const u16* __restrict__ A, const u16* __restrict__ Bph,
    const u16* __restrict__ Bpl, const float* __restrict__ bias,
    u16* __restrict__ C, int M, int K,
    const float* __restrict__ vsc, const float* __restrict__ vdc,
    float4* __restrict__ oas, float4* __restrict__ oad)
{
    constexpr int Nc = NCB * 16;
    __shared__ __align__(16) u16 aHi[64 * 40];
    __shared__ float svs[256], svd[256];

    const int tid = threadIdx.x;
    const int bm = blockIdx.x * 64;
    const int w = tid >> 6;
    const int l = tid & 63;

    if (vsc) { svs[tid] = vsc[tid]; svd[tid] = vdc[tid]; }

    const int srow = tid >> 2;
    const int sks  = (tid & 3) * 8;
    const int gr   = bm + srow;
    const bool sval = gr < M;
    const int NT = K >> 5;

    f4v acc[NCB];
#pragma unroll
    for (int cb = 0; cb < NCB; ++cb) { acc[cb][0] = 0.f; acc[cb][1] = 0.f; acc[cb][2] = 0.f; acc[cb][3] = 0.f; }

    s8v ra = {0,0,0,0,0,0,0,0};
    if (sval) ra = *(const s8v*)&A[(size_t)gr * K + sks];

    const int arow = 16 * w + (l & 15);
    const int akb8 = (l >> 4) * 8;
    const int colg = l & 15;

    for (int t = 0; t < NT; ++t) {
        *(s8v*)&aHi[srow * 40 + sks] = ra;
        __syncthreads();

        if (t + 1 < NT) {
            const int k0 = (t + 1) << 5;
            s8v z = {0,0,0,0,0,0,0,0};
            ra = z;
            if (sval) ra = *(const s8v*)&A[(size_t)gr * K + k0 + sks];
        }

        s8v ah = *(const s8v*)&aHi[arow * 40 + akb8];
        const int bkb = 4 * t + (l >> 4);
#pragma unroll
        for (int cb = 0; cb < NCB; ++cb) {
            int bidx = (bkb * Nc + cb * 16 + colg) * 8;
            s8v bh = *(const s8v*)&Bph[bidx];
            s8v bl = *(const s8v*)&Bpl[bidx];
            acc[cb] = __builtin_amdgcn_mfma_f32_16x16x32_bf16(ah, bh, acc[cb], 0, 0, 0);
            acc[cb] = __builtin_amdgcn_mfma_f32_16x16x32_bf16(ah, bl, acc[cb], 0, 0, 0);
        }
        __syncthreads();
    }

    const int ct = l & 15;
    const int cg = l >> 4;
    float val[NCB][4];
#pragma unroll
    for (int cb = 0; cb < NCB; ++cb) {
        float bvv = bias[cb * 16 + ct];
#pragma unroll
        for (int i = 0; i < 4; ++i) {
            float v = fmaxf(acc[cb][i] + bvv, 0.f);
            val[cb][i] = v;
            int row = bm + 16 * w + cg * 4 + i;
            if (row < M) C[(size_t)row * Nc + cb * 16 + ct] = f2bf(v);
        }
    }

    if (vsc) {
        float cs[NCB][4], cd[NCB][4];
#pragma unroll
        for (int cb = 0; cb < NCB; ++cb)
#pragma unroll
            for (int h = 0; h < 4; ++h) {
                cs[cb][h] = svs[(cb * 16 + ct) * 4 + h];
                cd[cb][h] = svd[(cb * 16 + ct) * 4 + h];
            }
#pragma unroll
        for (int i = 0; i < 4; ++i) {
            float ps[4] = {0.f, 0.f, 0.f, 0.f};
            float pd[4] = {0.f, 0.f, 0.f, 0.f};
#pragma unroll
            for (int cb = 0; cb < NCB; ++cb)
#pragma unroll
                for (int h = 0; h < 4; ++h) {
                    ps[h] = fmaf(val[cb][i], cs[cb][h], ps[h]);
                    pd[h] = fmaf(val[cb][i], cd[cb][h], pd[h]);
                }
#pragma unroll
            for (int off = 1; off < 16; off <<= 1) {
#pragma unroll
                for (int h = 0; h < 4; ++h) {
                    ps[h] += __shfl_xor(ps[h], off, 64);
                    pd[h] += __shfl_xor(pd[h], off, 64);
                }
            }
            if (ct == 0) {
                int row = bm + 16 * w + cg * 4 + i;
                if (row < M) {
                    float4 s4 = {ps[0], ps[1], ps[2], ps[3]};
                    float4 d4 = {pd[0], pd[1], pd[2], pd[3]};
                    oas[row] = s4;
                    oad[row] = d4;
                }
            }
        }
    }
}

// ---------------- fused 2-layer MLP (templated A/out dtype) ----------------
template <int NCB2, bool AB16, bool OB16>
__global__ __launch_bounds__(256) void mlp2_gemm(
    const void* __restrict__ Ap,
    const u16* __restrict__ B1h, const u16* __restrict__ B1l, const float* __restrict__ bias1,
    const u16* __restrict__ B2h, const u16* __restrict__ B2l, const float* __restrict__ bias2,
    void* __restrict__ Cp, int M, int K1,
    const float* __restrict__ vsc, const float* __restrict__ vdc,
    float4* __restrict__ oas, float4* __restrict__ oad)
{
    constexpr int Nc2 = NCB2 * 16;
    __shared__ __align__(16) u16 aHi[64 * 72];
    __shared__ __align__(16) u16 aLo[64 * 72];
    __shared__ float svs[256], svd[256];

    const float* Af = (const float*)Ap;
    const u16*   Ab = (const u16*)Ap;
    float* Cf = (float*)Cp;
    u16*   Cb = (u16*)Cp;

    const int tid = threadIdx.x;
    const int bm = blockIdx.x * 64;
    const int w = tid >> 6;
    const int l = tid & 63;

    if (vsc) { svs[tid] = vsc[tid]; svd[tid] = vdc[tid]; }

    const int srow = tid >> 2;
    const int sks  = (tid & 3) * 8;
    const int gr   = bm + srow;
    const bool sval = gr < M;
    const int NT = K1 >> 5;

    f4v acc1[4];
#pragma unroll
    for (int cb = 0; cb < 4; ++cb) { acc1[cb][0] = 0.f; acc1[cb][1] = 0.f; acc1[cb][2] = 0.f; acc1[cb][3] = 0.f; }

    float4 r0 = {0.f,0.f,0.f,0.f}, r1 = {0.f,0.f,0.f,0.f};
    s8v rb = {0,0,0,0,0,0,0,0};
    if (sval) {
        if constexpr (AB16) {
            rb = *(const s8v*)&Ab[(size_t)gr * K1 + sks];
        } else {
            r0 = *(const float4*)&Af[(size_t)gr * K1 + sks];
            r1 = *(const float4*)&Af[(size_t)gr * K1 + sks + 4];
        }
    }

    const int arow = 16 * w + (l & 15);
    const int akb8 = (l >> 4) * 8;
    const int colg = l & 15;

    // ---- stage 1 ----
    for (int t = 0; t < NT; ++t) {
        if constexpr (AB16) {
            *(s8v*)&aHi[srow * 72 + sks] = rb;
        } else {
            float vals[8] = {r0.x, r0.y, r0.z, r0.w, r1.x, r1.y, r1.z, r1.w};
            s8v hv, lv;
#pragma unroll
            for (int e = 0; e < 8; ++e) { short h, lo; split_bf16(vals[e], h, lo); hv[e] = h; lv[e] = lo; }
            *(s8v*)&aHi[srow * 72 + sks] = hv;
            *(s8v*)&aLo[srow * 72 + sks] = lv;
        }
        __syncthreads();

        if (t + 1 < NT) {
            const int k0 = (t + 1) << 5;
            if constexpr (AB16) {
                s8v z = {0,0,0,0,0,0,0,0};
                rb = z;
                if (sval) rb = *(const s8v*)&Ab[(size_t)gr * K1 + k0 + sks];
            } else {
                r0 = make_float4(0.f, 0.f, 0.f, 0.f);
                r1 = make_float4(0.f, 0.f, 0.f, 0.f);
                if (sval) {
                    r0 = *(const float4*)&Af[(size_t)gr * K1 + k0 + sks];
                    r1 = *(const float4*)&Af[(size_t)gr * K1 + k0 + sks + 4];
                }
            }
        }

        s8v ah = *(const s8v*)&aHi[arow * 72 + akb8];
        s8v al;
        if constexpr (!AB16) al = *(const s8v*)&aLo[arow * 72 + akb8];
        const int bkb = 4 * t + (l >> 4);
#pragma unroll
        for (int cb = 0; cb < 4; ++cb) {
            int bidx = (bkb * 64 + cb * 16 + colg) * 8;
            s8v bh = *(const s8v*)&B1h[bidx];
            s8v bl = *(const s8v*)&B1l[bidx];
            acc1[cb] = __builtin_amdgcn_mfma_f32_16x16x32_bf16(ah, bh, acc1[cb], 0, 0, 0);
            acc1[cb] = __builtin_amdgcn_mfma_f32_16x16x32_bf16(ah, bl, acc1[cb], 0, 0, 0);
            if constexpr (!AB16)
                acc1[cb] = __builtin_amdgcn_mfma_f32_16x16x32_bf16(al, bh, acc1[cb], 0, 0, 0);
        }
        __syncthreads();
    }

    // ---- stage-1 epilogue: hidden (fp32) -> hi/lo LDS frag buffer ----
    const int ct = l & 15;
    const int cg = l >> 4;
#pragma unroll
    for (int cb = 0; cb < 4; ++cb) {
        float bvv = bias1[cb * 16 + ct];
#pragma unroll
        for (int i = 0; i < 4; ++i) {
            float v = fmaxf(acc1[cb][i] + bvv, 0.f);
            int row = 16 * w + cg * 4 + i;
            int col = cb * 16 + ct;
            short hb, lb;
            split_bf16(v, hb, lb);
            aHi[row * 72 + col] = (u16)hb;
            aLo[row * 72 + col] = (u16)lb;
        }
    }
    __syncthreads();

    // ---- stage 2 ----
    f4v acc2[NCB2];
#pragma unroll
    for (int cb = 0; cb < NCB2; ++cb) { acc2[cb][0] = 0.f; acc2[cb][1] = 0.f; acc2[cb][2] = 0.f; acc2[cb][3] = 0.f; }
#pragma unroll
    for (int t2 = 0; t2 < 2; ++t2) {
        s8v ah = *(const s8v*)&aHi[arow * 72 + 32 * t2 + akb8];
        s8v al = *(const s8v*)&aLo[arow * 72 + 32 * t2 + akb8];
        const int bkb = 4 * t2 + (l >> 4);
#pragma unroll
        for (int cb = 0; cb < NCB2; ++cb) {
            int bidx = (bkb * Nc2 + cb * 16 + colg) * 8;
            s8v bh = *(const s8v*)&B2h[bidx];
            s8v bl = *(const s8v*)&B2l[bidx];
            acc2[cb] = __builtin_amdgcn_mfma_f32_16x16x32_bf16(ah, bh, acc2[cb], 0, 0, 0);
            acc2[cb] = __builtin_amdgcn_mfma_f32_16x16x32_bf16(ah, bl, acc2[cb], 0, 0, 0);
            acc2[cb] = __builtin_amdgcn_mfma_f32_16x16x32_bf16(al, bh, acc2[cb], 0, 0, 0);
        }
    }

    // ---- stage-2 epilogue ----
    float val[NCB2][4];
#pragma unroll
    for (int cb = 0; cb < NCB2; ++cb) {
        float bvv = bias2[cb * 16 + ct];
#pragma unroll
        for (int i = 0; i < 4; ++i) {
            float v = acc2[cb][i] + bvv;
            val[cb][i] = v;
            int row = bm + 16 * w + cg * 4 + i;
            if (row < M) {
                if constexpr (OB16) Cb[(size_t)row * Nc2 + cb * 16 + ct] = f2bf(v);
                else                Cf[(size_t)row * Nc2 + cb * 16 + ct] = v;
            }
        }
    }

    if (vsc) {
        float cs[NCB2][4], cd[NCB2][4];
#pragma unroll
        for (int cb = 0; cb < NCB2; ++cb)
#pragma unroll
            for (int h = 0; h < 4; ++h) {
                cs[cb][h] = svs[(cb * 16 + ct) * 4 + h];
                cd[cb][h] = svd[(cb * 16 + ct) * 4 + h];
            }
#pragma unroll
        for (int i = 0; i < 4; ++i) {
            float ps[4] = {0.f, 0.f, 0.f, 0.f};
            float pd[4] = {0.f, 0.f, 0.f, 0.f};
#pragma unroll
            for (int cb = 0; cb < NCB2; ++cb)
#pragma unroll
                for (int h = 0; h < 4; ++h) {
                    ps[h] = fmaf(val[cb][i], cs[cb][h], ps[h]);
                    pd[h] = fmaf(val[cb][i], cd[cb][h], pd[h]);
                }
#pragma unroll
            for (int off = 1; off < 16; off <<= 1) {
#pragma unroll
                for (int h = 0; h < 4; ++h) {
                    ps[h] += __shfl_xor(ps[h], off, 64);
                    pd[h] += __shfl_xor(pd[h], off, 64);
                }
            }
            if (ct == 0) {
                int row = bm + 16 * w + cg * 4 + i;
                if (row < M) {
                    float4 s4 = {ps[0], ps[1], ps[2], ps[3]};
                    float4 d4 = {pd[0], pd[1], pd[2], pd[3]};
                    oas[row] = s4;
                    oad[row] = d4;
                }
            }
        }
    }
}

__device__ __forceinline__ float lrelu(float x) { return fmaxf(x, 0.2f * x); }
__device__ __forceinline__ float fexp(float x) { return __expf(x); }
__device__ __forceinline__ int edge_src(const int* ei, int e) { return e < EE ? ei[e] : e - EE; }
__device__ __forceinline__ int edge_dst(const int* ei, int e) { return e < EE ? ei[EE + e] : e - EE; }

// ================= generic 3-kernel exclusive scan =================
__global__ __launch_bounds__(256) void gscan_partial(const int* __restrict__ in, int* __restrict__ partial, int n)
{
    __shared__ int s[256];
    int b = blockIdx.x;
    int gi = b * 512 + threadIdx.x;
    int v = 0;
    if (gi < n) v += in[gi];
    if (gi + 256 < n) v += in[gi + 256];
    s[threadIdx.x] = v;
    __syncthreads();
    for (int off = 128; off > 0; off >>= 1) {
        if (threadIdx.x < off) s[threadIdx.x] += s[threadIdx.x + off];
        __syncthreads();
    }
    if (threadIdx.x == 0) partial[b] = s[0];
}

__global__ __launch_bounds__(256) void gscan_top(int* __restrict__ partial, int nb)
{
    __shared__ int s[256];
    int tid = threadIdx.x;
    s[tid] = (tid < nb) ? partial[tid] : 0;
    __syncthreads();
    for (int off = 1; off < 256; off <<= 1) {
        int t = (tid >= off) ? s[tid - off] : 0;
        __syncthreads();
        s[tid] += t;
        __syncthreads();
    }
    if (tid < nb) partial[tid] = (tid == 0) ? 0 : s[tid - 1];
}

__global__ __launch_bounds__(256) void gscan_final(
    const int* __restrict__ in, const int* __restrict__ partial, int* __restrict__ out, int n)
{
    __shared__ int s[512];
    int b = blockIdx.x;
    int tid = threadIdx.x;
    int g0 = b * 512 + tid, g1 = b * 512 + tid + 256;
    s[tid]       = (g0 < n) ? in[g0] : 0;
    s[tid + 256] = (g1 < n) ? in[g1] : 0;
    __syncthreads();
#pragma unroll
    for (int d = 0; d < 9; ++d) {
        int stride = 1 << d, nn2 = 256 >> d;
        if (tid < nn2) s[(2 * tid + 2) * stride - 1] += s[(2 * tid + 1) * stride - 1];
        __syncthreads();
    }
    if (tid == 0) s[511] = 0;
    __syncthreads();
#pragma unroll
    for (int d = 8; d >= 0; --d) {
        int stride = 1 << d, nn2 = 256 >> d;
        if (tid < nn2) {
            int i1 = (2 * tid + 1) * stride - 1, i2 = (2 * tid + 2) * stride - 1;
            int t = s[i1];
            s[i1] = s[i2];
            s[i2] += t;
        }
        __syncthreads();
    }
    int off = partial[b];
    if (g0 < n) out[g0] = s[tid] + off;
    if (g1 < n) out[g1] = s[tid + 256] + off;
}

__global__ void set_tail(int* __restrict__ row_ptr)
{
    row_ptr[NN] = ETOT;
}

// ================= counting sort of edges by dst-group =================
__global__ __launch_bounds__(256) void sort_hist(
    const int* __restrict__ ei, int* __restrict__ hist_bm, int* __restrict__ cnt)
{
    __shared__ int h[NBUCK];
    int tid = threadIdx.x, blk = blockIdx.x;
    h[tid] = 0;
    __syncthreads();
#pragma unroll
    for (int it = 0; it < EPB / 256; ++it) {
        int e = blk * EPB + it * 256 + tid;
        if (e < ETOT) {
            int d = edge_dst(ei, e);
            atomicAdd(&h[d >> 9], 1);
            atomicAdd(&cnt[d], 1);
        }
    }
    __syncthreads();
    hist_bm[tid * NBLK2 + blk] = h[tid];
}

__global__ __launch_bounds__(256) void sort_scatter(
    const int* __restrict__ ei, const int* __restrict__ off_bm, int2* __restrict__ srec)
{
    __shared__ int cur[NBUCK];
    int tid = threadIdx.x, blk = blockIdx.x;
    cur[tid] = off_bm[tid * NBLK2 + blk];
    __syncthreads();
#pragma unroll
    for (int it = 0; it < EPB / 256; ++it) {
        int e = blk * EPB + it * 256 + tid;
        if (e < ETOT) {
            int d = edge_dst(ei, e);
            int s = edge_src(ei, e);
            int pos = atomicAdd(&cur[d >> 9], 1);
            srec[pos] = make_int2(s, d);
        }
    }
}

__global__ __launch_bounds__(256) void csr_fill2(
    const int* __restrict__ row_ptr, const int2* __restrict__ srec, int* __restrict__ col_src)
{
    __shared__ int cur[512];
    int g = blockIdx.x, tid = threadIdx.x;
    int n0 = g << 9;
    for (int i = tid; i < 512; i += 256) {
        int nd = n0 + i;
        cur[i] = (nd < NN) ? row_ptr[nd] : 0;
    }
    __syncthreads();
    int lo = row_ptr[n0];
    int hi = (n0 + 512 <= NN) ? row_ptr[n0 + 512] : ETOT;
    for (int idx = lo + tid; idx < hi; idx += 256) {
        int2 r = srec[idx];
        int pos = atomicAdd(&cur[r.y - n0], 1);
        col_src[pos] = r.x;
    }
}

// ================= per-layer precomputes: att vecs + frag-ordered hi/lo recombine B =================
__global__ __launch_bounds__(256) void prep_kernel(
    const float* __restrict__ W, const float* __restrict__ attS,
    const float* __restrict__ attD, float* __restrict__ vs, float* __restrict__ vd,
    u16* __restrict__ Bph, u16* __restrict__ Bpl)
{
    int tid = threadIdx.x;
    if (blockIdx.x == 64) {
        int k = tid >> 2, h = tid & 3;
        const float* wr = W + (size_t)k * 256 + h * 64;
        const float* as = attS + h * 64;
        const float* ad = attD + h * 64;
        float ss = 0.f, sd = 0.f;
#pragma unroll
        for (int j = 0; j < 64; ++j) {
            float wv = wr[j];
            ss += wv * as[j];
            sd += wv * ad[j];
        }
        vs[tid] = ss;
        vd[tid] = sd;
    } else {
        int i = blockIdx.x * 256 + tid;   // i = r*64+c ; r = h*64+k'
        int r = i >> 6, c = i & 63;
        int h = r >> 6, k = r & 63;
        float v = W[(size_t)k * 256 + h * 64 + c];
        short hb, lb;
        split_bf16(v, hb, lb);
        int pos = ((r >> 3) * 64 + c) * 8 + (r & 7);
        Bph[pos] = (u16)hb;
        Bpl[pos] = (u16)lb;
    }
}

// ================= plain weight -> frag-ordered hi/lo (W[K][Nc] row-major) =================
__global__ __launch_bounds__(256) void prep_w(
    const float* __restrict__ W, u16* __restrict__ Bph, u16* __restrict__ Bpl, int K, int Nc)
{
    int i = blockIdx.x * 256 + threadIdx.x;
    if (i >= K * Nc) return;
    int k = i / Nc, c = i - k * Nc;
    short hb, lb;
    split_bf16(W[i], hb, lb);
    int pos = ((k >> 3) * Nc + c) * 8 + (k & 7);
    Bph[pos] = (u16)hb;
    Bpl[pos] = (u16)lb;
}

// ================= fused softmax + gather aggregation (wave per dst; bf16 x/agg) =================
// R27: denominators accumulated redundantly per-lane in Phase B (p already read from
// LDS there) — removes the 24-shfl butterfly + Phase A running sums (shfl = ds op with
// lgkmcnt serialization; kernel is instruction/latency-bound at VALU 66%).
__global__ __launch_bounds__(256) void gat_fused(
    const int* __restrict__ row_ptr, const int* __restrict__ col_src,
    const float4* __restrict__ a4s, const float4* __restrict__ a4d,
    const u16* __restrict__ x, u16* __restrict__ agg)
{
    __shared__ float4 sp[4][CAP];
    __shared__ int    ssrc[4][CAP];
    const int wslot = threadIdx.x >> 6;
    const int lane = threadIdx.x & 63;
    const int d = (blockIdx.x * 256 + threadIdx.x) >> 6;

    const int rs = row_ptr[d];
    const int deg = row_ptr[d + 1] - rs;
    const float4 ad = a4d[d];

    // ---- Phase A: edge-parallel p -> LDS (no reductions) ----
    for (int base = 0; base < deg; base += 64) {
        int idx = base + lane;
        if (idx < deg) {
            int s = col_src[rs + idx];
            float4 v = a4s[s];
            float4 p;
            p.x = fexp(lrelu(v.x + ad.x));
            p.y = fexp(lrelu(v.y + ad.y));
            p.z = fexp(lrelu(v.z + ad.z));
            p.w = fexp(lrelu(v.w + ad.w));
            if (idx < CAP) { sp[wslot][idx] = p; ssrc[wslot][idx] = s; }
        }
    }

    // ---- Phase B: feature-parallel gather; heads + denominators accumulated in-loop ----
    float a0 = 0.f, a1 = 0.f, a2 = 0.f, a3 = 0.f;
    float d0 = 0.f, d1 = 0.f, d2 = 0.f, d3 = 0.f;
    const int lim = deg < CAP ? deg : CAP;
    int e = 0;
    for (; e + 4 <= lim; e += 4) {
        float4 p0 = sp[wslot][e + 0], p1 = sp[wslot][e + 1];
        float4 p2 = sp[wslot][e + 2], p3 = sp[wslot][e + 3];
        int s0 = ssrc[wslot][e + 0], s1 = ssrc[wslot][e + 1];
        int s2 = ssrc[wslot][e + 2], s3 = ssrc[wslot][e + 3];
        float x0 = bf2f(x[(size_t)s0 * 64 + lane]);
        float x1 = bf2f(x[(size_t)s1 * 64 + lane]);
        float x2 = bf2f(x[(size_t)s2 * 64 + lane]);
        float x3 = bf2f(x[(size_t)s3 * 64 + lane]);
        a0 += p0.x * x0 + p1.x * x1 + p2.x * x2 + p3.x * x3;
        a1 += p0.y * x0 + p1.y * x1 + p2.y * x2 + p3.y * x3;
        a2 += p0.z * x0 + p1.z * x1 + p2.z * x2 + p3.z * x3;
        a3 += p0.w * x0 + p1.w * x1 + p2.w * x2 + p3.w * x3;
        d0 += p0.x + p1.x + p2.x + p3.x;
        d1 += p0.y + p1.y + p2.y + p3.y;
        d2 += p0.z + p1.z + p2.z + p3.z;
        d3 += p0.w + p1.w + p2.w + p3.w;
    }
    for (; e < lim; ++e) {
        float4 p = sp[wslot][e];
        int s = ssrc[wslot][e];
        float xv = bf2f(x[(size_t)s * 64 + lane]);
        a0 = fmaf(p.x, xv, a0);
        a1 = fmaf(p.y, xv, a1);
        a2 = fmaf(p.z, xv, a2);
        a3 = fmaf(p.w, xv, a3);
        d0 += p.x; d1 += p.y; d2 += p.z; d3 += p.w;
    }
    for (; e < deg; ++e) {   // slow path, statistically never taken
        int s = col_src[rs + e];
        float4 v = a4s[s];
        float4 p;
        p.x = fexp(lrelu(v.x + ad.x)); p.y = fexp(lrelu(v.y + ad.y));
        p.z = fexp(lrelu(v.z + ad.z)); p.w = fexp(lrelu(v.w + ad.w));
        float xv = bf2f(x[(size_t)s * 64 + lane]);
        a0 = fmaf(p.x, xv, a0);
        a1 = fmaf(p.y, xv, a1);
        a2 = fmaf(p.z, xv, a2);
        a3 = fmaf(p.w, xv, a3);
        d0 += p.x; d1 += p.y; d2 += p.z; d3 += p.w;
    }

    const float ivx = 0.25f * __builtin_amdgcn_rcpf(d0);
    const float ivy = 0.25f * __builtin_amdgcn_rcpf(d1);
    const float ivz = 0.25f * __builtin_amdgcn_rcpf(d2);
    const float ivw = 0.25f * __builtin_amdgcn_rcpf(d3);

    u16* op = agg + (size_t)d * 256;
    __builtin_nontemporal_store(f2bf(a0 * ivx), &op[lane]);
    __builtin_nontemporal_store(f2bf(a1 * ivy), &op[64 + lane]);
    __builtin_nontemporal_store(f2bf(a2 * ivz), &op[128 + lane]);
    __builtin_nontemporal_store(f2bf(a3 * ivw), &op[192 + lane]);
}

extern "C" void kernel_launch(void* const* d_in, const int* in_sizes, int n_in,
                              void* d_out, int out_size, void* d_ws, size_t ws_size,
                              hipStream_t stream)
{
    const float* obs     = (const float*)d_in[0];
    const int*   ei      = (const int*)d_in[1];
    const float* enc_w1  = (const float*)d_in[2];
    const float* enc_b1  = (const float*)d_in[3];
    const float* enc_w2  = (const float*)d_in[4];
    const float* enc_b2  = (const float*)d_in[5];
    const float* gat1_w  = (const float*)d_in[6];
    const float* gat1_as = (const float*)d_in[7];
    const float* gat1_ad = (const float*)d_in[8];
    const float* gat1_b  = (const float*)d_in[9];
    const float* gat2_w  = (const float*)d_in[10];
    const float* gat2_as = (const float*)d_in[11];
    const float* gat2_ad = (const float*)d_in[12];
    const float* gat2_b  = (const float*)d_in[13];
    const float* dec_w1  = (const float*)d_in[14];
    const float* dec_b1  = (const float*)d_in[15];
    const float* dec_w2  = (const float*)d_in[16];
    const float* dec_b2  = (const float*)d_in[17];

    float* ws = (float*)d_ws;
    float* bufA    = ws;                                   // [N,64] (spare)
    float* bufB    = bufA + (size_t)NN * 64;               // region for x (bf16 [N,64])
    float* agg     = bufB + (size_t)NN * 64;               // region for agg (bf16 [N,256])
    float4* a4s    = (float4*)(agg + (size_t)NN * 256);    // [N]
    float4* a4d    = a4s + NN;                             // [N]
    int* row_ptr   = (int*)(a4d + NN);                     // [N+1] (+pad)
    int* cnt       = row_ptr + NN + 4;                     // [N]
    int* col_src   = cnt + NN;                             // [ETOT]
    int* partial   = col_src + ETOT;                       // [256]
    int* partial2  = partial + 256;                        // [256]
    float* vs1     = (float*)(partial2 + 256);             // [256]
    float* vd1     = vs1 + 256;                            // [256]
    float* vs2     = vd1 + 256;                            // [256]
    float* vd2     = vs2 + 256;                            // [256]
    float* B2a     = vd2 + 256;                            // recombine Bp hi/lo L1
    float* B2b     = B2a + 256 * 64;                       // recombine Bp hi/lo L2
    float* Wenc1   = B2b + 256 * 64;                       // enc_w1 hi/lo
    float* Wenc2   = Wenc1 + 128 * 64;                     // enc_w2 hi/lo
    float* Wdec1   = Wenc2 + 64 * 64;                      // dec_w1 hi/lo
    float* Wdec2   = Wdec1 + 64 * 64;                      // dec_w2 hi/lo
    int* hist      = (int*)(Wdec2 + 64 * 32);              // [NSCAN]
    int* off_bm    = hist + NSCAN;                         // [NSCAN]
    int2* srec     = (int2*)(off_bm + NSCAN);              // [ETOT]

    u16* xb   = (u16*)bufB;       // x as bf16 [N,64]
    u16* aggb = (u16*)agg;        // agg as bf16 [N,256]

    u16* Bph_a = (u16*)B2a;  u16* Bpl_a = Bph_a + 256 * 64;
    u16* Bph_b = (u16*)B2b;  u16* Bpl_b = Bph_b + 256 * 64;
    u16* e1h = (u16*)Wenc1;  u16* e1l = e1h + 128 * 64;
    u16* e2h = (u16*)Wenc2;  u16* e2l = e2h + 64 * 64;
    u16* d1h = (u16*)Wdec1;  u16* d1l = d1h + 64 * 64;
    u16* d2h = (u16*)Wdec2;  u16* d2l = d2h + 64 * 32;

    const int GB = (NN + 63) / 64;
    const int NCHUNK_N = (NN + 511) / 512;        // 196
    const int NCHUNK_S = (NSCAN + 511) / 512;     // 220

    // ---- CSR build via counting sort (once, reused by both GAT layers) ----
    hipMemsetAsync(cnt, 0, (size_t)NN * sizeof(int), stream);
    sort_hist<<<NBLK2, 256, 0, stream>>>(ei, hist, cnt);
    gscan_partial<<<NCHUNK_N, 256, 0, stream>>>(cnt, partial, NN);
    gscan_top<<<1, 256, 0, stream>>>(partial, NCHUNK_N);
    gscan_final<<<NCHUNK_N, 256, 0, stream>>>(cnt, partial, row_ptr, NN);
    set_tail<<<1, 1, 0, stream>>>(row_ptr);
    gscan_partial<<<NCHUNK_S, 256, 0, stream>>>(hist, partial2, NSCAN);
    gscan_top<<<1, 256, 0, stream>>>(partial2, NCHUNK_S);
    gscan_final<<<NCHUNK_S, 256, 0, stream>>>(hist, partial2, off_bm, NSCAN);
    sort_scatter<<<NBLK2, 256, 0, stream>>>(ei, off_bm, srec);
    csr_fill2<<<NGRP, 256, 0, stream>>>(row_ptr, srec, col_src);

    // ---- weight precomputes (hoisted) ----
    prep_kernel<<<65, 256, 0, stream>>>(gat1_w, gat1_as, gat1_ad, vs1, vd1, Bph_a, Bpl_a);
    prep_kernel<<<65, 256, 0, stream>>>(gat2_w, gat2_as, gat2_ad, vs2, vd2, Bph_b, Bpl_b);
    prep_w<<<32, 256, 0, stream>>>(enc_w1, e1h, e1l, 128, 64);
    prep_w<<<16, 256, 0, stream>>>(enc_w2, e2h, e2l, 64, 64);
    prep_w<<<16, 256, 0, stream>>>(dec_w1, d1h, d1l, 64, 64);
    prep_w<<<8, 256, 0, stream>>>(dec_w2, d2h, d2l, 64, 32);

    // ---- encoder: fused 2-layer MLP (fp32 obs -> bf16 x) + layer-1 scores ----
    mlp2_gemm<4, false, true><<<GB, 256, 0, stream>>>(obs, e1h, e1l, enc_b1, e2h, e2l, enc_b2,
                                                      xb, NN, 128, vs1, vd1, a4s, a4d);

    // ---- GAT layer 1 (bf16 recombine fused with layer-2 scores) ----
    gat_fused<<<(NN * 64) / 256, 256, 0, stream>>>(row_ptr, col_src, a4s, a4d, xb, aggb);
    mfma_gemm_b<4><<<GB, 256, 0, stream>>>(aggb, Bph_a, Bpl_a, gat1_b, xb, NN, 256,
                                           vs2, vd2, a4s, a4d);

    // ---- GAT layer 2 ----
    gat_fused<<<(NN * 64) / 256, 256, 0, stream>>>(row_ptr, col_src, a4s, a4d, xb, aggb);
    mfma_gemm_b<4><<<GB, 256, 0, stream>>>(aggb, Bph_b, Bpl_b, gat2_b, xb, NN, 256,
                                           nullptr, nullptr, nullptr, nullptr);

    // ---- decoder: fused 2-layer MLP (bf16 x -> fp32 out) ----
    mlp2_gemm<2, true, false><<<GB, 256, 0, stream>>>(xb, d1h, d1l, dec_b1, d2h, d2l, dec_b2,
                                                      d_out, NN, 64, nullptr, nullptr, nullptr, nullptr);
}